// Round 11
// baseline (905.867 us; speedup 1.0000x reference)
//
#include <hip/hip_runtime.h>
#include <hip/hip_bf16.h>
#include <hip/hip_fp16.h>

#define N_NODES  100000
#define N_PAD    100224   // 192 * 522
#define MTILE    192
#define N_EDGES  1600000
#define N_GRAPHS 128
#define D        108
#define IN_DIM   146
#define KP_H     128
#define KP_NF    160
#define PSTRIDE  128      // pooled row stride in halves (256B, line-aligned)
#define NBUCKET  391      // ceil(N_NODES/256)
#define LBUF     8192     // per-bucket LDS scatter buffer (max bucket edges ~4400)

typedef __bf16 bf16x8 __attribute__((ext_vector_type(8)));
typedef float  f32x4  __attribute__((ext_vector_type(4)));

__device__ __forceinline__ unsigned short f2bf_bits(float v) {
  __hip_bfloat16 b = __float2bfloat16(v);
  return __builtin_bit_cast(unsigned short, b);
}
__device__ __forceinline__ float bf_bits2f(unsigned short u) {
  __hip_bfloat16 b = __builtin_bit_cast(__hip_bfloat16, u);
  return __bfloat162float(b);
}
__device__ __forceinline__ void splitf(float v, unsigned short& hi, unsigned short& lo) {
  hi = f2bf_bits(v);
  lo = f2bf_bits(v - bf_bits2f(hi));
}

// ---------------- bucket histogram (LDS-batched) ----------------
__global__ __launch_bounds__(256)
void k_bhist(const int* __restrict__ dst, int* __restrict__ bhist) {
  __shared__ int bh[NBUCKET];
  int t = threadIdx.x;
  for (int i = t; i < NBUCKET; i += 256) bh[i] = 0;
  __syncthreads();
  int e0 = blockIdx.x * 2048;
#pragma unroll
  for (int j = 0; j < 8; j++) {
    int e = e0 + j * 256 + t;
    if (e < N_EDGES) atomicAdd(&bh[dst[e] >> 8], 1);
  }
  __syncthreads();
  for (int i = t; i < NBUCKET; i += 256)
    if (bh[i]) atomicAdd(&bhist[i], bh[i]);
}

// ---------------- bucket scan (one block) ----------------
__global__ __launch_bounds__(512)
void k_bscan(const int* __restrict__ bhist, int* __restrict__ boffs,
             int* __restrict__ bcur, int* __restrict__ offs) {
  __shared__ int sh[512];
  int t = threadIdx.x;
  sh[t] = (t < NBUCKET) ? bhist[t] : 0;
  __syncthreads();
  for (int off = 1; off < 512; off <<= 1) {
    int v = (t >= off) ? sh[t - off] : 0;
    __syncthreads();
    sh[t] += v;
    __syncthreads();
  }
  if (t < NBUCKET) {
    int excl = (t > 0) ? sh[t - 1] : 0;
    boffs[t] = excl;
    bcur[t]  = excl;
  }
  if (t == 0) { boffs[NBUCKET] = N_EDGES; offs[N_NODES] = N_EDGES; }
}

// ---------------- bin edges into bucket-contiguous ebin (LDS-batched ranks) ----
__global__ __launch_bounds__(256)
void k_binscatter(const int* __restrict__ src, const int* __restrict__ dst,
                  int* __restrict__ bcur, uint2* __restrict__ ebin) {
  __shared__ int lhist[NBUCKET];
  __shared__ int lbase[NBUCKET];
  int t = threadIdx.x;
  for (int i = t; i < NBUCKET; i += 256) lhist[i] = 0;
  __syncthreads();
  int e0 = blockIdx.x * 2048;
  int s[8], d[8], r[8];
#pragma unroll
  for (int j = 0; j < 8; j++) {
    int e = e0 + j * 256 + t;
    if (e < N_EDGES) {
      s[j] = src[e]; d[j] = dst[e];
      r[j] = atomicAdd(&lhist[d[j] >> 8], 1);
    }
  }
  __syncthreads();
  for (int i = t; i < NBUCKET; i += 256)
    lbase[i] = lhist[i] ? atomicAdd(&bcur[i], lhist[i]) : 0;
  __syncthreads();
#pragma unroll
  for (int j = 0; j < 8; j++) {
    int e = e0 + j * 256 + t;
    if (e < N_EDGES)
      ebin[(size_t)lbase[d[j] >> 8] + r[j]] = make_uint2((unsigned)s[j], (unsigned)d[j]);
  }
}

// ---------------- per-bucket local CSR: writes offs + coalesced esrc ----------
__global__ __launch_bounds__(256)
void k_scatter2(const uint2* __restrict__ ebin, const int* __restrict__ boffs,
                int* __restrict__ offs, int* __restrict__ esrc) {
  __shared__ int lcnt[256];
  __shared__ int lcur[256];
  __shared__ int lbuf[LBUF];
  int b = blockIdx.x;
  int t = threadIdx.x;
  int vbase = b << 8;
  int estart = boffs[b], eend = boffs[b + 1];
  int cnt = eend - estart;
  lcnt[t] = 0;
  __syncthreads();
  for (int e = estart + t; e < eend; e += 256)
    atomicAdd(&lcnt[ebin[e].y & 255], 1);
  __syncthreads();
  // inclusive scan of lcnt (in-place Hillis-Steele)
  for (int off = 1; off < 256; off <<= 1) {
    int v = (t >= off) ? lcnt[t - off] : 0;
    __syncthreads();
    lcnt[t] += v;
    __syncthreads();
  }
  int excl = (t > 0) ? lcnt[t - 1] : 0;
  int v = vbase + t;
  if (v < N_NODES) offs[v] = estart + excl;
  lcur[t] = excl;
  __syncthreads();
  if (cnt <= LBUF) {
    for (int e = estart + t; e < eend; e += 256) {
      uint2 u = ebin[e];
      int pos = atomicAdd(&lcur[u.y & 255], 1);
      lbuf[pos] = (int)u.x;
    }
    __syncthreads();
    for (int i = t; i < cnt; i += 256) esrc[estart + i] = lbuf[i];
  } else {   // safety fallback (statistically unreachable)
    for (int e = estart + t; e < eend; e += 256) {
      uint2 u = ebin[e];
      int pos = atomicAdd(&lcur[u.y & 255], 1);
      esrc[estart + pos] = (int)u.x;
    }
  }
}

// ---------------- split nodes_feat into padded bf16 hi/lo ----------------
__global__ void k_split_nf(const float* __restrict__ nf,
                           unsigned short* __restrict__ hi, unsigned short* __restrict__ lo) {
  size_t stride = (size_t)gridDim.x * blockDim.x;
  for (size_t i = (size_t)blockIdx.x * blockDim.x + threadIdx.x;
       i < (size_t)N_PAD * KP_NF; i += stride) {
    int row = (int)(i / KP_NF), k = (int)(i % KP_NF);
    float v = (row < N_NODES && k < IN_DIM) ? nf[(size_t)row * IN_DIM + k] : 0.f;
    unsigned short h, l; splitf(v, h, l);
    hi[i] = h; lo[i] = l;
  }
}

// ---------------- split + pad all weights into one packed pair ----------------
// layout: [0,17920) Wemb [112][160]; then 4x wpool [112][128]; 4x wnode1; 4x wnode2
#define WEMB_OFF   0
#define WPOOL_OFF  17920
#define WNODE1_OFF (17920 + 4*14336)
#define WNODE2_OFF (17920 + 8*14336)
#define W_TOTAL    (17920 + 12*14336)

__global__ void k_split_w(const float* __restrict__ W_emb, const float* __restrict__ W_pool,
                          const float* __restrict__ W_node,
                          unsigned short* __restrict__ hi, unsigned short* __restrict__ lo) {
  size_t stride = (size_t)gridDim.x * blockDim.x;
  for (size_t i = (size_t)blockIdx.x * blockDim.x + threadIdx.x; i < W_TOTAL; i += stride) {
    float v = 0.f;
    if (i < WPOOL_OFF) {
      int r = (int)(i / KP_NF), k = (int)(i % KP_NF);
      if (r < D && k < IN_DIM) v = W_emb[(size_t)r * IN_DIM + k];
    } else {
      size_t i2 = i - WPOOL_OFF;
      int seg = (int)(i2 / (4 * 14336));
      size_t r2 = i2 % (4 * 14336);
      int l = (int)(r2 / 14336);
      int n = (int)((r2 % 14336) / KP_H);
      int k = (int)(r2 % KP_H);
      if (n < D && k < D) {
        if (seg == 0)      v = W_pool[(size_t)l * D * D + (size_t)n * D + k];
        else if (seg == 1) v = W_node[(size_t)l * D * 2 * D + (size_t)n * 2 * D + k];
        else               v = W_node[(size_t)l * D * 2 * D + (size_t)n * 2 * D + D + k];
      }
    }
    unsigned short h, l2; splitf(v, h, l2);
    hi[i] = h; lo[i] = l2;
  }
}

// ---------------- zero pad rows/cols of h hi/lo ----------------
__global__ void k_padinit(unsigned short* __restrict__ hHi, unsigned short* __restrict__ hLo) {
  size_t stride = (size_t)gridDim.x * blockDim.x;
  for (size_t i = (size_t)blockIdx.x * blockDim.x + threadIdx.x;
       i < (size_t)N_PAD * KP_H; i += stride) {
    int row = (int)(i >> 7), col = (int)(i & 127);
    if (col >= D || row >= N_NODES) { hHi[i] = 0; hLo[i] = 0; }
  }
}

// ---------------- MFMA split-bf16 GEMM with LDS-staged W, R=3 ----------------
// grid 522, block 256 (4 waves), M-tile 192 (48 rows/wave), n-tile 112 (7x16)
// modes: 0 = embed (split out), 1 = pool (fp16 out + relu, PSTRIDE), 2 = node (fused norm/res)
#define WS_STRIDE 72
__global__ __launch_bounds__(256)
void k_mm(const unsigned short* A1h, const unsigned short* A1l, int lda1, int K1,
          const unsigned short* __restrict__ W1h, const unsigned short* __restrict__ W1l, int ldw1,
          const unsigned short* A2h, const unsigned short* A2l, int lda2, int K2,
          const unsigned short* __restrict__ W2h, const unsigned short* __restrict__ W2l, int ldw2,
          const float* __restrict__ bias, int mode,
          __half* __restrict__ outH,
          unsigned short* hHi, unsigned short* hLo,
          const float* __restrict__ snorm)
{
  __shared__ unsigned short WsH[112 * WS_STRIDE];
  __shared__ unsigned short WsL[112 * WS_STRIDE];

  const int t = threadIdx.x;
  const int lane = t & 63;
  const int wv = t >> 6;
  const int r15 = lane & 15;
  const int q = lane >> 4;
  const int m0 = blockIdx.x * MTILE + wv * 48;

  f32x4 acc[3][7];
#pragma unroll
  for (int i = 0; i < 3; i++)
#pragma unroll
    for (int j = 0; j < 7; j++) acc[i][j] = f32x4{0.f, 0.f, 0.f, 0.f};

  auto do_seg = [&](const unsigned short* Ah, const unsigned short* Al, int lda, int K,
                    const unsigned short* Wh, const unsigned short* Wl, int ldw) {
    for (int k0 = 0; k0 < K; k0 += 64) {
      const int klen = (K - k0 >= 64) ? 64 : (K - k0);
      const int ns = klen >> 5;
      __syncthreads();   // previous chunk's LDS reads done
      if (klen == 64) {
        for (int u = t; u < 896; u += 256) {
          int row = u >> 3, kq = u & 7;
          *(uint4*)&WsH[row * WS_STRIDE + kq * 8] =
              *(const uint4*)&Wh[(size_t)row * ldw + k0 + kq * 8];
          *(uint4*)&WsL[row * WS_STRIDE + kq * 8] =
              *(const uint4*)&Wl[(size_t)row * ldw + k0 + kq * 8];
        }
      } else { // 32
        for (int u = t; u < 448; u += 256) {
          int row = u >> 2, kq = u & 3;
          *(uint4*)&WsH[row * WS_STRIDE + kq * 8] =
              *(const uint4*)&Wh[(size_t)row * ldw + k0 + kq * 8];
          *(uint4*)&WsL[row * WS_STRIDE + kq * 8] =
              *(const uint4*)&Wl[(size_t)row * ldw + k0 + kq * 8];
        }
      }
      // prefetch A fragments for s=0 only (24 VGPR) — overlaps W staging
      bf16x8 pa_h[3], pa_l[3];
#pragma unroll
      for (int m = 0; m < 3; m++) {
        size_t base = (size_t)(m0 + m * 16 + r15) * lda + k0 + q * 8;
        pa_h[m] = *(const bf16x8*)&Ah[base];
        pa_l[m] = *(const bf16x8*)&Al[base];
      }
      __syncthreads();   // staged W visible
      // s = 0
#pragma unroll
      for (int n = 0; n < 7; n++) {
        int wrow = n * 16 + r15;
        const bf16x8 bh = *(const bf16x8*)&WsH[wrow * WS_STRIDE + q * 8];
        const bf16x8 bl = *(const bf16x8*)&WsL[wrow * WS_STRIDE + q * 8];
#pragma unroll
        for (int m = 0; m < 3; m++) {
          acc[m][n] = __builtin_amdgcn_mfma_f32_16x16x32_bf16(pa_h[m], bh, acc[m][n], 0, 0, 0);
          acc[m][n] = __builtin_amdgcn_mfma_f32_16x16x32_bf16(pa_h[m], bl, acc[m][n], 0, 0, 0);
          acc[m][n] = __builtin_amdgcn_mfma_f32_16x16x32_bf16(pa_l[m], bh, acc[m][n], 0, 0, 0);
        }
      }
      if (ns == 2) {
        // s = 1: reuse prefetch registers
#pragma unroll
        for (int m = 0; m < 3; m++) {
          size_t base = (size_t)(m0 + m * 16 + r15) * lda + k0 + 32 + q * 8;
          pa_h[m] = *(const bf16x8*)&Ah[base];
          pa_l[m] = *(const bf16x8*)&Al[base];
        }
#pragma unroll
        for (int n = 0; n < 7; n++) {
          int wrow = n * 16 + r15;
          const bf16x8 bh = *(const bf16x8*)&WsH[wrow * WS_STRIDE + 32 + q * 8];
          const bf16x8 bl = *(const bf16x8*)&WsL[wrow * WS_STRIDE + 32 + q * 8];
#pragma unroll
          for (int m = 0; m < 3; m++) {
            acc[m][n] = __builtin_amdgcn_mfma_f32_16x16x32_bf16(pa_h[m], bh, acc[m][n], 0, 0, 0);
            acc[m][n] = __builtin_amdgcn_mfma_f32_16x16x32_bf16(pa_h[m], bl, acc[m][n], 0, 0, 0);
            acc[m][n] = __builtin_amdgcn_mfma_f32_16x16x32_bf16(pa_l[m], bh, acc[m][n], 0, 0, 0);
          }
        }
      }
    }
  };

  do_seg(A1h, A1l, lda1, K1, W1h, W1l, ldw1);
  if (A2h) do_seg(A2h, A2l, lda2, K2, W2h, W2l, ldw2);

  // ---------------- epilogue ----------------
#pragma unroll
  for (int ms = 0; ms < 3; ++ms) {
    if (mode == 2) {
      // fused: v = acc+bias; L2-normalize row; relu; *snorm; h += v
      float ss[4] = {0.f, 0.f, 0.f, 0.f};
#pragma unroll
      for (int n = 0; n < 7; n++) {
        int col = n * 16 + r15;
        if (col < D) {
          float bv = bias[col];
#pragma unroll
          for (int r = 0; r < 4; r++) {
            float v = acc[ms][n][r] + bv;
            ss[r] += v * v;
          }
        }
      }
#pragma unroll
      for (int m_ = 1; m_ <= 8; m_ <<= 1) {
#pragma unroll
        for (int r = 0; r < 4; r++) ss[r] += __shfl_xor(ss[r], m_, 64);
      }
      float inv[4], sn[4]; int rows[4];
#pragma unroll
      for (int r = 0; r < 4; r++) {
        rows[r] = m0 + ms * 16 + q * 4 + r;
        float dn = fmaxf(sqrtf(ss[r]), 1e-12f);
        inv[r] = 1.0f / dn;
        sn[r] = (rows[r] < N_NODES) ? snorm[rows[r]] : 0.f;
      }
#pragma unroll
      for (int n = 0; n < 7; n++) {
        int col = n * 16 + r15;
        if (col >= D) continue;
        float bv = bias[col];
#pragma unroll
        for (int r = 0; r < 4; r++) {
          if (rows[r] >= N_NODES) continue;
          size_t idx = (size_t)rows[r] * KP_H + col;
          float hold = bf_bits2f(hHi[idx]) + bf_bits2f(hLo[idx]);
          float v = acc[ms][n][r] + bv;
          float x = fmaxf(v * inv[r], 0.f) * sn[r];
          float nh = hold + x;
          unsigned short h_, l_; splitf(nh, h_, l_);
          hHi[idx] = h_; hLo[idx] = l_;
        }
      }
    } else {
#pragma unroll
      for (int n = 0; n < 7; n++) {
        int col = n * 16 + r15;
        if (col >= D) continue;
        float bv = bias[col];
#pragma unroll
        for (int r = 0; r < 4; r++) {
          int row = m0 + ms * 16 + q * 4 + r;
          if (row >= N_NODES) continue;
          float v = acc[ms][n][r] + bv;
          if (mode == 1) {
            outH[(size_t)row * PSTRIDE + col] = __float2half_rn(fmaxf(v, 0.f));
          } else {
            unsigned short h_, l_; splitf(v, h_, l_);
            hHi[(size_t)row * KP_H + col] = h_;
            hLo[(size_t)row * KP_H + col] = l_;
          }
        }
      }
    }
  }
}

// ---------------- pull aggregation: one wave/node, 8 edges in flight ----------
// lane = (g, lp): g = edge slot (0..3), lp = 16B segment of the 256B row.
// 2x outer unroll: two independent dwordx4 gathers per iteration.
__global__ __launch_bounds__(256)
void k_aggregate(const __half* __restrict__ pooled, const int* __restrict__ offsets,
                 const int* __restrict__ esrc,
                 unsigned int* __restrict__ aggHi, unsigned int* __restrict__ aggLo)
{
  int t = threadIdx.x;
  int lane = t & 63;
  int g = lane >> 4;
  int lp = lane & 15;
  int v = blockIdx.x * 4 + (t >> 6);
  if (v >= N_PAD) return;
  float va[8];
#pragma unroll
  for (int j = 0; j < 8; j++) va[j] = 0.f;
  int s0 = 0, s1 = 0;
  if (v < N_NODES) { s0 = offsets[v]; s1 = offsets[v + 1]; }
  const uint4* P = (const uint4*)pooled;   // row = 16 uint4 (256B)
  int e = s0;
  for (; e + 7 < s1; e += 8) {
    int sa0 = esrc[e + g];
    int sa1 = esrc[e + 4 + g];
    uint4 u0 = P[(size_t)sa0 * 16 + lp];
    uint4 u1 = P[(size_t)sa1 * 16 + lp];
    float2 a0 = __half22float2(__builtin_bit_cast(__half2, u0.x));
    float2 a1 = __half22float2(__builtin_bit_cast(__half2, u0.y));
    float2 a2 = __half22float2(__builtin_bit_cast(__half2, u0.z));
    float2 a3 = __half22float2(__builtin_bit_cast(__half2, u0.w));
    va[0] += a0.x; va[1] += a0.y; va[2] += a1.x; va[3] += a1.y;
    va[4] += a2.x; va[5] += a2.y; va[6] += a3.x; va[7] += a3.y;
    float2 b0 = __half22float2(__builtin_bit_cast(__half2, u1.x));
    float2 b1 = __half22float2(__builtin_bit_cast(__half2, u1.y));
    float2 b2 = __half22float2(__builtin_bit_cast(__half2, u1.z));
    float2 b3 = __half22float2(__builtin_bit_cast(__half2, u1.w));
    va[0] += b0.x; va[1] += b0.y; va[2] += b1.x; va[3] += b1.y;
    va[4] += b2.x; va[5] += b2.y; va[6] += b3.x; va[7] += b3.y;
  }
  for (; e < s1; e += 4) {
    int idx = e + g;
    if (idx < s1) {
      int sa = esrc[idx];
      uint4 u = P[(size_t)sa * 16 + lp];
      float2 f0 = __half22float2(__builtin_bit_cast(__half2, u.x));
      float2 f1 = __half22float2(__builtin_bit_cast(__half2, u.y));
      float2 f2 = __half22float2(__builtin_bit_cast(__half2, u.z));
      float2 f3 = __half22float2(__builtin_bit_cast(__half2, u.w));
      va[0] += f0.x; va[1] += f0.y; va[2] += f1.x; va[3] += f1.y;
      va[4] += f2.x; va[5] += f2.y; va[6] += f3.x; va[7] += f3.y;
    }
  }
  // combine the 4 edge-slot groups (lanes with equal lp)
#pragma unroll
  for (int j = 0; j < 8; j++) {
    va[j] += __shfl_xor(va[j], 16, 64);
    va[j] += __shfl_xor(va[j], 32, 64);
  }
  if (g == 0) {
    int dgi = s1 - s0; if (dgi < 1) dgi = 1;
    float inv = 1.0f / (float)dgi;
    unsigned int hiw[4], low[4];
#pragma unroll
    for (int p = 0; p < 4; p++) {
      unsigned short h0, l0, h1, l1;
      splitf(va[2 * p] * inv, h0, l0);
      splitf(va[2 * p + 1] * inv, h1, l1);
      hiw[p] = (unsigned)h0 | ((unsigned)h1 << 16);
      low[p] = (unsigned)l0 | ((unsigned)l1 << 16);
    }
    *(uint4*)&aggHi[(size_t)v * 64 + lp * 4] = make_uint4(hiw[0], hiw[1], hiw[2], hiw[3]);
    *(uint4*)&aggLo[(size_t)v * 64 + lp * 4] = make_uint4(low[0], low[1], low[2], low[3]);
  }
}

// ---------------- per-graph mean, phase 1: 8 chunks/graph partial sums ----------
__global__ __launch_bounds__(256)
void k_gm_part(const unsigned short* __restrict__ hHi, const unsigned short* __restrict__ hLo,
               const int* __restrict__ gid, float* __restrict__ hgpart) {
  int g = blockIdx.x >> 3;
  int j = blockIdx.x & 7;
  int t = threadIdx.x;
  int c = t & 127, rp = t >> 7;
  // bounds of graph g (all threads redundantly)
  int lo = 0, hi = N_NODES;
  while (lo < hi) { int m = (lo + hi) >> 1; if (gid[m] < g) lo = m + 1; else hi = m; }
  int s = lo;
  hi = N_NODES;
  while (lo < hi) { int m = (lo + hi) >> 1; if (gid[m] < g + 1) lo = m + 1; else hi = m; }
  int e = lo;
  int per = ((e - s) + 7) >> 3;
  int vs = s + j * per;
  int ve = vs + per; if (ve > e) ve = e;
  float acc = 0.f;
  if (c < D) {
    for (int v = vs + rp; v < ve; v += 2) {
      size_t idx = (size_t)v * KP_H + c;
      acc += bf_bits2f(hHi[idx]) + bf_bits2f(hLo[idx]);
    }
  }
  __shared__ float part[2][128];
  part[rp][c] = acc;
  __syncthreads();
  if (rp == 0 && c < D)
    hgpart[(size_t)blockIdx.x * D + c] = part[0][c] + part[1][c];
}

// ---------------- per-graph mean, phase 2: reduce 8 chunks + divide ------------
__global__ __launch_bounds__(128)
void k_gm_fin(const float* __restrict__ hgpart, const int* __restrict__ gid,
              float* __restrict__ hg) {
  int g = blockIdx.x;
  int t = threadIdx.x;
  int lo = 0, hi = N_NODES;
  while (lo < hi) { int m = (lo + hi) >> 1; if (gid[m] < g) lo = m + 1; else hi = m; }
  int s = lo;
  hi = N_NODES;
  while (lo < hi) { int m = (lo + hi) >> 1; if (gid[m] < g + 1) lo = m + 1; else hi = m; }
  int cnt = lo - s; if (cnt < 1) cnt = 1;
  if (t < D) {
    float sum = 0.f;
#pragma unroll
    for (int j = 0; j < 8; j++) sum += hgpart[(size_t)(g * 8 + j) * D + t];
    hg[g * D + t] = sum / (float)cnt;
  }
}

// ---------------- MLP readout ----------------
__global__ __launch_bounds__(64)
void k_readout(const float* __restrict__ hg,
               const float* __restrict__ Wr0, const float* __restrict__ br0,
               const float* __restrict__ Wr1, const float* __restrict__ br1,
               const float* __restrict__ Wr2, const float* __restrict__ br2,
               float* __restrict__ out) {
  int g = blockIdx.x;
  int t = threadIdx.x;
  __shared__ float x0[D];
  __shared__ float x1[54];
  __shared__ float x2[27];
  for (int i = t; i < D; i += 64) x0[i] = hg[g * D + i];
  __syncthreads();
  if (t < 54) {
    float v = br0[t];
    for (int k = 0; k < D; k++) v += x0[k] * Wr0[t * D + k];
    x1[t] = fmaxf(v, 0.f);
  }
  __syncthreads();
  if (t < 27) {
    float v = br1[t];
    for (int k = 0; k < 54; k++) v += x1[k] * Wr1[t * 54 + k];
    x2[t] = fmaxf(v, 0.f);
  }
  __syncthreads();
  if (t < 10) {
    float v = br2[t];
    for (int k = 0; k < 27; k++) v += x2[k] * Wr2[t * 27 + k];
    out[g * 10 + t] = v;
  }
}

extern "C" void kernel_launch(void* const* d_in, const int* in_sizes, int n_in,
                              void* d_out, int out_size, void* d_ws, size_t ws_size,
                              hipStream_t stream) {
  const float* nodes_feat = (const float*)d_in[0];
  const float* snorm_n    = (const float*)d_in[1];
  const int*   src        = (const int*)d_in[2];
  const int*   dst        = (const int*)d_in[3];
  const int*   gid        = (const int*)d_in[4];
  const float* W_emb      = (const float*)d_in[6];
  const float* b_emb      = (const float*)d_in[7];
  const float* W_pool     = (const float*)d_in[8];
  const float* b_pool     = (const float*)d_in[9];
  const float* W_node     = (const float*)d_in[10];
  const float* b_node     = (const float*)d_in[11];
  const float* W_r0       = (const float*)d_in[12];
  const float* b_r0       = (const float*)d_in[13];
  const float* W_r1       = (const float*)d_in[14];
  const float* b_r1       = (const float*)d_in[15];
  const float* W_r2       = (const float*)d_in[16];
  const float* b_r2       = (const float*)d_in[17];
  float* out = (float*)d_out;

  char* ws = (char*)d_ws;
  size_t off = 0;
  auto alloc = [&](size_t bytes) { size_t o = off; off = (off + bytes + 255) & ~(size_t)255; return o; };

  __half* buf1 = (__half*)(ws + alloc((size_t)N_NODES * PSTRIDE * 2));  // pooled (fp16, padded)
  unsigned short* h_hi = (unsigned short*)(ws + alloc((size_t)N_PAD * KP_H * 2));
  unsigned short* h_lo = (unsigned short*)(ws + alloc((size_t)N_PAD * KP_H * 2));
  // nf (pair, [N_PAD][160]) aliased with agg (pair, [N_PAD][128]) — disjoint lifetimes
  char* nfagg = ws + alloc((size_t)N_PAD * KP_NF * 2 * 2);
  unsigned short* nf_hi = (unsigned short*)nfagg;
  unsigned short* nf_lo = (unsigned short*)(nfagg + (size_t)N_PAD * KP_NF * 2);
  unsigned short* agg_hi = (unsigned short*)nfagg;
  unsigned short* agg_lo = (unsigned short*)(nfagg + (size_t)N_PAD * KP_H * 2);
  uint2* ebin = (uint2*)(ws + alloc((size_t)N_EDGES * 8));
  int* esrc  = (int*)(ws + alloc((size_t)N_EDGES * 4));
  int* offs  = (int*)(ws + alloc((size_t)(N_NODES + 1) * 4));
  int* bhist = (int*)(ws + alloc((size_t)(NBUCKET + 1) * 4));
  int* boffs = (int*)(ws + alloc((size_t)(NBUCKET + 1) * 4));
  int* bcur  = (int*)(ws + alloc((size_t)(NBUCKET + 1) * 4));
  unsigned short* wHi = (unsigned short*)(ws + alloc((size_t)W_TOTAL * 2));
  unsigned short* wLo = (unsigned short*)(ws + alloc((size_t)W_TOTAL * 2));
  float* hgpart = (float*)(ws + alloc((size_t)N_GRAPHS * 8 * D * 4));
  float* hg = (float*)(ws + alloc((size_t)N_GRAPHS * D * 4));
  (void)ws_size; (void)n_in; (void)in_sizes; (void)out_size;

  hipMemsetAsync(bhist, 0, (size_t)NBUCKET * 4, stream);

  // splits + pad init
  k_split_w<<<(W_TOTAL + 255) / 256, 256, 0, stream>>>(W_emb, W_pool, W_node, wHi, wLo);
  k_split_nf<<<4096, 256, 0, stream>>>(nodes_feat, nf_hi, nf_lo);
  k_padinit<<<8192, 256, 0, stream>>>(h_hi, h_lo);

  // CSR build via bucket counting sort (writes offs + esrc)
  const int EB = (N_EDGES + 2047) / 2048;  // 782
  k_bhist<<<EB, 256, 0, stream>>>(dst, bhist);
  k_bscan<<<1, 512, 0, stream>>>(bhist, boffs, bcur, offs);
  k_binscatter<<<EB, 256, 0, stream>>>(src, dst, bcur, ebin);
  k_scatter2<<<NBUCKET, 256, 0, stream>>>(ebin, boffs, offs, esrc);

  const int GEMM_GRID = N_PAD / MTILE;  // 522
  // embedding: h = nodes_feat @ W_emb^T + b_emb  (uses nf region before agg aliases it)
  k_mm<<<GEMM_GRID, 256, 0, stream>>>(nf_hi, nf_lo, KP_NF, KP_NF,
                                      wHi + WEMB_OFF, wLo + WEMB_OFF, KP_NF,
                                      nullptr, nullptr, 0, 0, nullptr, nullptr, 0,
                                      b_emb, 0, nullptr, h_hi, h_lo, nullptr);

  for (int l = 0; l < 4; l++) {
    const unsigned short* wpH = wHi + WPOOL_OFF + (size_t)l * 14336;
    const unsigned short* wpL = wLo + WPOOL_OFF + (size_t)l * 14336;
    const unsigned short* wn1H = wHi + WNODE1_OFF + (size_t)l * 14336;
    const unsigned short* wn1L = wLo + WNODE1_OFF + (size_t)l * 14336;
    const unsigned short* wn2H = wHi + WNODE2_OFF + (size_t)l * 14336;
    const unsigned short* wn2L = wLo + WNODE2_OFF + (size_t)l * 14336;
    const float* bp = b_pool + (size_t)l * D;
    const float* bn = b_node + (size_t)l * D;

    // pooled = relu(h @ Wp^T + bp)  (fp16 out, padded stride)
    k_mm<<<GEMM_GRID, 256, 0, stream>>>(h_hi, h_lo, KP_H, KP_H,
                                        wpH, wpL, KP_H,
                                        nullptr, nullptr, 0, 0, nullptr, nullptr, 0,
                                        bp, 1, buf1, nullptr, nullptr, nullptr);
    // agg = mean_in(pooled)
    k_aggregate<<<N_PAD / 4, 256, 0, stream>>>(buf1, offs, esrc,
                                               (unsigned int*)agg_hi, (unsigned int*)agg_lo);
    // h += relu(normalize(h@Wn1^T + agg@Wn2^T + bn)) * snorm   (fused)
    k_mm<<<GEMM_GRID, 256, 0, stream>>>(h_hi, h_lo, KP_H, KP_H,
                                        wn1H, wn1L, KP_H,
                                        agg_hi, agg_lo, KP_H, KP_H,
                                        wn2H, wn2L, KP_H,
                                        bn, 2, nullptr, h_hi, h_lo, snorm_n);
  }

  k_gm_part<<<N_GRAPHS * 8, 256, 0, stream>>>(h_hi, h_lo, gid, hgpart);
  k_gm_fin<<<N_GRAPHS, 128, 0, stream>>>(hgpart, gid, hg);
  k_readout<<<N_GRAPHS, 64, 0, stream>>>(hg, W_r0, b_r0, W_r1, b_r1, W_r2, b_r2, out);
}

// Round 12
// 807.702 us; speedup vs baseline: 1.1215x; 1.1215x over previous
//
#include <hip/hip_runtime.h>
#include <hip/hip_bf16.h>
#include <hip/hip_fp16.h>

#define N_NODES  100000
#define N_PAD    100096
#define N_EDGES  1600000
#define N_GRAPHS 128
#define D        108
#define IN_DIM   146
#define KP_H     128
#define KP_NF    160
#define PSTRIDE  128      // pooled row stride in halves (256B, line-aligned)
#define NBUCKET  391      // ceil(N_NODES/256)
#define LBUF     8192     // per-bucket LDS scatter buffer (max bucket edges ~4400)

typedef __bf16 bf16x8 __attribute__((ext_vector_type(8)));
typedef float  f32x4  __attribute__((ext_vector_type(4)));

__device__ __forceinline__ unsigned short f2bf_bits(float v) {
  __hip_bfloat16 b = __float2bfloat16(v);
  return __builtin_bit_cast(unsigned short, b);
}
__device__ __forceinline__ float bf_bits2f(unsigned short u) {
  __hip_bfloat16 b = __builtin_bit_cast(__hip_bfloat16, u);
  return __bfloat162float(b);
}
__device__ __forceinline__ void splitf(float v, unsigned short& hi, unsigned short& lo) {
  hi = f2bf_bits(v);
  lo = f2bf_bits(v - bf_bits2f(hi));
}

// ---------------- bucket histogram (LDS-batched) ----------------
__global__ __launch_bounds__(256)
void k_bhist(const int* __restrict__ dst, int* __restrict__ bhist) {
  __shared__ int bh[NBUCKET];
  int t = threadIdx.x;
  for (int i = t; i < NBUCKET; i += 256) bh[i] = 0;
  __syncthreads();
  int e0 = blockIdx.x * 2048;
#pragma unroll
  for (int j = 0; j < 8; j++) {
    int e = e0 + j * 256 + t;
    if (e < N_EDGES) atomicAdd(&bh[dst[e] >> 8], 1);
  }
  __syncthreads();
  for (int i = t; i < NBUCKET; i += 256)
    if (bh[i]) atomicAdd(&bhist[i], bh[i]);
}

// ---------------- bucket scan (one block) ----------------
__global__ __launch_bounds__(512)
void k_bscan(const int* __restrict__ bhist, int* __restrict__ boffs,
             int* __restrict__ bcur, int* __restrict__ offs) {
  __shared__ int sh[512];
  int t = threadIdx.x;
  sh[t] = (t < NBUCKET) ? bhist[t] : 0;
  __syncthreads();
  for (int off = 1; off < 512; off <<= 1) {
    int v = (t >= off) ? sh[t - off] : 0;
    __syncthreads();
    sh[t] += v;
    __syncthreads();
  }
  if (t < NBUCKET) {
    int excl = (t > 0) ? sh[t - 1] : 0;
    boffs[t] = excl;
    bcur[t]  = excl;
  }
  if (t == 0) { boffs[NBUCKET] = N_EDGES; offs[N_NODES] = N_EDGES; }
}

// ---------------- bin edges into bucket-contiguous ebin (LDS-batched ranks) ----
__global__ __launch_bounds__(256)
void k_binscatter(const int* __restrict__ src, const int* __restrict__ dst,
                  int* __restrict__ bcur, uint2* __restrict__ ebin) {
  __shared__ int lhist[NBUCKET];
  __shared__ int lbase[NBUCKET];
  int t = threadIdx.x;
  for (int i = t; i < NBUCKET; i += 256) lhist[i] = 0;
  __syncthreads();
  int e0 = blockIdx.x * 2048;
  int s[8], d[8], r[8];
#pragma unroll
  for (int j = 0; j < 8; j++) {
    int e = e0 + j * 256 + t;
    if (e < N_EDGES) {
      s[j] = src[e]; d[j] = dst[e];
      r[j] = atomicAdd(&lhist[d[j] >> 8], 1);
    }
  }
  __syncthreads();
  for (int i = t; i < NBUCKET; i += 256)
    lbase[i] = lhist[i] ? atomicAdd(&bcur[i], lhist[i]) : 0;
  __syncthreads();
#pragma unroll
  for (int j = 0; j < 8; j++) {
    int e = e0 + j * 256 + t;
    if (e < N_EDGES)
      ebin[(size_t)lbase[d[j] >> 8] + r[j]] = make_uint2((unsigned)s[j], (unsigned)d[j]);
  }
}

// ---------------- per-bucket local CSR: writes offs + coalesced esrc ----------
__global__ __launch_bounds__(256)
void k_scatter2(const uint2* __restrict__ ebin, const int* __restrict__ boffs,
                int* __restrict__ offs, int* __restrict__ esrc) {
  __shared__ int lcnt[256];
  __shared__ int lcur[256];
  __shared__ int lbuf[LBUF];
  int b = blockIdx.x;
  int t = threadIdx.x;
  int vbase = b << 8;
  int estart = boffs[b], eend = boffs[b + 1];
  int cnt = eend - estart;
  lcnt[t] = 0;
  __syncthreads();
  for (int e = estart + t; e < eend; e += 256)
    atomicAdd(&lcnt[ebin[e].y & 255], 1);
  __syncthreads();
  // inclusive scan of lcnt (in-place Hillis-Steele)
  for (int off = 1; off < 256; off <<= 1) {
    int v = (t >= off) ? lcnt[t - off] : 0;
    __syncthreads();
    lcnt[t] += v;
    __syncthreads();
  }
  int excl = (t > 0) ? lcnt[t - 1] : 0;
  int v = vbase + t;
  if (v < N_NODES) offs[v] = estart + excl;
  lcur[t] = excl;
  __syncthreads();
  if (cnt <= LBUF) {
    for (int e = estart + t; e < eend; e += 256) {
      uint2 u = ebin[e];
      int pos = atomicAdd(&lcur[u.y & 255], 1);
      lbuf[pos] = (int)u.x;
    }
    __syncthreads();
    for (int i = t; i < cnt; i += 256) esrc[estart + i] = lbuf[i];
  } else {   // safety fallback (statistically unreachable)
    for (int e = estart + t; e < eend; e += 256) {
      uint2 u = ebin[e];
      int pos = atomicAdd(&lcur[u.y & 255], 1);
      esrc[estart + pos] = (int)u.x;
    }
  }
}

// ---------------- split nodes_feat into padded bf16 hi/lo ----------------
__global__ void k_split_nf(const float* __restrict__ nf,
                           unsigned short* __restrict__ hi, unsigned short* __restrict__ lo) {
  size_t stride = (size_t)gridDim.x * blockDim.x;
  for (size_t i = (size_t)blockIdx.x * blockDim.x + threadIdx.x;
       i < (size_t)N_PAD * KP_NF; i += stride) {
    int row = (int)(i / KP_NF), k = (int)(i % KP_NF);
    float v = (row < N_NODES && k < IN_DIM) ? nf[(size_t)row * IN_DIM + k] : 0.f;
    unsigned short h, l; splitf(v, h, l);
    hi[i] = h; lo[i] = l;
  }
}

// ---------------- split + pad all weights into one packed pair ----------------
// layout: [0,17920) Wemb [112][160]; then 4x wpool [112][128]; 4x wnode1; 4x wnode2
#define WEMB_OFF   0
#define WPOOL_OFF  17920
#define WNODE1_OFF (17920 + 4*14336)
#define WNODE2_OFF (17920 + 8*14336)
#define W_TOTAL    (17920 + 12*14336)

__global__ void k_split_w(const float* __restrict__ W_emb, const float* __restrict__ W_pool,
                          const float* __restrict__ W_node,
                          unsigned short* __restrict__ hi, unsigned short* __restrict__ lo) {
  size_t stride = (size_t)gridDim.x * blockDim.x;
  for (size_t i = (size_t)blockIdx.x * blockDim.x + threadIdx.x; i < W_TOTAL; i += stride) {
    float v = 0.f;
    if (i < WPOOL_OFF) {
      int r = (int)(i / KP_NF), k = (int)(i % KP_NF);
      if (r < D && k < IN_DIM) v = W_emb[(size_t)r * IN_DIM + k];
    } else {
      size_t i2 = i - WPOOL_OFF;
      int seg = (int)(i2 / (4 * 14336));
      size_t r2 = i2 % (4 * 14336);
      int l = (int)(r2 / 14336);
      int n = (int)((r2 % 14336) / KP_H);
      int k = (int)(r2 % KP_H);
      if (n < D && k < D) {
        if (seg == 0)      v = W_pool[(size_t)l * D * D + (size_t)n * D + k];
        else if (seg == 1) v = W_node[(size_t)l * D * 2 * D + (size_t)n * 2 * D + k];
        else               v = W_node[(size_t)l * D * 2 * D + (size_t)n * 2 * D + D + k];
      }
    }
    unsigned short h, l2; splitf(v, h, l2);
    hi[i] = h; lo[i] = l2;
  }
}

// ---------------- zero pad rows/cols of h hi/lo ----------------
__global__ void k_padinit(unsigned short* __restrict__ hHi, unsigned short* __restrict__ hLo) {
  size_t stride = (size_t)gridDim.x * blockDim.x;
  for (size_t i = (size_t)blockIdx.x * blockDim.x + threadIdx.x;
       i < (size_t)N_PAD * KP_H; i += stride) {
    int row = (int)(i >> 7), col = (int)(i & 127);
    if (col >= D || row >= N_NODES) { hHi[i] = 0; hLo[i] = 0; }
  }
}

// ---------------- MFMA split-bf16 GEMM with LDS-staged W, R=2 (proven) ----------
// grid 782, block 256 (4 waves), M-tile 128 (32 rows/wave), n-tile 112 (7x16)
// modes: 0 = embed (split out), 1 = pool (fp16 out + relu, PSTRIDE), 2 = node (fused norm/res)
#define WS_STRIDE 72
__global__ __launch_bounds__(256)
void k_mm(const unsigned short* A1h, const unsigned short* A1l, int lda1, int K1,
          const unsigned short* __restrict__ W1h, const unsigned short* __restrict__ W1l, int ldw1,
          const unsigned short* A2h, const unsigned short* A2l, int lda2, int K2,
          const unsigned short* __restrict__ W2h, const unsigned short* __restrict__ W2l, int ldw2,
          const float* __restrict__ bias, int mode,
          __half* __restrict__ outH,
          unsigned short* hHi, unsigned short* hLo,
          const float* __restrict__ snorm)
{
  __shared__ unsigned short WsH[112 * WS_STRIDE];
  __shared__ unsigned short WsL[112 * WS_STRIDE];

  const int t = threadIdx.x;
  const int lane = t & 63;
  const int wv = t >> 6;
  const int r15 = lane & 15;
  const int q = lane >> 4;
  const int m0 = blockIdx.x * 128 + wv * 32;

  f32x4 acc[2][7];
#pragma unroll
  for (int i = 0; i < 2; i++)
#pragma unroll
    for (int j = 0; j < 7; j++) acc[i][j] = f32x4{0.f, 0.f, 0.f, 0.f};

  auto do_seg = [&](const unsigned short* Ah, const unsigned short* Al, int lda, int K,
                    const unsigned short* Wh, const unsigned short* Wl, int ldw) {
    for (int k0 = 0; k0 < K; k0 += 64) {
      const int klen = (K - k0 >= 64) ? 64 : (K - k0);
      __syncthreads();   // previous chunk's LDS reads done
      if (klen == 64) {
        for (int u = t; u < 896; u += 256) {
          int row = u >> 3, kq = u & 7;
          *(uint4*)&WsH[row * WS_STRIDE + kq * 8] =
              *(const uint4*)&Wh[(size_t)row * ldw + k0 + kq * 8];
          *(uint4*)&WsL[row * WS_STRIDE + kq * 8] =
              *(const uint4*)&Wl[(size_t)row * ldw + k0 + kq * 8];
        }
      } else { // 32
        for (int u = t; u < 448; u += 256) {
          int row = u >> 2, kq = u & 3;
          *(uint4*)&WsH[row * WS_STRIDE + kq * 8] =
              *(const uint4*)&Wh[(size_t)row * ldw + k0 + kq * 8];
          *(uint4*)&WsL[row * WS_STRIDE + kq * 8] =
              *(const uint4*)&Wl[(size_t)row * ldw + k0 + kq * 8];
        }
      }
      // issue A loads for this chunk while staging completes
      bf16x8 a_h[2][2], a_l[2][2];
      const int ns = klen >> 5;
#pragma unroll
      for (int s = 0; s < 2; s++) {
        if (s < ns) {
          size_t base0 = (size_t)(m0 + r15) * lda + k0 + s * 32 + q * 8;
          size_t base1 = base0 + (size_t)16 * lda;
          a_h[s][0] = *(const bf16x8*)&Ah[base0];
          a_l[s][0] = *(const bf16x8*)&Al[base0];
          a_h[s][1] = *(const bf16x8*)&Ah[base1];
          a_l[s][1] = *(const bf16x8*)&Al[base1];
        }
      }
      __syncthreads();   // staged W visible
#pragma unroll
      for (int s = 0; s < 2; s++) {
        if (s < ns) {
#pragma unroll
          for (int n = 0; n < 7; n++) {
            int wrow = n * 16 + r15;
            const bf16x8 bh = *(const bf16x8*)&WsH[wrow * WS_STRIDE + s * 32 + q * 8];
            const bf16x8 bl = *(const bf16x8*)&WsL[wrow * WS_STRIDE + s * 32 + q * 8];
            acc[0][n] = __builtin_amdgcn_mfma_f32_16x16x32_bf16(a_h[s][0], bh, acc[0][n], 0, 0, 0);
            acc[0][n] = __builtin_amdgcn_mfma_f32_16x16x32_bf16(a_h[s][0], bl, acc[0][n], 0, 0, 0);
            acc[0][n] = __builtin_amdgcn_mfma_f32_16x16x32_bf16(a_l[s][0], bh, acc[0][n], 0, 0, 0);
            acc[1][n] = __builtin_amdgcn_mfma_f32_16x16x32_bf16(a_h[s][1], bh, acc[1][n], 0, 0, 0);
            acc[1][n] = __builtin_amdgcn_mfma_f32_16x16x32_bf16(a_h[s][1], bl, acc[1][n], 0, 0, 0);
            acc[1][n] = __builtin_amdgcn_mfma_f32_16x16x32_bf16(a_l[s][1], bh, acc[1][n], 0, 0, 0);
          }
        }
      }
    }
  };

  do_seg(A1h, A1l, lda1, K1, W1h, W1l, ldw1);
  if (A2h) do_seg(A2h, A2l, lda2, K2, W2h, W2l, ldw2);

  // ---------------- epilogue ----------------
#pragma unroll
  for (int ms = 0; ms < 2; ++ms) {
    if (mode == 2) {
      // fused: v = acc+bias; L2-normalize row; relu; *snorm; h += v
      float ss[4] = {0.f, 0.f, 0.f, 0.f};
#pragma unroll
      for (int n = 0; n < 7; n++) {
        int col = n * 16 + r15;
        if (col < D) {
          float bv = bias[col];
#pragma unroll
          for (int r = 0; r < 4; r++) {
            float v = acc[ms][n][r] + bv;
            ss[r] += v * v;
          }
        }
      }
#pragma unroll
      for (int m_ = 1; m_ <= 8; m_ <<= 1) {
#pragma unroll
        for (int r = 0; r < 4; r++) ss[r] += __shfl_xor(ss[r], m_, 64);
      }
      float inv[4], sn[4]; int rows[4];
#pragma unroll
      for (int r = 0; r < 4; r++) {
        rows[r] = m0 + ms * 16 + q * 4 + r;
        float dn = fmaxf(sqrtf(ss[r]), 1e-12f);
        inv[r] = 1.0f / dn;
        sn[r] = (rows[r] < N_NODES) ? snorm[rows[r]] : 0.f;
      }
#pragma unroll
      for (int n = 0; n < 7; n++) {
        int col = n * 16 + r15;
        if (col >= D) continue;
        float bv = bias[col];
#pragma unroll
        for (int r = 0; r < 4; r++) {
          if (rows[r] >= N_NODES) continue;
          size_t idx = (size_t)rows[r] * KP_H + col;
          float hold = bf_bits2f(hHi[idx]) + bf_bits2f(hLo[idx]);
          float v = acc[ms][n][r] + bv;
          float x = fmaxf(v * inv[r], 0.f) * sn[r];
          float nh = hold + x;
          unsigned short h_, l_; splitf(nh, h_, l_);
          hHi[idx] = h_; hLo[idx] = l_;
        }
      }
    } else {
#pragma unroll
      for (int n = 0; n < 7; n++) {
        int col = n * 16 + r15;
        if (col >= D) continue;
        float bv = bias[col];
#pragma unroll
        for (int r = 0; r < 4; r++) {
          int row = m0 + ms * 16 + q * 4 + r;
          if (row >= N_NODES) continue;
          float v = acc[ms][n][r] + bv;
          if (mode == 1) {
            outH[(size_t)row * PSTRIDE + col] = __float2half_rn(fmaxf(v, 0.f));
          } else {
            unsigned short h_, l_; splitf(v, h_, l_);
            hHi[(size_t)row * KP_H + col] = h_;
            hLo[(size_t)row * KP_H + col] = l_;
          }
        }
      }
    }
  }
}

// ---------------- pull aggregation: one wave/node, 8 edges in flight ----------
// lane = (g, lp): g = edge slot (0..3), lp = 16B segment of the 256B row.
// 2x outer unroll: two independent dwordx4 gathers per iteration.
__global__ __launch_bounds__(256)
void k_aggregate(const __half* __restrict__ pooled, const int* __restrict__ offsets,
                 const int* __restrict__ esrc,
                 unsigned int* __restrict__ aggHi, unsigned int* __restrict__ aggLo)
{
  int t = threadIdx.x;
  int lane = t & 63;
  int g = lane >> 4;
  int lp = lane & 15;
  int v = blockIdx.x * 4 + (t >> 6);
  if (v >= N_PAD) return;
  float va[8];
#pragma unroll
  for (int j = 0; j < 8; j++) va[j] = 0.f;
  int s0 = 0, s1 = 0;
  if (v < N_NODES) { s0 = offsets[v]; s1 = offsets[v + 1]; }
  const uint4* P = (const uint4*)pooled;   // row = 16 uint4 (256B)
  int e = s0;
  for (; e + 7 < s1; e += 8) {
    int sa0 = esrc[e + g];
    int sa1 = esrc[e + 4 + g];
    uint4 u0 = P[(size_t)sa0 * 16 + lp];
    uint4 u1 = P[(size_t)sa1 * 16 + lp];
    float2 a0 = __half22float2(__builtin_bit_cast(__half2, u0.x));
    float2 a1 = __half22float2(__builtin_bit_cast(__half2, u0.y));
    float2 a2 = __half22float2(__builtin_bit_cast(__half2, u0.z));
    float2 a3 = __half22float2(__builtin_bit_cast(__half2, u0.w));
    va[0] += a0.x; va[1] += a0.y; va[2] += a1.x; va[3] += a1.y;
    va[4] += a2.x; va[5] += a2.y; va[6] += a3.x; va[7] += a3.y;
    float2 b0 = __half22float2(__builtin_bit_cast(__half2, u1.x));
    float2 b1 = __half22float2(__builtin_bit_cast(__half2, u1.y));
    float2 b2 = __half22float2(__builtin_bit_cast(__half2, u1.z));
    float2 b3 = __half22float2(__builtin_bit_cast(__half2, u1.w));
    va[0] += b0.x; va[1] += b0.y; va[2] += b1.x; va[3] += b1.y;
    va[4] += b2.x; va[5] += b2.y; va[6] += b3.x; va[7] += b3.y;
  }
  for (; e < s1; e += 4) {
    int idx = e + g;
    if (idx < s1) {
      int sa = esrc[idx];
      uint4 u = P[(size_t)sa * 16 + lp];
      float2 f0 = __half22float2(__builtin_bit_cast(__half2, u.x));
      float2 f1 = __half22float2(__builtin_bit_cast(__half2, u.y));
      float2 f2 = __half22float2(__builtin_bit_cast(__half2, u.z));
      float2 f3 = __half22float2(__builtin_bit_cast(__half2, u.w));
      va[0] += f0.x; va[1] += f0.y; va[2] += f1.x; va[3] += f1.y;
      va[4] += f2.x; va[5] += f2.y; va[6] += f3.x; va[7] += f3.y;
    }
  }
  // combine the 4 edge-slot groups (lanes with equal lp)
#pragma unroll
  for (int j = 0; j < 8; j++) {
    va[j] += __shfl_xor(va[j], 16, 64);
    va[j] += __shfl_xor(va[j], 32, 64);
  }
  if (g == 0) {
    int dgi = s1 - s0; if (dgi < 1) dgi = 1;
    float inv = 1.0f / (float)dgi;
    unsigned int hiw[4], low[4];
#pragma unroll
    for (int p = 0; p < 4; p++) {
      unsigned short h0, l0, h1, l1;
      splitf(va[2 * p] * inv, h0, l0);
      splitf(va[2 * p + 1] * inv, h1, l1);
      hiw[p] = (unsigned)h0 | ((unsigned)h1 << 16);
      low[p] = (unsigned)l0 | ((unsigned)l1 << 16);
    }
    *(uint4*)&aggHi[(size_t)v * 64 + lp * 4] = make_uint4(hiw[0], hiw[1], hiw[2], hiw[3]);
    *(uint4*)&aggLo[(size_t)v * 64 + lp * 4] = make_uint4(low[0], low[1], low[2], low[3]);
  }
}

// ---------------- per-graph mean, phase 1: 8 chunks/graph partial sums ----------
__global__ __launch_bounds__(256)
void k_gm_part(const unsigned short* __restrict__ hHi, const unsigned short* __restrict__ hLo,
               const int* __restrict__ gid, float* __restrict__ hgpart) {
  int g = blockIdx.x >> 3;
  int j = blockIdx.x & 7;
  int t = threadIdx.x;
  int c = t & 127, rp = t >> 7;
  // bounds of graph g (all threads redundantly)
  int lo = 0, hi = N_NODES;
  while (lo < hi) { int m = (lo + hi) >> 1; if (gid[m] < g) lo = m + 1; else hi = m; }
  int s = lo;
  hi = N_NODES;
  while (lo < hi) { int m = (lo + hi) >> 1; if (gid[m] < g + 1) lo = m + 1; else hi = m; }
  int e = lo;
  int per = ((e - s) + 7) >> 3;
  int vs = s + j * per;
  int ve = vs + per; if (ve > e) ve = e;
  float acc = 0.f;
  if (c < D) {
    for (int v = vs + rp; v < ve; v += 2) {
      size_t idx = (size_t)v * KP_H + c;
      acc += bf_bits2f(hHi[idx]) + bf_bits2f(hLo[idx]);
    }
  }
  __shared__ float part[2][128];
  part[rp][c] = acc;
  __syncthreads();
  if (rp == 0 && c < D)
    hgpart[(size_t)blockIdx.x * D + c] = part[0][c] + part[1][c];
}

// ---------------- per-graph mean, phase 2: reduce 8 chunks + divide ------------
__global__ __launch_bounds__(128)
void k_gm_fin(const float* __restrict__ hgpart, const int* __restrict__ gid,
              float* __restrict__ hg) {
  int g = blockIdx.x;
  int t = threadIdx.x;
  int lo = 0, hi = N_NODES;
  while (lo < hi) { int m = (lo + hi) >> 1; if (gid[m] < g) lo = m + 1; else hi = m; }
  int s = lo;
  hi = N_NODES;
  while (lo < hi) { int m = (lo + hi) >> 1; if (gid[m] < g + 1) lo = m + 1; else hi = m; }
  int cnt = lo - s; if (cnt < 1) cnt = 1;
  if (t < D) {
    float sum = 0.f;
#pragma unroll
    for (int j = 0; j < 8; j++) sum += hgpart[(size_t)(g * 8 + j) * D + t];
    hg[g * D + t] = sum / (float)cnt;
  }
}

// ---------------- MLP readout ----------------
__global__ __launch_bounds__(64)
void k_readout(const float* __restrict__ hg,
               const float* __restrict__ Wr0, const float* __restrict__ br0,
               const float* __restrict__ Wr1, const float* __restrict__ br1,
               const float* __restrict__ Wr2, const float* __restrict__ br2,
               float* __restrict__ out) {
  int g = blockIdx.x;
  int t = threadIdx.x;
  __shared__ float x0[D];
  __shared__ float x1[54];
  __shared__ float x2[27];
  for (int i = t; i < D; i += 64) x0[i] = hg[g * D + i];
  __syncthreads();
  if (t < 54) {
    float v = br0[t];
    for (int k = 0; k < D; k++) v += x0[k] * Wr0[t * D + k];
    x1[t] = fmaxf(v, 0.f);
  }
  __syncthreads();
  if (t < 27) {
    float v = br1[t];
    for (int k = 0; k < 54; k++) v += x1[k] * Wr1[t * 54 + k];
    x2[t] = fmaxf(v, 0.f);
  }
  __syncthreads();
  if (t < 10) {
    float v = br2[t];
    for (int k = 0; k < 27; k++) v += x2[k] * Wr2[t * 27 + k];
    out[g * 10 + t] = v;
  }
}

extern "C" void kernel_launch(void* const* d_in, const int* in_sizes, int n_in,
                              void* d_out, int out_size, void* d_ws, size_t ws_size,
                              hipStream_t stream) {
  const float* nodes_feat = (const float*)d_in[0];
  const float* snorm_n    = (const float*)d_in[1];
  const int*   src        = (const int*)d_in[2];
  const int*   dst        = (const int*)d_in[3];
  const int*   gid        = (const int*)d_in[4];
  const float* W_emb      = (const float*)d_in[6];
  const float* b_emb      = (const float*)d_in[7];
  const float* W_pool     = (const float*)d_in[8];
  const float* b_pool     = (const float*)d_in[9];
  const float* W_node     = (const float*)d_in[10];
  const float* b_node     = (const float*)d_in[11];
  const float* W_r0       = (const float*)d_in[12];
  const float* b_r0       = (const float*)d_in[13];
  const float* W_r1       = (const float*)d_in[14];
  const float* b_r1       = (const float*)d_in[15];
  const float* W_r2       = (const float*)d_in[16];
  const float* b_r2       = (const float*)d_in[17];
  float* out = (float*)d_out;

  char* ws = (char*)d_ws;
  size_t off = 0;
  auto alloc = [&](size_t bytes) { size_t o = off; off = (off + bytes + 255) & ~(size_t)255; return o; };

  __half* buf1 = (__half*)(ws + alloc((size_t)N_NODES * PSTRIDE * 2));  // pooled (fp16, padded)
  unsigned short* h_hi = (unsigned short*)(ws + alloc((size_t)N_PAD * KP_H * 2));
  unsigned short* h_lo = (unsigned short*)(ws + alloc((size_t)N_PAD * KP_H * 2));
  // nf (pair, [N_PAD][160]) aliased with agg (pair, [N_PAD][128]) — disjoint lifetimes
  char* nfagg = ws + alloc((size_t)N_PAD * KP_NF * 2 * 2);
  unsigned short* nf_hi = (unsigned short*)nfagg;
  unsigned short* nf_lo = (unsigned short*)(nfagg + (size_t)N_PAD * KP_NF * 2);
  unsigned short* agg_hi = (unsigned short*)nfagg;
  unsigned short* agg_lo = (unsigned short*)(nfagg + (size_t)N_PAD * KP_H * 2);
  uint2* ebin = (uint2*)(ws + alloc((size_t)N_EDGES * 8));
  int* esrc  = (int*)(ws + alloc((size_t)N_EDGES * 4));
  int* offs  = (int*)(ws + alloc((size_t)(N_NODES + 1) * 4));
  int* bhist = (int*)(ws + alloc((size_t)(NBUCKET + 1) * 4));
  int* boffs = (int*)(ws + alloc((size_t)(NBUCKET + 1) * 4));
  int* bcur  = (int*)(ws + alloc((size_t)(NBUCKET + 1) * 4));
  unsigned short* wHi = (unsigned short*)(ws + alloc((size_t)W_TOTAL * 2));
  unsigned short* wLo = (unsigned short*)(ws + alloc((size_t)W_TOTAL * 2));
  float* hgpart = (float*)(ws + alloc((size_t)N_GRAPHS * 8 * D * 4));
  float* hg = (float*)(ws + alloc((size_t)N_GRAPHS * D * 4));
  (void)ws_size; (void)n_in; (void)in_sizes; (void)out_size;

  hipMemsetAsync(bhist, 0, (size_t)NBUCKET * 4, stream);

  // splits + pad init
  k_split_w<<<(W_TOTAL + 255) / 256, 256, 0, stream>>>(W_emb, W_pool, W_node, wHi, wLo);
  k_split_nf<<<4096, 256, 0, stream>>>(nodes_feat, nf_hi, nf_lo);
  k_padinit<<<8192, 256, 0, stream>>>(h_hi, h_lo);

  // CSR build via bucket counting sort (writes offs + esrc)
  const int EB = (N_EDGES + 2047) / 2048;  // 782
  k_bhist<<<EB, 256, 0, stream>>>(dst, bhist);
  k_bscan<<<1, 512, 0, stream>>>(bhist, boffs, bcur, offs);
  k_binscatter<<<EB, 256, 0, stream>>>(src, dst, bcur, ebin);
  k_scatter2<<<NBUCKET, 256, 0, stream>>>(ebin, boffs, offs, esrc);

  const int GEMM_GRID = N_PAD / 128;  // 782
  // embedding: h = nodes_feat @ W_emb^T + b_emb  (uses nf region before agg aliases it)
  k_mm<<<GEMM_GRID, 256, 0, stream>>>(nf_hi, nf_lo, KP_NF, KP_NF,
                                      wHi + WEMB_OFF, wLo + WEMB_OFF, KP_NF,
                                      nullptr, nullptr, 0, 0, nullptr, nullptr, 0,
                                      b_emb, 0, nullptr, h_hi, h_lo, nullptr);

  for (int l = 0; l < 4; l++) {
    const unsigned short* wpH = wHi + WPOOL_OFF + (size_t)l * 14336;
    const unsigned short* wpL = wLo + WPOOL_OFF + (size_t)l * 14336;
    const unsigned short* wn1H = wHi + WNODE1_OFF + (size_t)l * 14336;
    const unsigned short* wn1L = wLo + WNODE1_OFF + (size_t)l * 14336;
    const unsigned short* wn2H = wHi + WNODE2_OFF + (size_t)l * 14336;
    const unsigned short* wn2L = wLo + WNODE2_OFF + (size_t)l * 14336;
    const float* bp = b_pool + (size_t)l * D;
    const float* bn = b_node + (size_t)l * D;

    // pooled = relu(h @ Wp^T + bp)  (fp16 out, padded stride)
    k_mm<<<GEMM_GRID, 256, 0, stream>>>(h_hi, h_lo, KP_H, KP_H,
                                        wpH, wpL, KP_H,
                                        nullptr, nullptr, 0, 0, nullptr, nullptr, 0,
                                        bp, 1, buf1, nullptr, nullptr, nullptr);
    // agg = mean_in(pooled)
    k_aggregate<<<N_PAD / 4, 256, 0, stream>>>(buf1, offs, esrc,
                                               (unsigned int*)agg_hi, (unsigned int*)agg_lo);
    // h += relu(normalize(h@Wn1^T + agg@Wn2^T + bn)) * snorm   (fused)
    k_mm<<<GEMM_GRID, 256, 0, stream>>>(h_hi, h_lo, KP_H, KP_H,
                                        wn1H, wn1L, KP_H,
                                        agg_hi, agg_lo, KP_H, KP_H,
                                        wn2H, wn2L, KP_H,
                                        bn, 2, nullptr, h_hi, h_lo, snorm_n);
  }

  k_gm_part<<<N_GRAPHS * 8, 256, 0, stream>>>(h_hi, h_lo, gid, hgpart);
  k_gm_fin<<<N_GRAPHS, 128, 0, stream>>>(hgpart, gid, hg);
  k_readout<<<N_GRAPHS, 64, 0, stream>>>(hg, W_r0, b_r0, W_r1, b_r1, W_r2, b_r2, out);
}

// Round 13
// 771.511 us; speedup vs baseline: 1.1741x; 1.0469x over previous
//
#include <hip/hip_runtime.h>
#include <hip/hip_bf16.h>
#include <hip/hip_fp16.h>

#define N_NODES  100000
#define N_PAD    100096
#define N_EDGES  1600000
#define N_GRAPHS 128
#define D        108
#define IN_DIM   146
#define KP_H     128
#define KP_NF    160
#define PSTRIDE  128      // pooled row stride in halves (256B, line-aligned)
#define NBUCKET  391      // ceil(N_NODES/256)
#define LBUF     8192     // per-bucket LDS scatter buffer (max bucket edges ~4400)

typedef __bf16 bf16x8 __attribute__((ext_vector_type(8)));
typedef float  f32x4  __attribute__((ext_vector_type(4)));

__device__ __forceinline__ unsigned short f2bf_bits(float v) {
  __hip_bfloat16 b = __float2bfloat16(v);
  return __builtin_bit_cast(unsigned short, b);
}
__device__ __forceinline__ float bf_bits2f(unsigned short u) {
  __hip_bfloat16 b = __builtin_bit_cast(__hip_bfloat16, u);
  return __bfloat162float(b);
}
__device__ __forceinline__ void splitf(float v, unsigned short& hi, unsigned short& lo) {
  hi = f2bf_bits(v);
  lo = f2bf_bits(v - bf_bits2f(hi));
}

// ---------------- bucket histogram (LDS-batched) ----------------
__global__ __launch_bounds__(256)
void k_bhist(const int* __restrict__ dst, int* __restrict__ bhist) {
  __shared__ int bh[NBUCKET];
  int t = threadIdx.x;
  for (int i = t; i < NBUCKET; i += 256) bh[i] = 0;
  __syncthreads();
  int e0 = blockIdx.x * 2048;
#pragma unroll
  for (int j = 0; j < 8; j++) {
    int e = e0 + j * 256 + t;
    if (e < N_EDGES) atomicAdd(&bh[dst[e] >> 8], 1);
  }
  __syncthreads();
  for (int i = t; i < NBUCKET; i += 256)
    if (bh[i]) atomicAdd(&bhist[i], bh[i]);
}

// ---------------- bucket scan (one block) ----------------
__global__ __launch_bounds__(512)
void k_bscan(const int* __restrict__ bhist, int* __restrict__ boffs,
             int* __restrict__ bcur, int* __restrict__ offs) {
  __shared__ int sh[512];
  int t = threadIdx.x;
  sh[t] = (t < NBUCKET) ? bhist[t] : 0;
  __syncthreads();
  for (int off = 1; off < 512; off <<= 1) {
    int v = (t >= off) ? sh[t - off] : 0;
    __syncthreads();
    sh[t] += v;
    __syncthreads();
  }
  if (t < NBUCKET) {
    int excl = (t > 0) ? sh[t - 1] : 0;
    boffs[t] = excl;
    bcur[t]  = excl;
  }
  if (t == 0) { boffs[NBUCKET] = N_EDGES; offs[N_NODES] = N_EDGES; }
}

// ---------------- bin edges into bucket-contiguous ebin (LDS-batched ranks) ----
__global__ __launch_bounds__(256)
void k_binscatter(const int* __restrict__ src, const int* __restrict__ dst,
                  int* __restrict__ bcur, uint2* __restrict__ ebin) {
  __shared__ int lhist[NBUCKET];
  __shared__ int lbase[NBUCKET];
  int t = threadIdx.x;
  for (int i = t; i < NBUCKET; i += 256) lhist[i] = 0;
  __syncthreads();
  int e0 = blockIdx.x * 2048;
  int s[8], d[8], r[8];
#pragma unroll
  for (int j = 0; j < 8; j++) {
    int e = e0 + j * 256 + t;
    if (e < N_EDGES) {
      s[j] = src[e]; d[j] = dst[e];
      r[j] = atomicAdd(&lhist[d[j] >> 8], 1);
    }
  }
  __syncthreads();
  for (int i = t; i < NBUCKET; i += 256)
    lbase[i] = lhist[i] ? atomicAdd(&bcur[i], lhist[i]) : 0;
  __syncthreads();
#pragma unroll
  for (int j = 0; j < 8; j++) {
    int e = e0 + j * 256 + t;
    if (e < N_EDGES)
      ebin[(size_t)lbase[d[j] >> 8] + r[j]] = make_uint2((unsigned)s[j], (unsigned)d[j]);
  }
}

// ---------------- per-bucket local CSR: writes offs + coalesced esrc ----------
__global__ __launch_bounds__(256)
void k_scatter2(const uint2* __restrict__ ebin, const int* __restrict__ boffs,
                int* __restrict__ offs, int* __restrict__ esrc) {
  __shared__ int lcnt[256];
  __shared__ int lcur[256];
  __shared__ int lbuf[LBUF];
  int b = blockIdx.x;
  int t = threadIdx.x;
  int vbase = b << 8;
  int estart = boffs[b], eend = boffs[b + 1];
  int cnt = eend - estart;
  lcnt[t] = 0;
  __syncthreads();
  for (int e = estart + t; e < eend; e += 256)
    atomicAdd(&lcnt[ebin[e].y & 255], 1);
  __syncthreads();
  // inclusive scan of lcnt (in-place Hillis-Steele)
  for (int off = 1; off < 256; off <<= 1) {
    int v = (t >= off) ? lcnt[t - off] : 0;
    __syncthreads();
    lcnt[t] += v;
    __syncthreads();
  }
  int excl = (t > 0) ? lcnt[t - 1] : 0;
  int v = vbase + t;
  if (v < N_NODES) offs[v] = estart + excl;
  lcur[t] = excl;
  __syncthreads();
  if (cnt <= LBUF) {
    for (int e = estart + t; e < eend; e += 256) {
      uint2 u = ebin[e];
      int pos = atomicAdd(&lcur[u.y & 255], 1);
      lbuf[pos] = (int)u.x;
    }
    __syncthreads();
    for (int i = t; i < cnt; i += 256) esrc[estart + i] = lbuf[i];
  } else {   // safety fallback (statistically unreachable)
    for (int e = estart + t; e < eend; e += 256) {
      uint2 u = ebin[e];
      int pos = atomicAdd(&lcur[u.y & 255], 1);
      esrc[estart + pos] = (int)u.x;
    }
  }
}

// ---------------- split nodes_feat into padded bf16 hi/lo ----------------
__global__ void k_split_nf(const float* __restrict__ nf,
                           unsigned short* __restrict__ hi, unsigned short* __restrict__ lo) {
  size_t stride = (size_t)gridDim.x * blockDim.x;
  for (size_t i = (size_t)blockIdx.x * blockDim.x + threadIdx.x;
       i < (size_t)N_PAD * KP_NF; i += stride) {
    int row = (int)(i / KP_NF), k = (int)(i % KP_NF);
    float v = (row < N_NODES && k < IN_DIM) ? nf[(size_t)row * IN_DIM + k] : 0.f;
    unsigned short h, l; splitf(v, h, l);
    hi[i] = h; lo[i] = l;
  }
}

// ---------------- split + pad all weights into one packed pair ----------------
// layout: [0,17920) Wemb [112][160]; then 4x wpool [112][128]; 4x wnode1; 4x wnode2
#define WEMB_OFF   0
#define WPOOL_OFF  17920
#define WNODE1_OFF (17920 + 4*14336)
#define WNODE2_OFF (17920 + 8*14336)
#define W_TOTAL    (17920 + 12*14336)

__global__ void k_split_w(const float* __restrict__ W_emb, const float* __restrict__ W_pool,
                          const float* __restrict__ W_node,
                          unsigned short* __restrict__ hi, unsigned short* __restrict__ lo) {
  size_t stride = (size_t)gridDim.x * blockDim.x;
  for (size_t i = (size_t)blockIdx.x * blockDim.x + threadIdx.x; i < W_TOTAL; i += stride) {
    float v = 0.f;
    if (i < WPOOL_OFF) {
      int r = (int)(i / KP_NF), k = (int)(i % KP_NF);
      if (r < D && k < IN_DIM) v = W_emb[(size_t)r * IN_DIM + k];
    } else {
      size_t i2 = i - WPOOL_OFF;
      int seg = (int)(i2 / (4 * 14336));
      size_t r2 = i2 % (4 * 14336);
      int l = (int)(r2 / 14336);
      int n = (int)((r2 % 14336) / KP_H);
      int k = (int)(r2 % KP_H);
      if (n < D && k < D) {
        if (seg == 0)      v = W_pool[(size_t)l * D * D + (size_t)n * D + k];
        else if (seg == 1) v = W_node[(size_t)l * D * 2 * D + (size_t)n * 2 * D + k];
        else               v = W_node[(size_t)l * D * 2 * D + (size_t)n * 2 * D + D + k];
      }
    }
    unsigned short h, l2; splitf(v, h, l2);
    hi[i] = h; lo[i] = l2;
  }
}

// ---------------- zero pad rows/cols of h hi/lo ----------------
__global__ void k_padinit(unsigned short* __restrict__ hHi, unsigned short* __restrict__ hLo) {
  size_t stride = (size_t)gridDim.x * blockDim.x;
  for (size_t i = (size_t)blockIdx.x * blockDim.x + threadIdx.x;
       i < (size_t)N_PAD * KP_H; i += stride) {
    int row = (int)(i >> 7), col = (int)(i & 127);
    if (col >= D || row >= N_NODES) { hHi[i] = 0; hLo[i] = 0; }
  }
}

// ---------------- MFMA split-bf16 GEMM, LDS-staged W, 8 waves R=1 ----------------
// grid 782, block 512 (8 waves), M-tile 128 (16 rows/wave), n-tile 112 (7x16)
// modes: 0 = embed (split out), 1 = pool (fp16 out + relu, PSTRIDE), 2 = node (fused norm/res)
#define WS_STRIDE 72
__global__ __launch_bounds__(512)
void k_mm(const unsigned short* A1h, const unsigned short* A1l, int lda1, int K1,
          const unsigned short* __restrict__ W1h, const unsigned short* __restrict__ W1l, int ldw1,
          const unsigned short* A2h, const unsigned short* A2l, int lda2, int K2,
          const unsigned short* __restrict__ W2h, const unsigned short* __restrict__ W2l, int ldw2,
          const float* __restrict__ bias, int mode,
          __half* __restrict__ outH,
          unsigned short* hHi, unsigned short* hLo,
          const float* __restrict__ snorm)
{
  __shared__ unsigned short WsH[112 * WS_STRIDE];
  __shared__ unsigned short WsL[112 * WS_STRIDE];

  const int t = threadIdx.x;
  const int lane = t & 63;
  const int wv = t >> 6;          // 0..7
  const int r15 = lane & 15;
  const int q = lane >> 4;
  const int m0 = blockIdx.x * 128 + wv * 16;

  f32x4 acc[7];
#pragma unroll
  for (int j = 0; j < 7; j++) acc[j] = f32x4{0.f, 0.f, 0.f, 0.f};

  auto do_seg = [&](const unsigned short* Ah, const unsigned short* Al, int lda, int K,
                    const unsigned short* Wh, const unsigned short* Wl, int ldw) {
    for (int k0 = 0; k0 < K; k0 += 64) {
      const int klen = (K - k0 >= 64) ? 64 : (K - k0);
      __syncthreads();   // previous chunk's LDS reads done
      if (klen == 64) {
        for (int u = t; u < 896; u += 512) {
          int row = u >> 3, kq = u & 7;
          *(uint4*)&WsH[row * WS_STRIDE + kq * 8] =
              *(const uint4*)&Wh[(size_t)row * ldw + k0 + kq * 8];
          *(uint4*)&WsL[row * WS_STRIDE + kq * 8] =
              *(const uint4*)&Wl[(size_t)row * ldw + k0 + kq * 8];
        }
      } else { // 32
        for (int u = t; u < 448; u += 512) {
          int row = u >> 2, kq = u & 3;
          *(uint4*)&WsH[row * WS_STRIDE + kq * 8] =
              *(const uint4*)&Wh[(size_t)row * ldw + k0 + kq * 8];
          *(uint4*)&WsL[row * WS_STRIDE + kq * 8] =
              *(const uint4*)&Wl[(size_t)row * ldw + k0 + kq * 8];
        }
      }
      // issue A loads for this chunk while staging completes
      bf16x8 a_h[2], a_l[2];
      const int ns = klen >> 5;
#pragma unroll
      for (int s = 0; s < 2; s++) {
        if (s < ns) {
          size_t base = (size_t)(m0 + r15) * lda + k0 + s * 32 + q * 8;
          a_h[s] = *(const bf16x8*)&Ah[base];
          a_l[s] = *(const bf16x8*)&Al[base];
        }
      }
      __syncthreads();   // staged W visible
#pragma unroll
      for (int s = 0; s < 2; s++) {
        if (s < ns) {
#pragma unroll
          for (int n = 0; n < 7; n++) {
            int wrow = n * 16 + r15;
            const bf16x8 bh = *(const bf16x8*)&WsH[wrow * WS_STRIDE + s * 32 + q * 8];
            const bf16x8 bl = *(const bf16x8*)&WsL[wrow * WS_STRIDE + s * 32 + q * 8];
            acc[n] = __builtin_amdgcn_mfma_f32_16x16x32_bf16(a_h[s], bh, acc[n], 0, 0, 0);
            acc[n] = __builtin_amdgcn_mfma_f32_16x16x32_bf16(a_h[s], bl, acc[n], 0, 0, 0);
            acc[n] = __builtin_amdgcn_mfma_f32_16x16x32_bf16(a_l[s], bh, acc[n], 0, 0, 0);
          }
        }
      }
    }
  };

  do_seg(A1h, A1l, lda1, K1, W1h, W1l, ldw1);
  if (A2h) do_seg(A2h, A2l, lda2, K2, W2h, W2l, ldw2);

  // ---------------- epilogue ----------------
  if (mode == 2) {
    // fused: v = acc+bias; L2-normalize row; relu; *snorm; h += v
    float ss[4] = {0.f, 0.f, 0.f, 0.f};
#pragma unroll
    for (int n = 0; n < 7; n++) {
      int col = n * 16 + r15;
      if (col < D) {
        float bv = bias[col];
#pragma unroll
        for (int r = 0; r < 4; r++) {
          float v = acc[n][r] + bv;
          ss[r] += v * v;
        }
      }
    }
#pragma unroll
    for (int m_ = 1; m_ <= 8; m_ <<= 1) {
#pragma unroll
      for (int r = 0; r < 4; r++) ss[r] += __shfl_xor(ss[r], m_, 64);
    }
    float inv[4], sn[4]; int rows[4];
#pragma unroll
    for (int r = 0; r < 4; r++) {
      rows[r] = m0 + q * 4 + r;
      float dn = fmaxf(sqrtf(ss[r]), 1e-12f);
      inv[r] = 1.0f / dn;
      sn[r] = (rows[r] < N_NODES) ? snorm[rows[r]] : 0.f;
    }
#pragma unroll
    for (int n = 0; n < 7; n++) {
      int col = n * 16 + r15;
      if (col >= D) continue;
      float bv = bias[col];
#pragma unroll
      for (int r = 0; r < 4; r++) {
        if (rows[r] >= N_NODES) continue;
        size_t idx = (size_t)rows[r] * KP_H + col;
        float hold = bf_bits2f(hHi[idx]) + bf_bits2f(hLo[idx]);
        float v = acc[n][r] + bv;
        float x = fmaxf(v * inv[r], 0.f) * sn[r];
        float nh = hold + x;
        unsigned short h_, l_; splitf(nh, h_, l_);
        hHi[idx] = h_; hLo[idx] = l_;
      }
    }
  } else {
#pragma unroll
    for (int n = 0; n < 7; n++) {
      int col = n * 16 + r15;
      if (col >= D) continue;
      float bv = bias[col];
#pragma unroll
      for (int r = 0; r < 4; r++) {
        int row = m0 + q * 4 + r;
        if (row >= N_NODES) continue;
        float v = acc[n][r] + bv;
        if (mode == 1) {
          outH[(size_t)row * PSTRIDE + col] = __float2half_rn(fmaxf(v, 0.f));
        } else {
          unsigned short h_, l_; splitf(v, h_, l_);
          hHi[(size_t)row * KP_H + col] = h_;
          hLo[(size_t)row * KP_H + col] = l_;
        }
      }
    }
  }
}

// ---------------- pull aggregation: one wave/node, 8 edges in flight ----------
// lane = (g, lp): g = edge slot (0..3), lp = 16B segment of the 256B row.
// 2x outer unroll: two independent dwordx4 gathers per iteration.
__global__ __launch_bounds__(256)
void k_aggregate(const __half* __restrict__ pooled, const int* __restrict__ offsets,
                 const int* __restrict__ esrc,
                 unsigned int* __restrict__ aggHi, unsigned int* __restrict__ aggLo)
{
  int t = threadIdx.x;
  int lane = t & 63;
  int g = lane >> 4;
  int lp = lane & 15;
  int v = blockIdx.x * 4 + (t >> 6);
  if (v >= N_PAD) return;
  float va[8];
#pragma unroll
  for (int j = 0; j < 8; j++) va[j] = 0.f;
  int s0 = 0, s1 = 0;
  if (v < N_NODES) { s0 = offsets[v]; s1 = offsets[v + 1]; }
  const uint4* P = (const uint4*)pooled;   // row = 16 uint4 (256B)
  int e = s0;
  for (; e + 7 < s1; e += 8) {
    int sa0 = esrc[e + g];
    int sa1 = esrc[e + 4 + g];
    uint4 u0 = P[(size_t)sa0 * 16 + lp];
    uint4 u1 = P[(size_t)sa1 * 16 + lp];
    float2 a0 = __half22float2(__builtin_bit_cast(__half2, u0.x));
    float2 a1 = __half22float2(__builtin_bit_cast(__half2, u0.y));
    float2 a2 = __half22float2(__builtin_bit_cast(__half2, u0.z));
    float2 a3 = __half22float2(__builtin_bit_cast(__half2, u0.w));
    va[0] += a0.x; va[1] += a0.y; va[2] += a1.x; va[3] += a1.y;
    va[4] += a2.x; va[5] += a2.y; va[6] += a3.x; va[7] += a3.y;
    float2 b0 = __half22float2(__builtin_bit_cast(__half2, u1.x));
    float2 b1 = __half22float2(__builtin_bit_cast(__half2, u1.y));
    float2 b2 = __half22float2(__builtin_bit_cast(__half2, u1.z));
    float2 b3 = __half22float2(__builtin_bit_cast(__half2, u1.w));
    va[0] += b0.x; va[1] += b0.y; va[2] += b1.x; va[3] += b1.y;
    va[4] += b2.x; va[5] += b2.y; va[6] += b3.x; va[7] += b3.y;
  }
  for (; e < s1; e += 4) {
    int idx = e + g;
    if (idx < s1) {
      int sa = esrc[idx];
      uint4 u = P[(size_t)sa * 16 + lp];
      float2 f0 = __half22float2(__builtin_bit_cast(__half2, u.x));
      float2 f1 = __half22float2(__builtin_bit_cast(__half2, u.y));
      float2 f2 = __half22float2(__builtin_bit_cast(__half2, u.z));
      float2 f3 = __half22float2(__builtin_bit_cast(__half2, u.w));
      va[0] += f0.x; va[1] += f0.y; va[2] += f1.x; va[3] += f1.y;
      va[4] += f2.x; va[5] += f2.y; va[6] += f3.x; va[7] += f3.y;
    }
  }
  // combine the 4 edge-slot groups (lanes with equal lp)
#pragma unroll
  for (int j = 0; j < 8; j++) {
    va[j] += __shfl_xor(va[j], 16, 64);
    va[j] += __shfl_xor(va[j], 32, 64);
  }
  if (g == 0) {
    int dgi = s1 - s0; if (dgi < 1) dgi = 1;
    float inv = 1.0f / (float)dgi;
    unsigned int hiw[4], low[4];
#pragma unroll
    for (int p = 0; p < 4; p++) {
      unsigned short h0, l0, h1, l1;
      splitf(va[2 * p] * inv, h0, l0);
      splitf(va[2 * p + 1] * inv, h1, l1);
      hiw[p] = (unsigned)h0 | ((unsigned)h1 << 16);
      low[p] = (unsigned)l0 | ((unsigned)l1 << 16);
    }
    *(uint4*)&aggHi[(size_t)v * 64 + lp * 4] = make_uint4(hiw[0], hiw[1], hiw[2], hiw[3]);
    *(uint4*)&aggLo[(size_t)v * 64 + lp * 4] = make_uint4(low[0], low[1], low[2], low[3]);
  }
}

// ---------------- per-graph mean, phase 1: 8 chunks/graph partial sums ----------
__global__ __launch_bounds__(256)
void k_gm_part(const unsigned short* __restrict__ hHi, const unsigned short* __restrict__ hLo,
               const int* __restrict__ gid, float* __restrict__ hgpart) {
  int g = blockIdx.x >> 3;
  int j = blockIdx.x & 7;
  int t = threadIdx.x;
  int c = t & 127, rp = t >> 7;
  // bounds of graph g (all threads redundantly)
  int lo = 0, hi = N_NODES;
  while (lo < hi) { int m = (lo + hi) >> 1; if (gid[m] < g) lo = m + 1; else hi = m; }
  int s = lo;
  hi = N_NODES;
  while (lo < hi) { int m = (lo + hi) >> 1; if (gid[m] < g + 1) lo = m + 1; else hi = m; }
  int e = lo;
  int per = ((e - s) + 7) >> 3;
  int vs = s + j * per;
  int ve = vs + per; if (ve > e) ve = e;
  float acc = 0.f;
  if (c < D) {
    for (int v = vs + rp; v < ve; v += 2) {
      size_t idx = (size_t)v * KP_H + c;
      acc += bf_bits2f(hHi[idx]) + bf_bits2f(hLo[idx]);
    }
  }
  __shared__ float part[2][128];
  part[rp][c] = acc;
  __syncthreads();
  if (rp == 0 && c < D)
    hgpart[(size_t)blockIdx.x * D + c] = part[0][c] + part[1][c];
}

// ---------------- per-graph mean, phase 2: reduce 8 chunks + divide ------------
__global__ __launch_bounds__(128)
void k_gm_fin(const float* __restrict__ hgpart, const int* __restrict__ gid,
              float* __restrict__ hg) {
  int g = blockIdx.x;
  int t = threadIdx.x;
  int lo = 0, hi = N_NODES;
  while (lo < hi) { int m = (lo + hi) >> 1; if (gid[m] < g) lo = m + 1; else hi = m; }
  int s = lo;
  hi = N_NODES;
  while (lo < hi) { int m = (lo + hi) >> 1; if (gid[m] < g + 1) lo = m + 1; else hi = m; }
  int cnt = lo - s; if (cnt < 1) cnt = 1;
  if (t < D) {
    float sum = 0.f;
#pragma unroll
    for (int j = 0; j < 8; j++) sum += hgpart[(size_t)(g * 8 + j) * D + t];
    hg[g * D + t] = sum / (float)cnt;
  }
}

// ---------------- MLP readout ----------------
__global__ __launch_bounds__(64)
void k_readout(const float* __restrict__ hg,
               const float* __restrict__ Wr0, const float* __restrict__ br0,
               const float* __restrict__ Wr1, const float* __restrict__ br1,
               const float* __restrict__ Wr2, const float* __restrict__ br2,
               float* __restrict__ out) {
  int g = blockIdx.x;
  int t = threadIdx.x;
  __shared__ float x0[D];
  __shared__ float x1[54];
  __shared__ float x2[27];
  for (int i = t; i < D; i += 64) x0[i] = hg[g * D + i];
  __syncthreads();
  if (t < 54) {
    float v = br0[t];
    for (int k = 0; k < D; k++) v += x0[k] * Wr0[t * D + k];
    x1[t] = fmaxf(v, 0.f);
  }
  __syncthreads();
  if (t < 27) {
    float v = br1[t];
    for (int k = 0; k < 54; k++) v += x1[k] * Wr1[t * 54 + k];
    x2[t] = fmaxf(v, 0.f);
  }
  __syncthreads();
  if (t < 10) {
    float v = br2[t];
    for (int k = 0; k < 27; k++) v += x2[k] * Wr2[t * 27 + k];
    out[g * 10 + t] = v;
  }
}

extern "C" void kernel_launch(void* const* d_in, const int* in_sizes, int n_in,
                              void* d_out, int out_size, void* d_ws, size_t ws_size,
                              hipStream_t stream) {
  const float* nodes_feat = (const float*)d_in[0];
  const float* snorm_n    = (const float*)d_in[1];
  const int*   src        = (const int*)d_in[2];
  const int*   dst        = (const int*)d_in[3];
  const int*   gid        = (const int*)d_in[4];
  const float* W_emb      = (const float*)d_in[6];
  const float* b_emb      = (const float*)d_in[7];
  const float* W_pool     = (const float*)d_in[8];
  const float* b_pool     = (const float*)d_in[9];
  const float* W_node     = (const float*)d_in[10];
  const float* b_node     = (const float*)d_in[11];
  const float* W_r0       = (const float*)d_in[12];
  const float* b_r0       = (const float*)d_in[13];
  const float* W_r1       = (const float*)d_in[14];
  const float* b_r1       = (const float*)d_in[15];
  const float* W_r2       = (const float*)d_in[16];
  const float* b_r2       = (const float*)d_in[17];
  float* out = (float*)d_out;

  char* ws = (char*)d_ws;
  size_t off = 0;
  auto alloc = [&](size_t bytes) { size_t o = off; off = (off + bytes + 255) & ~(size_t)255; return o; };

  __half* buf1 = (__half*)(ws + alloc((size_t)N_NODES * PSTRIDE * 2));  // pooled (fp16, padded)
  unsigned short* h_hi = (unsigned short*)(ws + alloc((size_t)N_PAD * KP_H * 2));
  unsigned short* h_lo = (unsigned short*)(ws + alloc((size_t)N_PAD * KP_H * 2));
  // nf (pair, [N_PAD][160]) aliased with agg (pair, [N_PAD][128]) — disjoint lifetimes
  char* nfagg = ws + alloc((size_t)N_PAD * KP_NF * 2 * 2);
  unsigned short* nf_hi = (unsigned short*)nfagg;
  unsigned short* nf_lo = (unsigned short*)(nfagg + (size_t)N_PAD * KP_NF * 2);
  unsigned short* agg_hi = (unsigned short*)nfagg;
  unsigned short* agg_lo = (unsigned short*)(nfagg + (size_t)N_PAD * KP_H * 2);
  uint2* ebin = (uint2*)(ws + alloc((size_t)N_EDGES * 8));
  int* esrc  = (int*)(ws + alloc((size_t)N_EDGES * 4));
  int* offs  = (int*)(ws + alloc((size_t)(N_NODES + 1) * 4));
  int* bhist = (int*)(ws + alloc((size_t)(NBUCKET + 1) * 4));
  int* boffs = (int*)(ws + alloc((size_t)(NBUCKET + 1) * 4));
  int* bcur  = (int*)(ws + alloc((size_t)(NBUCKET + 1) * 4));
  unsigned short* wHi = (unsigned short*)(ws + alloc((size_t)W_TOTAL * 2));
  unsigned short* wLo = (unsigned short*)(ws + alloc((size_t)W_TOTAL * 2));
  float* hgpart = (float*)(ws + alloc((size_t)N_GRAPHS * 8 * D * 4));
  float* hg = (float*)(ws + alloc((size_t)N_GRAPHS * D * 4));
  (void)ws_size; (void)n_in; (void)in_sizes; (void)out_size;

  hipMemsetAsync(bhist, 0, (size_t)NBUCKET * 4, stream);

  // splits + pad init
  k_split_w<<<(W_TOTAL + 255) / 256, 256, 0, stream>>>(W_emb, W_pool, W_node, wHi, wLo);
  k_split_nf<<<4096, 256, 0, stream>>>(nodes_feat, nf_hi, nf_lo);
  k_padinit<<<8192, 256, 0, stream>>>(h_hi, h_lo);

  // CSR build via bucket counting sort (writes offs + esrc)
  const int EB = (N_EDGES + 2047) / 2048;  // 782
  k_bhist<<<EB, 256, 0, stream>>>(dst, bhist);
  k_bscan<<<1, 512, 0, stream>>>(bhist, boffs, bcur, offs);
  k_binscatter<<<EB, 256, 0, stream>>>(src, dst, bcur, ebin);
  k_scatter2<<<NBUCKET, 256, 0, stream>>>(ebin, boffs, offs, esrc);

  const int GEMM_GRID = N_PAD / 128;  // 782
  // embedding: h = nodes_feat @ W_emb^T + b_emb  (uses nf region before agg aliases it)
  k_mm<<<GEMM_GRID, 512, 0, stream>>>(nf_hi, nf_lo, KP_NF, KP_NF,
                                      wHi + WEMB_OFF, wLo + WEMB_OFF, KP_NF,
                                      nullptr, nullptr, 0, 0, nullptr, nullptr, 0,
                                      b_emb, 0, nullptr, h_hi, h_lo, nullptr);

  for (int l = 0; l < 4; l++) {
    const unsigned short* wpH = wHi + WPOOL_OFF + (size_t)l * 14336;
    const unsigned short* wpL = wLo + WPOOL_OFF + (size_t)l * 14336;
    const unsigned short* wn1H = wHi + WNODE1_OFF + (size_t)l * 14336;
    const unsigned short* wn1L = wLo + WNODE1_OFF + (size_t)l * 14336;
    const unsigned short* wn2H = wHi + WNODE2_OFF + (size_t)l * 14336;
    const unsigned short* wn2L = wLo + WNODE2_OFF + (size_t)l * 14336;
    const float* bp = b_pool + (size_t)l * D;
    const float* bn = b_node + (size_t)l * D;

    // pooled = relu(h @ Wp^T + bp)  (fp16 out, padded stride)
    k_mm<<<GEMM_GRID, 512, 0, stream>>>(h_hi, h_lo, KP_H, KP_H,
                                        wpH, wpL, KP_H,
                                        nullptr, nullptr, 0, 0, nullptr, nullptr, 0,
                                        bp, 1, buf1, nullptr, nullptr, nullptr);
    // agg = mean_in(pooled)
    k_aggregate<<<N_PAD / 4, 256, 0, stream>>>(buf1, offs, esrc,
                                               (unsigned int*)agg_hi, (unsigned int*)agg_lo);
    // h += relu(normalize(h@Wn1^T + agg@Wn2^T + bn)) * snorm   (fused)
    k_mm<<<GEMM_GRID, 512, 0, stream>>>(h_hi, h_lo, KP_H, KP_H,
                                        wn1H, wn1L, KP_H,
                                        agg_hi, agg_lo, KP_H, KP_H,
                                        wn2H, wn2L, KP_H,
                                        bn, 2, nullptr, h_hi, h_lo, snorm_n);
  }

  k_gm_part<<<N_GRAPHS * 8, 256, 0, stream>>>(h_hi, h_lo, gid, hgpart);
  k_gm_fin<<<N_GRAPHS, 128, 0, stream>>>(hgpart, gid, hg);
  k_readout<<<N_GRAPHS, 64, 0, stream>>>(hg, W_r0, b_r0, W_r1, b_r1, W_r2, b_r2, out);
}

// Round 14
// 736.672 us; speedup vs baseline: 1.2297x; 1.0473x over previous
//
#include <hip/hip_runtime.h>
#include <hip/hip_bf16.h>
#include <hip/hip_fp16.h>

#define N_NODES  100000
#define N_PAD    100096
#define N_EDGES  1600000
#define N_GRAPHS 128
#define D        108
#define IN_DIM   146
#define KP_H     128
#define KP_NF    160
#define PSTRIDE  128      // pooled row stride in halves (256B, line-aligned)
#define NBUCKET  391      // ceil(N_NODES/256)
#define LBUF     8192     // per-bucket LDS scatter buffer (max bucket edges ~4400)

typedef __bf16 bf16x8 __attribute__((ext_vector_type(8)));
typedef float  f32x4  __attribute__((ext_vector_type(4)));

__device__ __forceinline__ unsigned short f2bf_bits(float v) {
  __hip_bfloat16 b = __float2bfloat16(v);
  return __builtin_bit_cast(unsigned short, b);
}
__device__ __forceinline__ float bf_bits2f(unsigned short u) {
  __hip_bfloat16 b = __builtin_bit_cast(__hip_bfloat16, u);
  return __bfloat162float(b);
}
__device__ __forceinline__ void splitf(float v, unsigned short& hi, unsigned short& lo) {
  hi = f2bf_bits(v);
  lo = f2bf_bits(v - bf_bits2f(hi));
}

// ---------------- bucket histogram (LDS-batched) ----------------
__global__ __launch_bounds__(256)
void k_bhist(const int* __restrict__ dst, int* __restrict__ bhist) {
  __shared__ int bh[NBUCKET];
  int t = threadIdx.x;
  for (int i = t; i < NBUCKET; i += 256) bh[i] = 0;
  __syncthreads();
  int e0 = blockIdx.x * 2048;
#pragma unroll
  for (int j = 0; j < 8; j++) {
    int e = e0 + j * 256 + t;
    if (e < N_EDGES) atomicAdd(&bh[dst[e] >> 8], 1);
  }
  __syncthreads();
  for (int i = t; i < NBUCKET; i += 256)
    if (bh[i]) atomicAdd(&bhist[i], bh[i]);
}

// ---------------- bucket scan (one block) ----------------
__global__ __launch_bounds__(512)
void k_bscan(const int* __restrict__ bhist, int* __restrict__ boffs,
             int* __restrict__ bcur, int* __restrict__ offs) {
  __shared__ int sh[512];
  int t = threadIdx.x;
  sh[t] = (t < NBUCKET) ? bhist[t] : 0;
  __syncthreads();
  for (int off = 1; off < 512; off <<= 1) {
    int v = (t >= off) ? sh[t - off] : 0;
    __syncthreads();
    sh[t] += v;
    __syncthreads();
  }
  if (t < NBUCKET) {
    int excl = (t > 0) ? sh[t - 1] : 0;
    boffs[t] = excl;
    bcur[t]  = excl;
  }
  if (t == 0) { boffs[NBUCKET] = N_EDGES; offs[N_NODES] = N_EDGES; }
}

// ---------------- bin edges into bucket-contiguous ebin (LDS-batched ranks) ----
__global__ __launch_bounds__(256)
void k_binscatter(const int* __restrict__ src, const int* __restrict__ dst,
                  int* __restrict__ bcur, uint2* __restrict__ ebin) {
  __shared__ int lhist[NBUCKET];
  __shared__ int lbase[NBUCKET];
  int t = threadIdx.x;
  for (int i = t; i < NBUCKET; i += 256) lhist[i] = 0;
  __syncthreads();
  int e0 = blockIdx.x * 2048;
  int s[8], d[8], r[8];
#pragma unroll
  for (int j = 0; j < 8; j++) {
    int e = e0 + j * 256 + t;
    if (e < N_EDGES) {
      s[j] = src[e]; d[j] = dst[e];
      r[j] = atomicAdd(&lhist[d[j] >> 8], 1);
    }
  }
  __syncthreads();
  for (int i = t; i < NBUCKET; i += 256)
    lbase[i] = lhist[i] ? atomicAdd(&bcur[i], lhist[i]) : 0;
  __syncthreads();
#pragma unroll
  for (int j = 0; j < 8; j++) {
    int e = e0 + j * 256 + t;
    if (e < N_EDGES)
      ebin[(size_t)lbase[d[j] >> 8] + r[j]] = make_uint2((unsigned)s[j], (unsigned)d[j]);
  }
}

// ---------------- per-bucket local CSR: writes offs + coalesced esrc ----------
// esrc entries are PREMULTIPLIED by 16 (uint4-index of the pooled row).
__global__ __launch_bounds__(256)
void k_scatter2(const uint2* __restrict__ ebin, const int* __restrict__ boffs,
                int* __restrict__ offs, int* __restrict__ esrc) {
  __shared__ int lcnt[256];
  __shared__ int lcur[256];
  __shared__ int lbuf[LBUF];
  int b = blockIdx.x;
  int t = threadIdx.x;
  int vbase = b << 8;
  int estart = boffs[b], eend = boffs[b + 1];
  int cnt = eend - estart;
  lcnt[t] = 0;
  __syncthreads();
  for (int e = estart + t; e < eend; e += 256)
    atomicAdd(&lcnt[ebin[e].y & 255], 1);
  __syncthreads();
  // inclusive scan of lcnt (in-place Hillis-Steele)
  for (int off = 1; off < 256; off <<= 1) {
    int v = (t >= off) ? lcnt[t - off] : 0;
    __syncthreads();
    lcnt[t] += v;
    __syncthreads();
  }
  int excl = (t > 0) ? lcnt[t - 1] : 0;
  int v = vbase + t;
  if (v < N_NODES) offs[v] = estart + excl;
  lcur[t] = excl;
  __syncthreads();
  if (cnt <= LBUF) {
    for (int e = estart + t; e < eend; e += 256) {
      uint2 u = ebin[e];
      int pos = atomicAdd(&lcur[u.y & 255], 1);
      lbuf[pos] = (int)(u.x << 4);
    }
    __syncthreads();
    for (int i = t; i < cnt; i += 256) esrc[estart + i] = lbuf[i];
  } else {   // safety fallback (statistically unreachable)
    for (int e = estart + t; e < eend; e += 256) {
      uint2 u = ebin[e];
      int pos = atomicAdd(&lcur[u.y & 255], 1);
      esrc[estart + pos] = (int)(u.x << 4);
    }
  }
}

// ---------------- split + pad all weights into one packed pair ----------------
// layout: [0,17920) Wemb [112][160]; then 4x wpool [112][128]; 4x wnode1; 4x wnode2
#define WEMB_OFF   0
#define WPOOL_OFF  17920
#define WNODE1_OFF (17920 + 4*14336)
#define WNODE2_OFF (17920 + 8*14336)
#define W_TOTAL    (17920 + 12*14336)

__global__ void k_split_w(const float* __restrict__ W_emb, const float* __restrict__ W_pool,
                          const float* __restrict__ W_node,
                          unsigned short* __restrict__ hi, unsigned short* __restrict__ lo) {
  size_t stride = (size_t)gridDim.x * blockDim.x;
  for (size_t i = (size_t)blockIdx.x * blockDim.x + threadIdx.x; i < W_TOTAL; i += stride) {
    float v = 0.f;
    if (i < WPOOL_OFF) {
      int r = (int)(i / KP_NF), k = (int)(i % KP_NF);
      if (r < D && k < IN_DIM) v = W_emb[(size_t)r * IN_DIM + k];
    } else {
      size_t i2 = i - WPOOL_OFF;
      int seg = (int)(i2 / (4 * 14336));
      size_t r2 = i2 % (4 * 14336);
      int l = (int)(r2 / 14336);
      int n = (int)((r2 % 14336) / KP_H);
      int k = (int)(r2 % KP_H);
      if (n < D && k < D) {
        if (seg == 0)      v = W_pool[(size_t)l * D * D + (size_t)n * D + k];
        else if (seg == 1) v = W_node[(size_t)l * D * 2 * D + (size_t)n * 2 * D + k];
        else               v = W_node[(size_t)l * D * 2 * D + (size_t)n * 2 * D + D + k];
      }
    }
    unsigned short h, l2; splitf(v, h, l2);
    hi[i] = h; lo[i] = l2;
  }
}

// ---------------- zero pad rows/cols of h hi/lo ----------------
__global__ void k_padinit(unsigned short* __restrict__ hHi, unsigned short* __restrict__ hLo) {
  size_t stride = (size_t)gridDim.x * blockDim.x;
  for (size_t i = (size_t)blockIdx.x * blockDim.x + threadIdx.x;
       i < (size_t)N_PAD * KP_H; i += stride) {
    int row = (int)(i >> 7), col = (int)(i & 127);
    if (col >= D || row >= N_NODES) { hHi[i] = 0; hLo[i] = 0; }
  }
}

// ---------------- embed GEMM: fp32 A (nodes_feat, unpadded) -> split h ----------
// grid 782, block 512 (8 waves), M-tile 128 (16 rows/wave), n-tile 112 (7x16)
#define WS_STRIDE 72
__global__ __launch_bounds__(512)
void k_mm_embed(const float* __restrict__ Af,
                const unsigned short* __restrict__ Wh_, const unsigned short* __restrict__ Wl_,
                const float* __restrict__ bias,
                unsigned short* __restrict__ hHi, unsigned short* __restrict__ hLo)
{
  __shared__ unsigned short WsH[112 * WS_STRIDE];
  __shared__ unsigned short WsL[112 * WS_STRIDE];

  const int t = threadIdx.x;
  const int lane = t & 63;
  const int wv = t >> 6;
  const int r15 = lane & 15;
  const int q = lane >> 4;
  const int m0 = blockIdx.x * 128 + wv * 16;
  const int row = m0 + r15;
  const bool rok = row < N_NODES;
  const float* rp_ = Af + (size_t)row * IN_DIM;

  f32x4 acc[7];
#pragma unroll
  for (int j = 0; j < 7; j++) acc[j] = f32x4{0.f, 0.f, 0.f, 0.f};

  for (int k0 = 0; k0 < KP_NF; k0 += 64) {
    const int klen = (KP_NF - k0 >= 64) ? 64 : (KP_NF - k0);
    const int ns = klen >> 5;
    __syncthreads();
    if (klen == 64) {
      for (int u = t; u < 896; u += 512) {
        int r_ = u >> 3, kq = u & 7;
        *(uint4*)&WsH[r_ * WS_STRIDE + kq * 8] =
            *(const uint4*)&Wh_[(size_t)r_ * KP_NF + k0 + kq * 8];
        *(uint4*)&WsL[r_ * WS_STRIDE + kq * 8] =
            *(const uint4*)&Wl_[(size_t)r_ * KP_NF + k0 + kq * 8];
      }
    } else {
      for (int u = t; u < 448; u += 512) {
        int r_ = u >> 2, kq = u & 3;
        *(uint4*)&WsH[r_ * WS_STRIDE + kq * 8] =
            *(const uint4*)&Wh_[(size_t)r_ * KP_NF + k0 + kq * 8];
        *(uint4*)&WsL[r_ * WS_STRIDE + kq * 8] =
            *(const uint4*)&Wl_[(size_t)r_ * KP_NF + k0 + kq * 8];
      }
    }
    // load + split A fragments from fp32 (guarded)
    bf16x8 a_h[2], a_l[2];
#pragma unroll
    for (int s = 0; s < 2; s++) {
      if (s < ns) {
#pragma unroll
        for (int j = 0; j < 8; j++) {
          int k = k0 + s * 32 + q * 8 + j;
          float v = (rok && k < IN_DIM) ? rp_[k] : 0.f;
          unsigned short h_, l_; splitf(v, h_, l_);
          a_h[s][j] = __builtin_bit_cast(__bf16, h_);
          a_l[s][j] = __builtin_bit_cast(__bf16, l_);
        }
      }
    }
    __syncthreads();
#pragma unroll
    for (int s = 0; s < 2; s++) {
      if (s < ns) {
#pragma unroll
        for (int n = 0; n < 7; n++) {
          int wrow = n * 16 + r15;
          const bf16x8 bh = *(const bf16x8*)&WsH[wrow * WS_STRIDE + s * 32 + q * 8];
          const bf16x8 bl = *(const bf16x8*)&WsL[wrow * WS_STRIDE + s * 32 + q * 8];
          acc[n] = __builtin_amdgcn_mfma_f32_16x16x32_bf16(a_h[s], bh, acc[n], 0, 0, 0);
          acc[n] = __builtin_amdgcn_mfma_f32_16x16x32_bf16(a_h[s], bl, acc[n], 0, 0, 0);
          acc[n] = __builtin_amdgcn_mfma_f32_16x16x32_bf16(a_l[s], bh, acc[n], 0, 0, 0);
        }
      }
    }
  }

#pragma unroll
  for (int n = 0; n < 7; n++) {
    int col = n * 16 + r15;
    if (col >= D) continue;
    float bv = bias[col];
#pragma unroll
    for (int r = 0; r < 4; r++) {
      int orow = m0 + q * 4 + r;
      if (orow >= N_NODES) continue;
      float v = acc[n][r] + bv;
      unsigned short h_, l_; splitf(v, h_, l_);
      hHi[(size_t)orow * KP_H + col] = h_;
      hLo[(size_t)orow * KP_H + col] = l_;
    }
  }
}

// ---------------- MFMA split-bf16 GEMM, LDS-staged W, 8 waves R=1 ----------------
// grid 782, block 512 (8 waves), M-tile 128 (16 rows/wave), n-tile 112 (7x16)
// modes: 1 = pool (fp16 out + relu, PSTRIDE), 2 = node (fused norm/res)
__global__ __launch_bounds__(512)
void k_mm(const unsigned short* A1h, const unsigned short* A1l, int lda1, int K1,
          const unsigned short* __restrict__ W1h, const unsigned short* __restrict__ W1l, int ldw1,
          const unsigned short* A2h, const unsigned short* A2l, int lda2, int K2,
          const unsigned short* __restrict__ W2h, const unsigned short* __restrict__ W2l, int ldw2,
          const float* __restrict__ bias, int mode,
          __half* __restrict__ outH,
          unsigned short* hHi, unsigned short* hLo,
          const float* __restrict__ snorm)
{
  __shared__ unsigned short WsH[112 * WS_STRIDE];
  __shared__ unsigned short WsL[112 * WS_STRIDE];

  const int t = threadIdx.x;
  const int lane = t & 63;
  const int wv = t >> 6;          // 0..7
  const int r15 = lane & 15;
  const int q = lane >> 4;
  const int m0 = blockIdx.x * 128 + wv * 16;

  f32x4 acc[7];
#pragma unroll
  for (int j = 0; j < 7; j++) acc[j] = f32x4{0.f, 0.f, 0.f, 0.f};

  auto do_seg = [&](const unsigned short* Ah, const unsigned short* Al, int lda, int K,
                    const unsigned short* Wh, const unsigned short* Wl, int ldw) {
    for (int k0 = 0; k0 < K; k0 += 64) {
      const int klen = (K - k0 >= 64) ? 64 : (K - k0);
      __syncthreads();   // previous chunk's LDS reads done
      if (klen == 64) {
        for (int u = t; u < 896; u += 512) {
          int row = u >> 3, kq = u & 7;
          *(uint4*)&WsH[row * WS_STRIDE + kq * 8] =
              *(const uint4*)&Wh[(size_t)row * ldw + k0 + kq * 8];
          *(uint4*)&WsL[row * WS_STRIDE + kq * 8] =
              *(const uint4*)&Wl[(size_t)row * ldw + k0 + kq * 8];
        }
      } else { // 32
        for (int u = t; u < 448; u += 512) {
          int row = u >> 2, kq = u & 3;
          *(uint4*)&WsH[row * WS_STRIDE + kq * 8] =
              *(const uint4*)&Wh[(size_t)row * ldw + k0 + kq * 8];
          *(uint4*)&WsL[row * WS_STRIDE + kq * 8] =
              *(const uint4*)&Wl[(size_t)row * ldw + k0 + kq * 8];
        }
      }
      // issue A loads for this chunk while staging completes
      bf16x8 a_h[2], a_l[2];
      const int ns = klen >> 5;
#pragma unroll
      for (int s = 0; s < 2; s++) {
        if (s < ns) {
          size_t base = (size_t)(m0 + r15) * lda + k0 + s * 32 + q * 8;
          a_h[s] = *(const bf16x8*)&Ah[base];
          a_l[s] = *(const bf16x8*)&Al[base];
        }
      }
      __syncthreads();   // staged W visible
#pragma unroll
      for (int s = 0; s < 2; s++) {
        if (s < ns) {
#pragma unroll
          for (int n = 0; n < 7; n++) {
            int wrow = n * 16 + r15;
            const bf16x8 bh = *(const bf16x8*)&WsH[wrow * WS_STRIDE + s * 32 + q * 8];
            const bf16x8 bl = *(const bf16x8*)&WsL[wrow * WS_STRIDE + s * 32 + q * 8];
            acc[n] = __builtin_amdgcn_mfma_f32_16x16x32_bf16(a_h[s], bh, acc[n], 0, 0, 0);
            acc[n] = __builtin_amdgcn_mfma_f32_16x16x32_bf16(a_h[s], bl, acc[n], 0, 0, 0);
            acc[n] = __builtin_amdgcn_mfma_f32_16x16x32_bf16(a_l[s], bh, acc[n], 0, 0, 0);
          }
        }
      }
    }
  };

  do_seg(A1h, A1l, lda1, K1, W1h, W1l, ldw1);
  if (A2h) do_seg(A2h, A2l, lda2, K2, W2h, W2l, ldw2);

  // ---------------- epilogue ----------------
  if (mode == 2) {
    // fused: v = acc+bias; L2-normalize row; relu; *snorm; h += v
    float ss[4] = {0.f, 0.f, 0.f, 0.f};
#pragma unroll
    for (int n = 0; n < 7; n++) {
      int col = n * 16 + r15;
      if (col < D) {
        float bv = bias[col];
#pragma unroll
        for (int r = 0; r < 4; r++) {
          float v = acc[n][r] + bv;
          ss[r] += v * v;
        }
      }
    }
#pragma unroll
    for (int m_ = 1; m_ <= 8; m_ <<= 1) {
#pragma unroll
      for (int r = 0; r < 4; r++) ss[r] += __shfl_xor(ss[r], m_, 64);
    }
    float inv[4], sn[4]; int rows[4];
#pragma unroll
    for (int r = 0; r < 4; r++) {
      rows[r] = m0 + q * 4 + r;
      float dn = fmaxf(sqrtf(ss[r]), 1e-12f);
      inv[r] = 1.0f / dn;
      sn[r] = (rows[r] < N_NODES) ? snorm[rows[r]] : 0.f;
    }
#pragma unroll
    for (int n = 0; n < 7; n++) {
      int col = n * 16 + r15;
      if (col >= D) continue;
      float bv = bias[col];
#pragma unroll
      for (int r = 0; r < 4; r++) {
        if (rows[r] >= N_NODES) continue;
        size_t idx = (size_t)rows[r] * KP_H + col;
        float hold = bf_bits2f(hHi[idx]) + bf_bits2f(hLo[idx]);
        float v = acc[n][r] + bv;
        float x = fmaxf(v * inv[r], 0.f) * sn[r];
        float nh = hold + x;
        unsigned short h_, l_; splitf(nh, h_, l_);
        hHi[idx] = h_; hLo[idx] = l_;
      }
    }
  } else {
#pragma unroll
    for (int n = 0; n < 7; n++) {
      int col = n * 16 + r15;
      if (col >= D) continue;
      float bv = bias[col];
#pragma unroll
      for (int r = 0; r < 4; r++) {
        int row = m0 + q * 4 + r;
        if (row >= N_NODES) continue;
        float v = acc[n][r] + bv;
        outH[(size_t)row * PSTRIDE + col] = __float2half_rn(fmaxf(v, 0.f));
      }
    }
  }
}

// ---------------- pull aggregation: one wave/node, 16 edges in flight ----------
// lane = (g, lp): g = edge slot (0..3), lp = 16B segment of the 256B row.
// esrc entries premultiplied by 16. 4x outer: four independent gathers/iter.
__global__ __launch_bounds__(256)
void k_aggregate(const __half* __restrict__ pooled, const int* __restrict__ offsets,
                 const int* __restrict__ esrc,
                 unsigned int* __restrict__ aggHi, unsigned int* __restrict__ aggLo)
{
  int t = threadIdx.x;
  int lane = t & 63;
  int g = lane >> 4;
  int lp = lane & 15;
  int v = blockIdx.x * 4 + (t >> 6);
  if (v >= N_PAD) return;
  float va[8];
#pragma unroll
  for (int j = 0; j < 8; j++) va[j] = 0.f;
  int s0 = 0, s1 = 0;
  if (v < N_NODES) { s0 = offsets[v]; s1 = offsets[v + 1]; }
  const uint4* P = (const uint4*)pooled;   // row = 16 uint4 (256B)
  int e = s0;
  for (; e + 15 < s1; e += 16) {
    unsigned o0 = (unsigned)esrc[e + g] + lp;
    unsigned o1 = (unsigned)esrc[e + 4 + g] + lp;
    unsigned o2 = (unsigned)esrc[e + 8 + g] + lp;
    unsigned o3 = (unsigned)esrc[e + 12 + g] + lp;
    uint4 u0 = P[o0];
    uint4 u1 = P[o1];
    uint4 u2 = P[o2];
    uint4 u3 = P[o3];
#pragma unroll
    for (int w = 0; w < 4; w++) {
      uint4 u = (w == 0) ? u0 : (w == 1) ? u1 : (w == 2) ? u2 : u3;
      float2 f0 = __half22float2(__builtin_bit_cast(__half2, u.x));
      float2 f1 = __half22float2(__builtin_bit_cast(__half2, u.y));
      float2 f2 = __half22float2(__builtin_bit_cast(__half2, u.z));
      float2 f3 = __half22float2(__builtin_bit_cast(__half2, u.w));
      va[0] += f0.x; va[1] += f0.y; va[2] += f1.x; va[3] += f1.y;
      va[4] += f2.x; va[5] += f2.y; va[6] += f3.x; va[7] += f3.y;
    }
  }
  for (; e + 7 < s1; e += 8) {
    unsigned o0 = (unsigned)esrc[e + g] + lp;
    unsigned o1 = (unsigned)esrc[e + 4 + g] + lp;
    uint4 u0 = P[o0];
    uint4 u1 = P[o1];
#pragma unroll
    for (int w = 0; w < 2; w++) {
      uint4 u = (w == 0) ? u0 : u1;
      float2 f0 = __half22float2(__builtin_bit_cast(__half2, u.x));
      float2 f1 = __half22float2(__builtin_bit_cast(__half2, u.y));
      float2 f2 = __half22float2(__builtin_bit_cast(__half2, u.z));
      float2 f3 = __half22float2(__builtin_bit_cast(__half2, u.w));
      va[0] += f0.x; va[1] += f0.y; va[2] += f1.x; va[3] += f1.y;
      va[4] += f2.x; va[5] += f2.y; va[6] += f3.x; va[7] += f3.y;
    }
  }
  for (; e < s1; e += 4) {
    int idx = e + g;
    if (idx < s1) {
      unsigned o = (unsigned)esrc[idx] + lp;
      uint4 u = P[o];
      float2 f0 = __half22float2(__builtin_bit_cast(__half2, u.x));
      float2 f1 = __half22float2(__builtin_bit_cast(__half2, u.y));
      float2 f2 = __half22float2(__builtin_bit_cast(__half2, u.z));
      float2 f3 = __half22float2(__builtin_bit_cast(__half2, u.w));
      va[0] += f0.x; va[1] += f0.y; va[2] += f1.x; va[3] += f1.y;
      va[4] += f2.x; va[5] += f2.y; va[6] += f3.x; va[7] += f3.y;
    }
  }
  // combine the 4 edge-slot groups (lanes with equal lp)
#pragma unroll
  for (int j = 0; j < 8; j++) {
    va[j] += __shfl_xor(va[j], 16, 64);
    va[j] += __shfl_xor(va[j], 32, 64);
  }
  if (g == 0) {
    int dgi = s1 - s0; if (dgi < 1) dgi = 1;
    float inv = 1.0f / (float)dgi;
    unsigned int hiw[4], low[4];
#pragma unroll
    for (int p = 0; p < 4; p++) {
      unsigned short h0, l0, h1, l1;
      splitf(va[2 * p] * inv, h0, l0);
      splitf(va[2 * p + 1] * inv, h1, l1);
      hiw[p] = (unsigned)h0 | ((unsigned)h1 << 16);
      low[p] = (unsigned)l0 | ((unsigned)l1 << 16);
    }
    *(uint4*)&aggHi[(size_t)v * 64 + lp * 4] = make_uint4(hiw[0], hiw[1], hiw[2], hiw[3]);
    *(uint4*)&aggLo[(size_t)v * 64 + lp * 4] = make_uint4(low[0], low[1], low[2], low[3]);
  }
}

// ---------------- per-graph mean, phase 1: 8 chunks/graph partial sums ----------
__global__ __launch_bounds__(256)
void k_gm_part(const unsigned short* __restrict__ hHi, const unsigned short* __restrict__ hLo,
               const int* __restrict__ gid, float* __restrict__ hgpart) {
  int g = blockIdx.x >> 3;
  int j = blockIdx.x & 7;
  int t = threadIdx.x;
  int c = t & 127, rp = t >> 7;
  // bounds of graph g (all threads redundantly)
  int lo = 0, hi = N_NODES;
  while (lo < hi) { int m = (lo + hi) >> 1; if (gid[m] < g) lo = m + 1; else hi = m; }
  int s = lo;
  hi = N_NODES;
  while (lo < hi) { int m = (lo + hi) >> 1; if (gid[m] < g + 1) lo = m + 1; else hi = m; }
  int e = lo;
  int per = ((e - s) + 7) >> 3;
  int vs = s + j * per;
  int ve = vs + per; if (ve > e) ve = e;
  float acc = 0.f;
  if (c < D) {
    for (int v = vs + rp; v < ve; v += 2) {
      size_t idx = (size_t)v * KP_H + c;
      acc += bf_bits2f(hHi[idx]) + bf_bits2f(hLo[idx]);
    }
  }
  __shared__ float part[2][128];
  part[rp][c] = acc;
  __syncthreads();
  if (rp == 0 && c < D)
    hgpart[(size_t)blockIdx.x * D + c] = part[0][c] + part[1][c];
}

// ---------------- per-graph mean, phase 2: reduce 8 chunks + divide ------------
__global__ __launch_bounds__(128)
void k_gm_fin(const float* __restrict__ hgpart, const int* __restrict__ gid,
              float* __restrict__ hg) {
  int g = blockIdx.x;
  int t = threadIdx.x;
  int lo = 0, hi = N_NODES;
  while (lo < hi) { int m = (lo + hi) >> 1; if (gid[m] < g) lo = m + 1; else hi = m; }
  int s = lo;
  hi = N_NODES;
  while (lo < hi) { int m = (lo + hi) >> 1; if (gid[m] < g + 1) lo = m + 1; else hi = m; }
  int cnt = lo - s; if (cnt < 1) cnt = 1;
  if (t < D) {
    float sum = 0.f;
#pragma unroll
    for (int j = 0; j < 8; j++) sum += hgpart[(size_t)(g * 8 + j) * D + t];
    hg[g * D + t] = sum / (float)cnt;
  }
}

// ---------------- MLP readout ----------------
__global__ __launch_bounds__(64)
void k_readout(const float* __restrict__ hg,
               const float* __restrict__ Wr0, const float* __restrict__ br0,
               const float* __restrict__ Wr1, const float* __restrict__ br1,
               const float* __restrict__ Wr2, const float* __restrict__ br2,
               float* __restrict__ out) {
  int g = blockIdx.x;
  int t = threadIdx.x;
  __shared__ float x0[D];
  __shared__ float x1[54];
  __shared__ float x2[27];
  for (int i = t; i < D; i += 64) x0[i] = hg[g * D + i];
  __syncthreads();
  if (t < 54) {
    float v = br0[t];
    for (int k = 0; k < D; k++) v += x0[k] * Wr0[t * D + k];
    x1[t] = fmaxf(v, 0.f);
  }
  __syncthreads();
  if (t < 27) {
    float v = br1[t];
    for (int k = 0; k < 54; k++) v += x1[k] * Wr1[t * 54 + k];
    x2[t] = fmaxf(v, 0.f);
  }
  __syncthreads();
  if (t < 10) {
    float v = br2[t];
    for (int k = 0; k < 27; k++) v += x2[k] * Wr2[t * 27 + k];
    out[g * 10 + t] = v;
  }
}

extern "C" void kernel_launch(void* const* d_in, const int* in_sizes, int n_in,
                              void* d_out, int out_size, void* d_ws, size_t ws_size,
                              hipStream_t stream) {
  const float* nodes_feat = (const float*)d_in[0];
  const float* snorm_n    = (const float*)d_in[1];
  const int*   src        = (const int*)d_in[2];
  const int*   dst        = (const int*)d_in[3];
  const int*   gid        = (const int*)d_in[4];
  const float* W_emb      = (const float*)d_in[6];
  const float* b_emb      = (const float*)d_in[7];
  const float* W_pool     = (const float*)d_in[8];
  const float* b_pool     = (const float*)d_in[9];
  const float* W_node     = (const float*)d_in[10];
  const float* b_node     = (const float*)d_in[11];
  const float* W_r0       = (const float*)d_in[12];
  const float* b_r0       = (const float*)d_in[13];
  const float* W_r1       = (const float*)d_in[14];
  const float* b_r1       = (const float*)d_in[15];
  const float* W_r2       = (const float*)d_in[16];
  const float* b_r2       = (const float*)d_in[17];
  float* out = (float*)d_out;

  char* ws = (char*)d_ws;
  size_t off = 0;
  auto alloc = [&](size_t bytes) { size_t o = off; off = (off + bytes + 255) & ~(size_t)255; return o; };

  __half* buf1 = (__half*)(ws + alloc((size_t)N_NODES * PSTRIDE * 2));  // pooled (fp16, padded)
  unsigned short* h_hi = (unsigned short*)(ws + alloc((size_t)N_PAD * KP_H * 2));
  unsigned short* h_lo = (unsigned short*)(ws + alloc((size_t)N_PAD * KP_H * 2));
  unsigned short* agg_hi = (unsigned short*)(ws + alloc((size_t)N_PAD * KP_H * 2));
  unsigned short* agg_lo = (unsigned short*)(ws + alloc((size_t)N_PAD * KP_H * 2));
  uint2* ebin = (uint2*)(ws + alloc((size_t)N_EDGES * 8));
  int* esrc  = (int*)(ws + alloc((size_t)N_EDGES * 4));
  int* offs  = (int*)(ws + alloc((size_t)(N_NODES + 1) * 4));
  int* bhist = (int*)(ws + alloc((size_t)(NBUCKET + 1) * 4));
  int* boffs = (int*)(ws + alloc((size_t)(NBUCKET + 1) * 4));
  int* bcur  = (int*)(ws + alloc((size_t)(NBUCKET + 1) * 4));
  unsigned short* wHi = (unsigned short*)(ws + alloc((size_t)W_TOTAL * 2));
  unsigned short* wLo = (unsigned short*)(ws + alloc((size_t)W_TOTAL * 2));
  float* hgpart = (float*)(ws + alloc((size_t)N_GRAPHS * 8 * D * 4));
  float* hg = (float*)(ws + alloc((size_t)N_GRAPHS * D * 4));
  (void)ws_size; (void)n_in; (void)in_sizes; (void)out_size;

  hipMemsetAsync(bhist, 0, (size_t)NBUCKET * 4, stream);

  // weight split + h pad init
  k_split_w<<<(W_TOTAL + 255) / 256, 256, 0, stream>>>(W_emb, W_pool, W_node, wHi, wLo);
  k_padinit<<<8192, 256, 0, stream>>>(h_hi, h_lo);

  // CSR build via bucket counting sort (writes offs + esrc premultiplied)
  const int EB = (N_EDGES + 2047) / 2048;  // 782
  k_bhist<<<EB, 256, 0, stream>>>(dst, bhist);
  k_bscan<<<1, 512, 0, stream>>>(bhist, boffs, bcur, offs);
  k_binscatter<<<EB, 256, 0, stream>>>(src, dst, bcur, ebin);
  k_scatter2<<<NBUCKET, 256, 0, stream>>>(ebin, boffs, offs, esrc);

  const int GEMM_GRID = N_PAD / 128;  // 782
  // embedding: h = nodes_feat @ W_emb^T + b_emb  (fp32 A fused split)
  k_mm_embed<<<GEMM_GRID, 512, 0, stream>>>(nodes_feat, wHi + WEMB_OFF, wLo + WEMB_OFF,
                                            b_emb, h_hi, h_lo);

  for (int l = 0; l < 4; l++) {
    const unsigned short* wpH = wHi + WPOOL_OFF + (size_t)l * 14336;
    const unsigned short* wpL = wLo + WPOOL_OFF + (size_t)l * 14336;
    const unsigned short* wn1H = wHi + WNODE1_OFF + (size_t)l * 14336;
    const unsigned short* wn1L = wLo + WNODE1_OFF + (size_t)l * 14336;
    const unsigned short* wn2H = wHi + WNODE2_OFF + (size_t)l * 14336;
    const unsigned short* wn2L = wLo + WNODE2_OFF + (size_t)l * 14336;
    const float* bp = b_pool + (size_t)l * D;
    const float* bn = b_node + (size_t)l * D;

    // pooled = relu(h @ Wp^T + bp)  (fp16 out, padded stride)
    k_mm<<<GEMM_GRID, 512, 0, stream>>>(h_hi, h_lo, KP_H, KP_H,
                                        wpH, wpL, KP_H,
                                        nullptr, nullptr, 0, 0, nullptr, nullptr, 0,
                                        bp, 1, buf1, nullptr, nullptr, nullptr);
    // agg = mean_in(pooled)
    k_aggregate<<<N_PAD / 4, 256, 0, stream>>>(buf1, offs, esrc,
                                               (unsigned int*)agg_hi, (unsigned int*)agg_lo);
    // h += relu(normalize(h@Wn1^T + agg@Wn2^T + bn)) * snorm   (fused)
    k_mm<<<GEMM_GRID, 512, 0, stream>>>(h_hi, h_lo, KP_H, KP_H,
                                        wn1H, wn1L, KP_H,
                                        agg_hi, agg_lo, KP_H, KP_H,
                                        wn2H, wn2L, KP_H,
                                        bn, 2, nullptr, h_hi, h_lo, snorm_n);
  }

  k_gm_part<<<N_GRAPHS * 8, 256, 0, stream>>>(h_hi, h_lo, gid, hgpart);
  k_gm_fin<<<N_GRAPHS, 128, 0, stream>>>(hgpart, gid, hg);
  k_readout<<<N_GRAPHS, 64, 0, stream>>>(hg, W_r0, b_r0, W_r1, b_r1, W_r2, b_r2, out);
}

// Round 15
// 704.310 us; speedup vs baseline: 1.2862x; 1.0459x over previous
//
#include <hip/hip_runtime.h>
#include <hip/hip_bf16.h>
#include <hip/hip_fp16.h>

#define N_NODES  100000
#define N_PAD    100096
#define N_EDGES  1600000
#define N_GRAPHS 128
#define D        108
#define IN_DIM   146
#define KP_H     128
#define KP_NF    160
#define PSTRIDE  128      // pooled row stride in halves (256B, line-aligned)
#define NBUCKET  391      // ceil(N_NODES/256)
#define LBUF     8192     // per-bucket LDS scatter buffer (max bucket edges ~4400)

typedef __bf16 bf16x8 __attribute__((ext_vector_type(8)));
typedef float  f32x4  __attribute__((ext_vector_type(4)));

__device__ __forceinline__ unsigned short f2bf_bits(float v) {
  __hip_bfloat16 b = __float2bfloat16(v);
  return __builtin_bit_cast(unsigned short, b);
}
__device__ __forceinline__ float bf_bits2f(unsigned short u) {
  __hip_bfloat16 b = __builtin_bit_cast(__hip_bfloat16, u);
  return __bfloat162float(b);
}
__device__ __forceinline__ void splitf(float v, unsigned short& hi, unsigned short& lo) {
  hi = f2bf_bits(v);
  lo = f2bf_bits(v - bf_bits2f(hi));
}

// ---------------- bucket histogram (LDS-batched) ----------------
__global__ __launch_bounds__(256)
void k_bhist(const int* __restrict__ dst, int* __restrict__ bhist) {
  __shared__ int bh[NBUCKET];
  int t = threadIdx.x;
  for (int i = t; i < NBUCKET; i += 256) bh[i] = 0;
  __syncthreads();
  int e0 = blockIdx.x * 2048;
#pragma unroll
  for (int j = 0; j < 8; j++) {
    int e = e0 + j * 256 + t;
    if (e < N_EDGES) atomicAdd(&bh[dst[e] >> 8], 1);
  }
  __syncthreads();
  for (int i = t; i < NBUCKET; i += 256)
    if (bh[i]) atomicAdd(&bhist[i], bh[i]);
}

// ---------------- bucket scan (one block) ----------------
__global__ __launch_bounds__(512)
void k_bscan(const int* __restrict__ bhist, int* __restrict__ boffs,
             int* __restrict__ bcur, int* __restrict__ offs) {
  __shared__ int sh[512];
  int t = threadIdx.x;
  sh[t] = (t < NBUCKET) ? bhist[t] : 0;
  __syncthreads();
  for (int off = 1; off < 512; off <<= 1) {
    int v = (t >= off) ? sh[t - off] : 0;
    __syncthreads();
    sh[t] += v;
    __syncthreads();
  }
  if (t < NBUCKET) {
    int excl = (t > 0) ? sh[t - 1] : 0;
    boffs[t] = excl;
    bcur[t]  = excl;
  }
  if (t == 0) { boffs[NBUCKET] = N_EDGES; offs[N_NODES] = N_EDGES; }
}

// ---------------- bin edges into bucket-contiguous ebin (LDS-batched ranks) ----
__global__ __launch_bounds__(256)
void k_binscatter(const int* __restrict__ src, const int* __restrict__ dst,
                  int* __restrict__ bcur, uint2* __restrict__ ebin) {
  __shared__ int lhist[NBUCKET];
  __shared__ int lbase[NBUCKET];
  int t = threadIdx.x;
  for (int i = t; i < NBUCKET; i += 256) lhist[i] = 0;
  __syncthreads();
  int e0 = blockIdx.x * 2048;
  int s[8], d[8], r[8];
#pragma unroll
  for (int j = 0; j < 8; j++) {
    int e = e0 + j * 256 + t;
    if (e < N_EDGES) {
      s[j] = src[e]; d[j] = dst[e];
      r[j] = atomicAdd(&lhist[d[j] >> 8], 1);
    }
  }
  __syncthreads();
  for (int i = t; i < NBUCKET; i += 256)
    lbase[i] = lhist[i] ? atomicAdd(&bcur[i], lhist[i]) : 0;
  __syncthreads();
#pragma unroll
  for (int j = 0; j < 8; j++) {
    int e = e0 + j * 256 + t;
    if (e < N_EDGES)
      ebin[(size_t)lbase[d[j] >> 8] + r[j]] = make_uint2((unsigned)s[j], (unsigned)d[j]);
  }
}

// ---------------- per-bucket local CSR: writes offs + coalesced esrc ----------
// esrc entries are PREMULTIPLIED by 16 (uint4-index of the pooled row).
__global__ __launch_bounds__(256)
void k_scatter2(const uint2* __restrict__ ebin, const int* __restrict__ boffs,
                int* __restrict__ offs, int* __restrict__ esrc) {
  __shared__ int lcnt[256];
  __shared__ int lcur[256];
  __shared__ int lbuf[LBUF];
  int b = blockIdx.x;
  int t = threadIdx.x;
  int vbase = b << 8;
  int estart = boffs[b], eend = boffs[b + 1];
  int cnt = eend - estart;
  lcnt[t] = 0;
  __syncthreads();
  for (int e = estart + t; e < eend; e += 256)
    atomicAdd(&lcnt[ebin[e].y & 255], 1);
  __syncthreads();
  // inclusive scan of lcnt (in-place Hillis-Steele)
  for (int off = 1; off < 256; off <<= 1) {
    int v = (t >= off) ? lcnt[t - off] : 0;
    __syncthreads();
    lcnt[t] += v;
    __syncthreads();
  }
  int excl = (t > 0) ? lcnt[t - 1] : 0;
  int v = vbase + t;
  if (v < N_NODES) offs[v] = estart + excl;
  lcur[t] = excl;
  __syncthreads();
  if (cnt <= LBUF) {
    for (int e = estart + t; e < eend; e += 256) {
      uint2 u = ebin[e];
      int pos = atomicAdd(&lcur[u.y & 255], 1);
      lbuf[pos] = (int)(u.x << 4);
    }
    __syncthreads();
    for (int i = t; i < cnt; i += 256) esrc[estart + i] = lbuf[i];
  } else {   // safety fallback (statistically unreachable)
    for (int e = estart + t; e < eend; e += 256) {
      uint2 u = ebin[e];
      int pos = atomicAdd(&lcur[u.y & 255], 1);
      esrc[estart + pos] = (int)(u.x << 4);
    }
  }
}

// ---------------- split + pad all weights into one packed pair ----------------
// layout: [0,17920) Wemb [112][160]; then 4x wpool [112][128]; 4x wnode1; 4x wnode2
#define WEMB_OFF   0
#define WPOOL_OFF  17920
#define WNODE1_OFF (17920 + 4*14336)
#define WNODE2_OFF (17920 + 8*14336)
#define W_TOTAL    (17920 + 12*14336)

__global__ void k_split_w(const float* __restrict__ W_emb, const float* __restrict__ W_pool,
                          const float* __restrict__ W_node,
                          unsigned short* __restrict__ hi, unsigned short* __restrict__ lo) {
  size_t stride = (size_t)gridDim.x * blockDim.x;
  for (size_t i = (size_t)blockIdx.x * blockDim.x + threadIdx.x; i < W_TOTAL; i += stride) {
    float v = 0.f;
    if (i < WPOOL_OFF) {
      int r = (int)(i / KP_NF), k = (int)(i % KP_NF);
      if (r < D && k < IN_DIM) v = W_emb[(size_t)r * IN_DIM + k];
    } else {
      size_t i2 = i - WPOOL_OFF;
      int seg = (int)(i2 / (4 * 14336));
      size_t r2 = i2 % (4 * 14336);
      int l = (int)(r2 / 14336);
      int n = (int)((r2 % 14336) / KP_H);
      int k = (int)(r2 % KP_H);
      if (n < D && k < D) {
        if (seg == 0)      v = W_pool[(size_t)l * D * D + (size_t)n * D + k];
        else if (seg == 1) v = W_node[(size_t)l * D * 2 * D + (size_t)n * 2 * D + k];
        else               v = W_node[(size_t)l * D * 2 * D + (size_t)n * 2 * D + D + k];
      }
    }
    unsigned short h, l2; splitf(v, h, l2);
    hi[i] = h; lo[i] = l2;
  }
}

// ---------------- embed GEMM: fp32 A (nodes_feat, unpadded) -> split h ----------
// grid 782, block 512 (8 waves), M-tile 128 (16 rows/wave), n-tile 112 (7x16)
// Also writes h pad (cols 112..127 and rows >= N_NODES) = 0, replacing k_padinit.
#define WS_STRIDE 76
__global__ __launch_bounds__(512)
void k_mm_embed(const float* __restrict__ Af,
                const unsigned short* __restrict__ Wh_, const unsigned short* __restrict__ Wl_,
                const float* __restrict__ bias,
                unsigned short* __restrict__ hHi, unsigned short* __restrict__ hLo)
{
  __shared__ unsigned short WsH[112 * WS_STRIDE];
  __shared__ unsigned short WsL[112 * WS_STRIDE];

  const int t = threadIdx.x;
  const int lane = t & 63;
  const int wv = t >> 6;
  const int r15 = lane & 15;
  const int q = lane >> 4;
  const int m0 = blockIdx.x * 128 + wv * 16;
  const int row = m0 + r15;
  const bool rok = row < N_NODES;
  const float* rp_ = Af + (size_t)row * IN_DIM;

  f32x4 acc[7];
#pragma unroll
  for (int j = 0; j < 7; j++) acc[j] = f32x4{0.f, 0.f, 0.f, 0.f};

  for (int k0 = 0; k0 < KP_NF; k0 += 64) {
    const int klen = (KP_NF - k0 >= 64) ? 64 : (KP_NF - k0);
    const int ns = klen >> 5;
    __syncthreads();
    if (klen == 64) {
      for (int u = t; u < 896; u += 512) {
        int r_ = u >> 3, kq = u & 7;
        *(uint4*)&WsH[r_ * WS_STRIDE + kq * 8] =
            *(const uint4*)&Wh_[(size_t)r_ * KP_NF + k0 + kq * 8];
        *(uint4*)&WsL[r_ * WS_STRIDE + kq * 8] =
            *(const uint4*)&Wl_[(size_t)r_ * KP_NF + k0 + kq * 8];
      }
    } else {
      for (int u = t; u < 448; u += 512) {
        int r_ = u >> 2, kq = u & 3;
        *(uint4*)&WsH[r_ * WS_STRIDE + kq * 8] =
            *(const uint4*)&Wh_[(size_t)r_ * KP_NF + k0 + kq * 8];
        *(uint4*)&WsL[r_ * WS_STRIDE + kq * 8] =
            *(const uint4*)&Wl_[(size_t)r_ * KP_NF + k0 + kq * 8];
      }
    }
    // load + split A fragments from fp32 (vectorized when fully in-bounds)
    bf16x8 a_h[2], a_l[2];
#pragma unroll
    for (int s = 0; s < 2; s++) {
      if (s < ns) {
        int kb = k0 + s * 32 + q * 8;
        float vv[8];
        if (rok && kb + 8 <= IN_DIM) {
          const float2* pf = (const float2*)(rp_ + kb);   // 8B-aligned always
          float2 f0 = pf[0], f1 = pf[1], f2 = pf[2], f3 = pf[3];
          vv[0] = f0.x; vv[1] = f0.y; vv[2] = f1.x; vv[3] = f1.y;
          vv[4] = f2.x; vv[5] = f2.y; vv[6] = f3.x; vv[7] = f3.y;
        } else {
#pragma unroll
          for (int j = 0; j < 8; j++) {
            int k = kb + j;
            vv[j] = (rok && k < IN_DIM) ? rp_[k] : 0.f;
          }
        }
#pragma unroll
        for (int j = 0; j < 8; j++) {
          unsigned short h_, l_; splitf(vv[j], h_, l_);
          a_h[s][j] = __builtin_bit_cast(__bf16, h_);
          a_l[s][j] = __builtin_bit_cast(__bf16, l_);
        }
      }
    }
    __syncthreads();
#pragma unroll
    for (int s = 0; s < 2; s++) {
      if (s < ns) {
#pragma unroll
        for (int n = 0; n < 7; n++) {
          int wrow = n * 16 + r15;
          const bf16x8 bh = *(const bf16x8*)&WsH[wrow * WS_STRIDE + s * 32 + q * 8];
          const bf16x8 bl = *(const bf16x8*)&WsL[wrow * WS_STRIDE + s * 32 + q * 8];
          acc[n] = __builtin_amdgcn_mfma_f32_16x16x32_bf16(a_h[s], bh, acc[n], 0, 0, 0);
          acc[n] = __builtin_amdgcn_mfma_f32_16x16x32_bf16(a_h[s], bl, acc[n], 0, 0, 0);
          acc[n] = __builtin_amdgcn_mfma_f32_16x16x32_bf16(a_l[s], bh, acc[n], 0, 0, 0);
        }
      }
    }
  }

  // epilogue: write full [row][0..127] including pad zeros (replaces k_padinit)
#pragma unroll
  for (int n = 0; n < 7; n++) {
    int col = n * 16 + r15;
    float bv = (col < D) ? bias[col] : 0.f;
#pragma unroll
    for (int r = 0; r < 4; r++) {
      int orow = m0 + q * 4 + r;
      float v = (orow < N_NODES && col < D) ? (acc[n][r] + bv) : 0.f;
      unsigned short h_, l_; splitf(v, h_, l_);
      hHi[(size_t)orow * KP_H + col] = h_;
      hLo[(size_t)orow * KP_H + col] = l_;
    }
  }
  {
    int col = 112 + r15;
#pragma unroll
    for (int r = 0; r < 4; r++) {
      int orow = m0 + q * 4 + r;
      hHi[(size_t)orow * KP_H + col] = 0;
      hLo[(size_t)orow * KP_H + col] = 0;
    }
  }
}

// ---------------- MFMA split-bf16 GEMM, LDS-staged W, 8 waves R=1 ----------------
// grid 782, block 512 (8 waves), M-tile 128 (16 rows/wave), n-tile 112 (7x16)
// modes: 1 = pool (fp16 out + relu, PSTRIDE), 2 = node (fused norm/res)
__global__ __launch_bounds__(512)
void k_mm(const unsigned short* A1h, const unsigned short* A1l, int lda1, int K1,
          const unsigned short* __restrict__ W1h, const unsigned short* __restrict__ W1l, int ldw1,
          const unsigned short* A2h, const unsigned short* A2l, int lda2, int K2,
          const unsigned short* __restrict__ W2h, const unsigned short* __restrict__ W2l, int ldw2,
          const float* __restrict__ bias, int mode,
          __half* __restrict__ outH,
          unsigned short* hHi, unsigned short* hLo,
          const float* __restrict__ snorm)
{
  __shared__ unsigned short WsH[112 * WS_STRIDE];
  __shared__ unsigned short WsL[112 * WS_STRIDE];

  const int t = threadIdx.x;
  const int lane = t & 63;
  const int wv = t >> 6;          // 0..7
  const int r15 = lane & 15;
  const int q = lane >> 4;
  const int m0 = blockIdx.x * 128 + wv * 16;

  f32x4 acc[7];
#pragma unroll
  for (int j = 0; j < 7; j++) acc[j] = f32x4{0.f, 0.f, 0.f, 0.f};

  auto do_seg = [&](const unsigned short* Ah, const unsigned short* Al, int lda, int K,
                    const unsigned short* Wh, const unsigned short* Wl, int ldw) {
    for (int k0 = 0; k0 < K; k0 += 64) {
      const int klen = (K - k0 >= 64) ? 64 : (K - k0);
      __syncthreads();   // previous chunk's LDS reads done
      if (klen == 64) {
        for (int u = t; u < 896; u += 512) {
          int row = u >> 3, kq = u & 7;
          *(uint4*)&WsH[row * WS_STRIDE + kq * 8] =
              *(const uint4*)&Wh[(size_t)row * ldw + k0 + kq * 8];
          *(uint4*)&WsL[row * WS_STRIDE + kq * 8] =
              *(const uint4*)&Wl[(size_t)row * ldw + k0 + kq * 8];
        }
      } else { // 32
        for (int u = t; u < 448; u += 512) {
          int row = u >> 2, kq = u & 3;
          *(uint4*)&WsH[row * WS_STRIDE + kq * 8] =
              *(const uint4*)&Wh[(size_t)row * ldw + k0 + kq * 8];
          *(uint4*)&WsL[row * WS_STRIDE + kq * 8] =
              *(const uint4*)&Wl[(size_t)row * ldw + k0 + kq * 8];
        }
      }
      // issue A loads for this chunk while staging completes
      bf16x8 a_h[2], a_l[2];
      const int ns = klen >> 5;
#pragma unroll
      for (int s = 0; s < 2; s++) {
        if (s < ns) {
          size_t base = (size_t)(m0 + r15) * lda + k0 + s * 32 + q * 8;
          a_h[s] = *(const bf16x8*)&Ah[base];
          a_l[s] = *(const bf16x8*)&Al[base];
        }
      }
      __syncthreads();   // staged W visible
#pragma unroll
      for (int s = 0; s < 2; s++) {
        if (s < ns) {
#pragma unroll
          for (int n = 0; n < 7; n++) {
            int wrow = n * 16 + r15;
            const bf16x8 bh = *(const bf16x8*)&WsH[wrow * WS_STRIDE + s * 32 + q * 8];
            const bf16x8 bl = *(const bf16x8*)&WsL[wrow * WS_STRIDE + s * 32 + q * 8];
            acc[n] = __builtin_amdgcn_mfma_f32_16x16x32_bf16(a_h[s], bh, acc[n], 0, 0, 0);
            acc[n] = __builtin_amdgcn_mfma_f32_16x16x32_bf16(a_h[s], bl, acc[n], 0, 0, 0);
            acc[n] = __builtin_amdgcn_mfma_f32_16x16x32_bf16(a_l[s], bh, acc[n], 0, 0, 0);
          }
        }
      }
    }
  };

  do_seg(A1h, A1l, lda1, K1, W1h, W1l, ldw1);
  if (A2h) do_seg(A2h, A2l, lda2, K2, W2h, W2l, ldw2);

  // ---------------- epilogue ----------------
  if (mode == 2) {
    // fused: v = acc+bias; L2-normalize row; relu; *snorm; h += v
    float ss[4] = {0.f, 0.f, 0.f, 0.f};
#pragma unroll
    for (int n = 0; n < 7; n++) {
      int col = n * 16 + r15;
      if (col < D) {
        float bv = bias[col];
#pragma unroll
        for (int r = 0; r < 4; r++) {
          float v = acc[n][r] + bv;
          ss[r] += v * v;
        }
      }
    }
#pragma unroll
    for (int m_ = 1; m_ <= 8; m_ <<= 1) {
#pragma unroll
      for (int r = 0; r < 4; r++) ss[r] += __shfl_xor(ss[r], m_, 64);
    }
    float inv[4], sn[4]; int rows[4];
#pragma unroll
    for (int r = 0; r < 4; r++) {
      rows[r] = m0 + q * 4 + r;
      float dn = fmaxf(sqrtf(ss[r]), 1e-12f);
      inv[r] = 1.0f / dn;
      sn[r] = (rows[r] < N_NODES) ? snorm[rows[r]] : 0.f;
    }
#pragma unroll
    for (int n = 0; n < 7; n++) {
      int col = n * 16 + r15;
      if (col >= D) continue;
      float bv = bias[col];
#pragma unroll
      for (int r = 0; r < 4; r++) {
        if (rows[r] >= N_NODES) continue;
        size_t idx = (size_t)rows[r] * KP_H + col;
        float hold = bf_bits2f(hHi[idx]) + bf_bits2f(hLo[idx]);
        float v = acc[n][r] + bv;
        float x = fmaxf(v * inv[r], 0.f) * sn[r];
        float nh = hold + x;
        unsigned short h_, l_; splitf(nh, h_, l_);
        hHi[idx] = h_; hLo[idx] = l_;
      }
    }
  } else {
#pragma unroll
    for (int n = 0; n < 7; n++) {
      int col = n * 16 + r15;
      if (col >= D) continue;
      float bv = bias[col];
#pragma unroll
      for (int r = 0; r < 4; r++) {
        int row = m0 + q * 4 + r;
        if (row >= N_NODES) continue;
        float v = acc[n][r] + bv;
        outH[(size_t)row * PSTRIDE + col] = __float2half_rn(fmaxf(v, 0.f));
      }
    }
  }
}

// ---------------- pull aggregation: one wave/node, 16 edges in flight ----------
// lane = (g, lp): g = edge slot (0..3), lp = 16B segment of the 256B row.
// esrc entries premultiplied by 16. 4x outer: four independent gathers/iter.
__global__ __launch_bounds__(256)
void k_aggregate(const __half* __restrict__ pooled, const int* __restrict__ offsets,
                 const int* __restrict__ esrc,
                 unsigned int* __restrict__ aggHi, unsigned int* __restrict__ aggLo)
{
  int t = threadIdx.x;
  int lane = t & 63;
  int g = lane >> 4;
  int lp = lane & 15;
  int v = blockIdx.x * 4 + (t >> 6);
  if (v >= N_PAD) return;
  float va[8];
#pragma unroll
  for (int j = 0; j < 8; j++) va[j] = 0.f;
  int s0 = 0, s1 = 0;
  if (v < N_NODES) { s0 = offsets[v]; s1 = offsets[v + 1]; }
  const uint4* P = (const uint4*)pooled;   // row = 16 uint4 (256B)
  int e = s0;
  for (; e + 15 < s1; e += 16) {
    unsigned o0 = (unsigned)esrc[e + g] + lp;
    unsigned o1 = (unsigned)esrc[e + 4 + g] + lp;
    unsigned o2 = (unsigned)esrc[e + 8 + g] + lp;
    unsigned o3 = (unsigned)esrc[e + 12 + g] + lp;
    uint4 u0 = P[o0];
    uint4 u1 = P[o1];
    uint4 u2 = P[o2];
    uint4 u3 = P[o3];
#pragma unroll
    for (int w = 0; w < 4; w++) {
      uint4 u = (w == 0) ? u0 : (w == 1) ? u1 : (w == 2) ? u2 : u3;
      float2 f0 = __half22float2(__builtin_bit_cast(__half2, u.x));
      float2 f1 = __half22float2(__builtin_bit_cast(__half2, u.y));
      float2 f2 = __half22float2(__builtin_bit_cast(__half2, u.z));
      float2 f3 = __half22float2(__builtin_bit_cast(__half2, u.w));
      va[0] += f0.x; va[1] += f0.y; va[2] += f1.x; va[3] += f1.y;
      va[4] += f2.x; va[5] += f2.y; va[6] += f3.x; va[7] += f3.y;
    }
  }
  for (; e + 7 < s1; e += 8) {
    unsigned o0 = (unsigned)esrc[e + g] + lp;
    unsigned o1 = (unsigned)esrc[e + 4 + g] + lp;
    uint4 u0 = P[o0];
    uint4 u1 = P[o1];
#pragma unroll
    for (int w = 0; w < 2; w++) {
      uint4 u = (w == 0) ? u0 : u1;
      float2 f0 = __half22float2(__builtin_bit_cast(__half2, u.x));
      float2 f1 = __half22float2(__builtin_bit_cast(__half2, u.y));
      float2 f2 = __half22float2(__builtin_bit_cast(__half2, u.z));
      float2 f3 = __half22float2(__builtin_bit_cast(__half2, u.w));
      va[0] += f0.x; va[1] += f0.y; va[2] += f1.x; va[3] += f1.y;
      va[4] += f2.x; va[5] += f2.y; va[6] += f3.x; va[7] += f3.y;
    }
  }
  for (; e < s1; e += 4) {
    int idx = e + g;
    if (idx < s1) {
      unsigned o = (unsigned)esrc[idx] + lp;
      uint4 u = P[o];
      float2 f0 = __half22float2(__builtin_bit_cast(__half2, u.x));
      float2 f1 = __half22float2(__builtin_bit_cast(__half2, u.y));
      float2 f2 = __half22float2(__builtin_bit_cast(__half2, u.z));
      float2 f3 = __half22float2(__builtin_bit_cast(__half2, u.w));
      va[0] += f0.x; va[1] += f0.y; va[2] += f1.x; va[3] += f1.y;
      va[4] += f2.x; va[5] += f2.y; va[6] += f3.x; va[7] += f3.y;
    }
  }
  // combine the 4 edge-slot groups (lanes with equal lp)
#pragma unroll
  for (int j = 0; j < 8; j++) {
    va[j] += __shfl_xor(va[j], 16, 64);
    va[j] += __shfl_xor(va[j], 32, 64);
  }
  if (g == 0) {
    int dgi = s1 - s0; if (dgi < 1) dgi = 1;
    float inv = 1.0f / (float)dgi;
    unsigned int hiw[4], low[4];
#pragma unroll
    for (int p = 0; p < 4; p++) {
      unsigned short h0, l0, h1, l1;
      splitf(va[2 * p] * inv, h0, l0);
      splitf(va[2 * p + 1] * inv, h1, l1);
      hiw[p] = (unsigned)h0 | ((unsigned)h1 << 16);
      low[p] = (unsigned)l0 | ((unsigned)l1 << 16);
    }
    *(uint4*)&aggHi[(size_t)v * 64 + lp * 4] = make_uint4(hiw[0], hiw[1], hiw[2], hiw[3]);
    *(uint4*)&aggLo[(size_t)v * 64 + lp * 4] = make_uint4(low[0], low[1], low[2], low[3]);
  }
}

// ---------------- per-graph mean, phase 1: 8 chunks/graph partial sums ----------
__global__ __launch_bounds__(256)
void k_gm_part(const unsigned short* __restrict__ hHi, const unsigned short* __restrict__ hLo,
               const int* __restrict__ gid, float* __restrict__ hgpart) {
  int g = blockIdx.x >> 3;
  int j = blockIdx.x & 7;
  int t = threadIdx.x;
  int c = t & 127, rp = t >> 7;
  // bounds of graph g (all threads redundantly)
  int lo = 0, hi = N_NODES;
  while (lo < hi) { int m = (lo + hi) >> 1; if (gid[m] < g) lo = m + 1; else hi = m; }
  int s = lo;
  hi = N_NODES;
  while (lo < hi) { int m = (lo + hi) >> 1; if (gid[m] < g + 1) lo = m + 1; else hi = m; }
  int e = lo;
  int per = ((e - s) + 7) >> 3;
  int vs = s + j * per;
  int ve = vs + per; if (ve > e) ve = e;
  float acc = 0.f;
  if (c < D) {
    for (int v = vs + rp; v < ve; v += 2) {
      size_t idx = (size_t)v * KP_H + c;
      acc += bf_bits2f(hHi[idx]) + bf_bits2f(hLo[idx]);
    }
  }
  __shared__ float part[2][128];
  part[rp][c] = acc;
  __syncthreads();
  if (rp == 0 && c < D)
    hgpart[(size_t)blockIdx.x * D + c] = part[0][c] + part[1][c];
}

// ---------------- per-graph mean, phase 2: reduce 8 chunks + divide ------------
__global__ __launch_bounds__(128)
void k_gm_fin(const float* __restrict__ hgpart, const int* __restrict__ gid,
              float* __restrict__ hg) {
  int g = blockIdx.x;
  int t = threadIdx.x;
  int lo = 0, hi = N_NODES;
  while (lo < hi) { int m = (lo + hi) >> 1; if (gid[m] < g) lo = m + 1; else hi = m; }
  int s = lo;
  hi = N_NODES;
  while (lo < hi) { int m = (lo + hi) >> 1; if (gid[m] < g + 1) lo = m + 1; else hi = m; }
  int cnt = lo - s; if (cnt < 1) cnt = 1;
  if (t < D) {
    float sum = 0.f;
#pragma unroll
    for (int j = 0; j < 8; j++) sum += hgpart[(size_t)(g * 8 + j) * D + t];
    hg[g * D + t] = sum / (float)cnt;
  }
}

// ---------------- MLP readout ----------------
__global__ __launch_bounds__(64)
void k_readout(const float* __restrict__ hg,
               const float* __restrict__ Wr0, const float* __restrict__ br0,
               const float* __restrict__ Wr1, const float* __restrict__ br1,
               const float* __restrict__ Wr2, const float* __restrict__ br2,
               float* __restrict__ out) {
  int g = blockIdx.x;
  int t = threadIdx.x;
  __shared__ float x0[D];
  __shared__ float x1[54];
  __shared__ float x2[27];
  for (int i = t; i < D; i += 64) x0[i] = hg[g * D + i];
  __syncthreads();
  if (t < 54) {
    float v = br0[t];
    for (int k = 0; k < D; k++) v += x0[k] * Wr0[t * D + k];
    x1[t] = fmaxf(v, 0.f);
  }
  __syncthreads();
  if (t < 27) {
    float v = br1[t];
    for (int k = 0; k < 54; k++) v += x1[k] * Wr1[t * 54 + k];
    x2[t] = fmaxf(v, 0.f);
  }
  __syncthreads();
  if (t < 10) {
    float v = br2[t];
    for (int k = 0; k < 27; k++) v += x2[k] * Wr2[t * 27 + k];
    out[g * 10 + t] = v;
  }
}

extern "C" void kernel_launch(void* const* d_in, const int* in_sizes, int n_in,
                              void* d_out, int out_size, void* d_ws, size_t ws_size,
                              hipStream_t stream) {
  const float* nodes_feat = (const float*)d_in[0];
  const float* snorm_n    = (const float*)d_in[1];
  const int*   src        = (const int*)d_in[2];
  const int*   dst        = (const int*)d_in[3];
  const int*   gid        = (const int*)d_in[4];
  const float* W_emb      = (const float*)d_in[6];
  const float* b_emb      = (const float*)d_in[7];
  const float* W_pool     = (const float*)d_in[8];
  const float* b_pool     = (const float*)d_in[9];
  const float* W_node     = (const float*)d_in[10];
  const float* b_node     = (const float*)d_in[11];
  const float* W_r0       = (const float*)d_in[12];
  const float* b_r0       = (const float*)d_in[13];
  const float* W_r1       = (const float*)d_in[14];
  const float* b_r1       = (const float*)d_in[15];
  const float* W_r2       = (const float*)d_in[16];
  const float* b_r2       = (const float*)d_in[17];
  float* out = (float*)d_out;

  char* ws = (char*)d_ws;
  size_t off = 0;
  auto alloc = [&](size_t bytes) { size_t o = off; off = (off + bytes + 255) & ~(size_t)255; return o; };

  __half* buf1 = (__half*)(ws + alloc((size_t)N_NODES * PSTRIDE * 2));  // pooled (fp16, padded)
  unsigned short* h_hi = (unsigned short*)(ws + alloc((size_t)N_PAD * KP_H * 2));
  unsigned short* h_lo = (unsigned short*)(ws + alloc((size_t)N_PAD * KP_H * 2));
  unsigned short* agg_hi = (unsigned short*)(ws + alloc((size_t)N_PAD * KP_H * 2));
  unsigned short* agg_lo = (unsigned short*)(ws + alloc((size_t)N_PAD * KP_H * 2));
  uint2* ebin = (uint2*)(ws + alloc((size_t)N_EDGES * 8));
  int* esrc  = (int*)(ws + alloc((size_t)N_EDGES * 4));
  int* offs  = (int*)(ws + alloc((size_t)(N_NODES + 1) * 4));
  int* bhist = (int*)(ws + alloc((size_t)(NBUCKET + 1) * 4));
  int* boffs = (int*)(ws + alloc((size_t)(NBUCKET + 1) * 4));
  int* bcur  = (int*)(ws + alloc((size_t)(NBUCKET + 1) * 4));
  unsigned short* wHi = (unsigned short*)(ws + alloc((size_t)W_TOTAL * 2));
  unsigned short* wLo = (unsigned short*)(ws + alloc((size_t)W_TOTAL * 2));
  float* hgpart = (float*)(ws + alloc((size_t)N_GRAPHS * 8 * D * 4));
  float* hg = (float*)(ws + alloc((size_t)N_GRAPHS * D * 4));
  (void)ws_size; (void)n_in; (void)in_sizes; (void)out_size;

  hipMemsetAsync(bhist, 0, (size_t)NBUCKET * 4, stream);

  // weight split
  k_split_w<<<(W_TOTAL + 255) / 256, 256, 0, stream>>>(W_emb, W_pool, W_node, wHi, wLo);

  // CSR build via bucket counting sort (writes offs + esrc premultiplied)
  const int EB = (N_EDGES + 2047) / 2048;  // 782
  k_bhist<<<EB, 256, 0, stream>>>(dst, bhist);
  k_bscan<<<1, 512, 0, stream>>>(bhist, boffs, bcur, offs);
  k_binscatter<<<EB, 256, 0, stream>>>(src, dst, bcur, ebin);
  k_scatter2<<<NBUCKET, 256, 0, stream>>>(ebin, boffs, offs, esrc);

  const int GEMM_GRID = N_PAD / 128;  // 782
  // embedding: h = nodes_feat @ W_emb^T + b_emb  (fp32 A fused split; writes h pad)
  k_mm_embed<<<GEMM_GRID, 512, 0, stream>>>(nodes_feat, wHi + WEMB_OFF, wLo + WEMB_OFF,
                                            b_emb, h_hi, h_lo);

  for (int l = 0; l < 4; l++) {
    const unsigned short* wpH = wHi + WPOOL_OFF + (size_t)l * 14336;
    const unsigned short* wpL = wLo + WPOOL_OFF + (size_t)l * 14336;
    const unsigned short* wn1H = wHi + WNODE1_OFF + (size_t)l * 14336;
    const unsigned short* wn1L = wLo + WNODE1_OFF + (size_t)l * 14336;
    const unsigned short* wn2H = wHi + WNODE2_OFF + (size_t)l * 14336;
    const unsigned short* wn2L = wLo + WNODE2_OFF + (size_t)l * 14336;
    const float* bp = b_pool + (size_t)l * D;
    const float* bn = b_node + (size_t)l * D;

    // pooled = relu(h @ Wp^T + bp)  (fp16 out, padded stride)
    k_mm<<<GEMM_GRID, 512, 0, stream>>>(h_hi, h_lo, KP_H, KP_H,
                                        wpH, wpL, KP_H,
                                        nullptr, nullptr, 0, 0, nullptr, nullptr, 0,
                                        bp, 1, buf1, nullptr, nullptr, nullptr);
    // agg = mean_in(pooled)
    k_aggregate<<<N_PAD / 4, 256, 0, stream>>>(buf1, offs, esrc,
                                               (unsigned int*)agg_hi, (unsigned int*)agg_lo);
    // h += relu(normalize(h@Wn1^T + agg@Wn2^T + bn)) * snorm   (fused)
    k_mm<<<GEMM_GRID, 512, 0, stream>>>(h_hi, h_lo, KP_H, KP_H,
                                        wn1H, wn1L, KP_H,
                                        agg_hi, agg_lo, KP_H, KP_H,
                                        wn2H, wn2L, KP_H,
                                        bn, 2, nullptr, h_hi, h_lo, snorm_n);
  }

  k_gm_part<<<N_GRAPHS * 8, 256, 0, stream>>>(h_hi, h_lo, gid, hgpart);
  k_gm_fin<<<N_GRAPHS, 128, 0, stream>>>(hgpart, gid, hg);
  k_readout<<<N_GRAPHS, 64, 0, stream>>>(hg, W_r0, b_r0, W_r1, b_r1, W_r2, b_r2, out);
}

// Round 16
// 694.218 us; speedup vs baseline: 1.3049x; 1.0145x over previous
//
#include <hip/hip_runtime.h>
#include <hip/hip_bf16.h>
#include <hip/hip_fp16.h>

#define N_NODES  100000
#define N_PAD    100096
#define N_EDGES  1600000
#define N_GRAPHS 128
#define D        108
#define IN_DIM   146
#define KP_H     128
#define KP_NF    160
#define PSTRIDE  128      // pooled row stride in halves (256B, line-aligned)
#define NBUCKET  391      // ceil(N_NODES/256)
#define LBUF     8192     // per-bucket LDS scatter buffer (max bucket edges ~4400)

typedef __bf16 bf16x8 __attribute__((ext_vector_type(8)));
typedef float  f32x4  __attribute__((ext_vector_type(4)));

__device__ __forceinline__ unsigned short f2bf_bits(float v) {
  __hip_bfloat16 b = __float2bfloat16(v);
  return __builtin_bit_cast(unsigned short, b);
}
__device__ __forceinline__ float bf_bits2f(unsigned short u) {
  __hip_bfloat16 b = __builtin_bit_cast(__hip_bfloat16, u);
  return __bfloat162float(b);
}
__device__ __forceinline__ void splitf(float v, unsigned short& hi, unsigned short& lo) {
  hi = f2bf_bits(v);
  lo = f2bf_bits(v - bf_bits2f(hi));
}

// ---------------- bucket histogram (LDS-batched) ----------------
__global__ __launch_bounds__(256)
void k_bhist(const int* __restrict__ dst, int* __restrict__ bhist) {
  __shared__ int bh[NBUCKET];
  int t = threadIdx.x;
  for (int i = t; i < NBUCKET; i += 256) bh[i] = 0;
  __syncthreads();
  int e0 = blockIdx.x * 2048;
#pragma unroll
  for (int j = 0; j < 8; j++) {
    int e = e0 + j * 256 + t;
    if (e < N_EDGES) atomicAdd(&bh[dst[e] >> 8], 1);
  }
  __syncthreads();
  for (int i = t; i < NBUCKET; i += 256)
    if (bh[i]) atomicAdd(&bhist[i], bh[i]);
}

// ---------------- bucket scan (one block) ----------------
__global__ __launch_bounds__(512)
void k_bscan(const int* __restrict__ bhist, int* __restrict__ boffs,
             int* __restrict__ bcur, int* __restrict__ offs) {
  __shared__ int sh[512];
  int t = threadIdx.x;
  sh[t] = (t < NBUCKET) ? bhist[t] : 0;
  __syncthreads();
  for (int off = 1; off < 512; off <<= 1) {
    int v = (t >= off) ? sh[t - off] : 0;
    __syncthreads();
    sh[t] += v;
    __syncthreads();
  }
  if (t < NBUCKET) {
    int excl = (t > 0) ? sh[t - 1] : 0;
    boffs[t] = excl;
    bcur[t]  = excl;
  }
  if (t == 0) { boffs[NBUCKET] = N_EDGES; offs[N_NODES] = N_EDGES; }
}

// ---------------- bin edges into bucket-contiguous ebin (LDS-batched ranks) ----
__global__ __launch_bounds__(256)
void k_binscatter(const int* __restrict__ src, const int* __restrict__ dst,
                  int* __restrict__ bcur, uint2* __restrict__ ebin) {
  __shared__ int lhist[NBUCKET];
  __shared__ int lbase[NBUCKET];
  int t = threadIdx.x;
  for (int i = t; i < NBUCKET; i += 256) lhist[i] = 0;
  __syncthreads();
  int e0 = blockIdx.x * 2048;
  int s[8], d[8], r[8];
#pragma unroll
  for (int j = 0; j < 8; j++) {
    int e = e0 + j * 256 + t;
    if (e < N_EDGES) {
      s[j] = src[e]; d[j] = dst[e];
      r[j] = atomicAdd(&lhist[d[j] >> 8], 1);
    }
  }
  __syncthreads();
  for (int i = t; i < NBUCKET; i += 256)
    lbase[i] = lhist[i] ? atomicAdd(&bcur[i], lhist[i]) : 0;
  __syncthreads();
#pragma unroll
  for (int j = 0; j < 8; j++) {
    int e = e0 + j * 256 + t;
    if (e < N_EDGES)
      ebin[(size_t)lbase[d[j] >> 8] + r[j]] = make_uint2((unsigned)s[j], (unsigned)d[j]);
  }
}

// ---------------- per-bucket local CSR: writes offs + coalesced esrc ----------
// esrc entries are PREMULTIPLIED by 16 (uint4-index of the pooled row).
__global__ __launch_bounds__(256)
void k_scatter2(const uint2* __restrict__ ebin, const int* __restrict__ boffs,
                int* __restrict__ offs, int* __restrict__ esrc) {
  __shared__ int lcnt[256];
  __shared__ int lcur[256];
  __shared__ int lbuf[LBUF];
  int b = blockIdx.x;
  int t = threadIdx.x;
  int vbase = b << 8;
  int estart = boffs[b], eend = boffs[b + 1];
  int cnt = eend - estart;
  lcnt[t] = 0;
  __syncthreads();
  for (int e = estart + t; e < eend; e += 256)
    atomicAdd(&lcnt[ebin[e].y & 255], 1);
  __syncthreads();
  // inclusive scan of lcnt (in-place Hillis-Steele)
  for (int off = 1; off < 256; off <<= 1) {
    int v = (t >= off) ? lcnt[t - off] : 0;
    __syncthreads();
    lcnt[t] += v;
    __syncthreads();
  }
  int excl = (t > 0) ? lcnt[t - 1] : 0;
  int v = vbase + t;
  if (v < N_NODES) offs[v] = estart + excl;
  lcur[t] = excl;
  __syncthreads();
  if (cnt <= LBUF) {
    for (int e = estart + t; e < eend; e += 256) {
      uint2 u = ebin[e];
      int pos = atomicAdd(&lcur[u.y & 255], 1);
      lbuf[pos] = (int)(u.x << 4);
    }
    __syncthreads();
    for (int i = t; i < cnt; i += 256) esrc[estart + i] = lbuf[i];
  } else {   // safety fallback (statistically unreachable)
    for (int e = estart + t; e < eend; e += 256) {
      uint2 u = ebin[e];
      int pos = atomicAdd(&lcur[u.y & 255], 1);
      esrc[estart + pos] = (int)(u.x << 4);
    }
  }
}

// ---------------- split + pad all weights into one packed pair ----------------
// layout: [0,17920) Wemb [112][160]; then 4x wpool [112][128]; 4x wnode1; 4x wnode2
#define WEMB_OFF   0
#define WPOOL_OFF  17920
#define WNODE1_OFF (17920 + 4*14336)
#define WNODE2_OFF (17920 + 8*14336)
#define W_TOTAL    (17920 + 12*14336)

__global__ void k_split_w(const float* __restrict__ W_emb, const float* __restrict__ W_pool,
                          const float* __restrict__ W_node,
                          unsigned short* __restrict__ hi, unsigned short* __restrict__ lo) {
  size_t stride = (size_t)gridDim.x * blockDim.x;
  for (size_t i = (size_t)blockIdx.x * blockDim.x + threadIdx.x; i < W_TOTAL; i += stride) {
    float v = 0.f;
    if (i < WPOOL_OFF) {
      int r = (int)(i / KP_NF), k = (int)(i % KP_NF);
      if (r < D && k < IN_DIM) v = W_emb[(size_t)r * IN_DIM + k];
    } else {
      size_t i2 = i - WPOOL_OFF;
      int seg = (int)(i2 / (4 * 14336));
      size_t r2 = i2 % (4 * 14336);
      int l = (int)(r2 / 14336);
      int n = (int)((r2 % 14336) / KP_H);
      int k = (int)(r2 % KP_H);
      if (n < D && k < D) {
        if (seg == 0)      v = W_pool[(size_t)l * D * D + (size_t)n * D + k];
        else if (seg == 1) v = W_node[(size_t)l * D * 2 * D + (size_t)n * 2 * D + k];
        else               v = W_node[(size_t)l * D * 2 * D + (size_t)n * 2 * D + D + k];
      }
    }
    unsigned short h, l2; splitf(v, h, l2);
    hi[i] = h; lo[i] = l2;
  }
}

// ---------------- embed GEMM: fp32 A (nodes_feat, unpadded) -> split h ----------
// grid 782, block 512 (8 waves), M-tile 128 (16 rows/wave), n-tile 112 (7x16)
// Full split (3-MFMA) for h0 accuracy. Writes h pad = 0.
#define WS_STRIDE 76
__global__ __launch_bounds__(512)
void k_mm_embed(const float* __restrict__ Af,
                const unsigned short* __restrict__ Wh_, const unsigned short* __restrict__ Wl_,
                const float* __restrict__ bias,
                unsigned short* __restrict__ hHi, unsigned short* __restrict__ hLo)
{
  __shared__ unsigned short WsH[112 * WS_STRIDE];
  __shared__ unsigned short WsL[112 * WS_STRIDE];

  const int t = threadIdx.x;
  const int lane = t & 63;
  const int wv = t >> 6;
  const int r15 = lane & 15;
  const int q = lane >> 4;
  const int m0 = blockIdx.x * 128 + wv * 16;
  const int row = m0 + r15;
  const bool rok = row < N_NODES;
  const float* rp_ = Af + (size_t)row * IN_DIM;

  f32x4 acc[7];
#pragma unroll
  for (int j = 0; j < 7; j++) acc[j] = f32x4{0.f, 0.f, 0.f, 0.f};

  for (int k0 = 0; k0 < KP_NF; k0 += 64) {
    const int klen = (KP_NF - k0 >= 64) ? 64 : (KP_NF - k0);
    const int ns = klen >> 5;
    __syncthreads();
    if (klen == 64) {
      for (int u = t; u < 896; u += 512) {
        int r_ = u >> 3, kq = u & 7;
        *(uint4*)&WsH[r_ * WS_STRIDE + kq * 8] =
            *(const uint4*)&Wh_[(size_t)r_ * KP_NF + k0 + kq * 8];
        *(uint4*)&WsL[r_ * WS_STRIDE + kq * 8] =
            *(const uint4*)&Wl_[(size_t)r_ * KP_NF + k0 + kq * 8];
      }
    } else {
      for (int u = t; u < 448; u += 512) {
        int r_ = u >> 2, kq = u & 3;
        *(uint4*)&WsH[r_ * WS_STRIDE + kq * 8] =
            *(const uint4*)&Wh_[(size_t)r_ * KP_NF + k0 + kq * 8];
        *(uint4*)&WsL[r_ * WS_STRIDE + kq * 8] =
            *(const uint4*)&Wl_[(size_t)r_ * KP_NF + k0 + kq * 8];
      }
    }
    // load + split A fragments from fp32 (vectorized when fully in-bounds)
    bf16x8 a_h[2], a_l[2];
#pragma unroll
    for (int s = 0; s < 2; s++) {
      if (s < ns) {
        int kb = k0 + s * 32 + q * 8;
        float vv[8];
        if (rok && kb + 8 <= IN_DIM) {
          const float2* pf = (const float2*)(rp_ + kb);   // 8B-aligned always
          float2 f0 = pf[0], f1 = pf[1], f2 = pf[2], f3 = pf[3];
          vv[0] = f0.x; vv[1] = f0.y; vv[2] = f1.x; vv[3] = f1.y;
          vv[4] = f2.x; vv[5] = f2.y; vv[6] = f3.x; vv[7] = f3.y;
        } else {
#pragma unroll
          for (int j = 0; j < 8; j++) {
            int k = kb + j;
            vv[j] = (rok && k < IN_DIM) ? rp_[k] : 0.f;
          }
        }
#pragma unroll
        for (int j = 0; j < 8; j++) {
          unsigned short h_, l_; splitf(vv[j], h_, l_);
          a_h[s][j] = __builtin_bit_cast(__bf16, h_);
          a_l[s][j] = __builtin_bit_cast(__bf16, l_);
        }
      }
    }
    __syncthreads();
#pragma unroll
    for (int s = 0; s < 2; s++) {
      if (s < ns) {
#pragma unroll
        for (int n = 0; n < 7; n++) {
          int wrow = n * 16 + r15;
          const bf16x8 bh = *(const bf16x8*)&WsH[wrow * WS_STRIDE + s * 32 + q * 8];
          const bf16x8 bl = *(const bf16x8*)&WsL[wrow * WS_STRIDE + s * 32 + q * 8];
          acc[n] = __builtin_amdgcn_mfma_f32_16x16x32_bf16(a_h[s], bh, acc[n], 0, 0, 0);
          acc[n] = __builtin_amdgcn_mfma_f32_16x16x32_bf16(a_h[s], bl, acc[n], 0, 0, 0);
          acc[n] = __builtin_amdgcn_mfma_f32_16x16x32_bf16(a_l[s], bh, acc[n], 0, 0, 0);
        }
      }
    }
  }

  // epilogue: write full [row][0..127] including pad zeros
#pragma unroll
  for (int n = 0; n < 7; n++) {
    int col = n * 16 + r15;
    float bv = (col < D) ? bias[col] : 0.f;
#pragma unroll
    for (int r = 0; r < 4; r++) {
      int orow = m0 + q * 4 + r;
      float v = (orow < N_NODES && col < D) ? (acc[n][r] + bv) : 0.f;
      unsigned short h_, l_; splitf(v, h_, l_);
      hHi[(size_t)orow * KP_H + col] = h_;
      hLo[(size_t)orow * KP_H + col] = l_;
    }
  }
  {
    int col = 112 + r15;
#pragma unroll
    for (int r = 0; r < 4; r++) {
      int orow = m0 + q * 4 + r;
      hHi[(size_t)orow * KP_H + col] = 0;
      hLo[(size_t)orow * KP_H + col] = 0;
    }
  }
}

// ---------------- MFMA GEMM: A = bf16-hi only, W = split hi/lo --------------
// grid 782, block 512 (8 waves), M-tile 128 (16 rows/wave), n-tile 112 (7x16)
// modes: 1 = pool (fp16 out + relu, PSTRIDE), 2 = node (fused norm/res)
__global__ __launch_bounds__(512)
void k_mm(const unsigned short* A1, int lda1, int K1,
          const unsigned short* __restrict__ W1h, const unsigned short* __restrict__ W1l, int ldw1,
          const unsigned short* A2, int lda2, int K2,
          const unsigned short* __restrict__ W2h, const unsigned short* __restrict__ W2l, int ldw2,
          const float* __restrict__ bias, int mode,
          __half* __restrict__ outH,
          unsigned short* hHi, unsigned short* hLo,
          const float* __restrict__ snorm)
{
  __shared__ unsigned short WsH[112 * WS_STRIDE];
  __shared__ unsigned short WsL[112 * WS_STRIDE];

  const int t = threadIdx.x;
  const int lane = t & 63;
  const int wv = t >> 6;          // 0..7
  const int r15 = lane & 15;
  const int q = lane >> 4;
  const int m0 = blockIdx.x * 128 + wv * 16;

  f32x4 acc[7];
#pragma unroll
  for (int j = 0; j < 7; j++) acc[j] = f32x4{0.f, 0.f, 0.f, 0.f};

  auto do_seg = [&](const unsigned short* A, int lda, int K,
                    const unsigned short* Wh, const unsigned short* Wl, int ldw) {
    for (int k0 = 0; k0 < K; k0 += 64) {
      const int klen = (K - k0 >= 64) ? 64 : (K - k0);
      __syncthreads();   // previous chunk's LDS reads done
      if (klen == 64) {
        for (int u = t; u < 896; u += 512) {
          int row = u >> 3, kq = u & 7;
          *(uint4*)&WsH[row * WS_STRIDE + kq * 8] =
              *(const uint4*)&Wh[(size_t)row * ldw + k0 + kq * 8];
          *(uint4*)&WsL[row * WS_STRIDE + kq * 8] =
              *(const uint4*)&Wl[(size_t)row * ldw + k0 + kq * 8];
        }
      } else { // 32
        for (int u = t; u < 448; u += 512) {
          int row = u >> 2, kq = u & 3;
          *(uint4*)&WsH[row * WS_STRIDE + kq * 8] =
              *(const uint4*)&Wh[(size_t)row * ldw + k0 + kq * 8];
          *(uint4*)&WsL[row * WS_STRIDE + kq * 8] =
              *(const uint4*)&Wl[(size_t)row * ldw + k0 + kq * 8];
        }
      }
      // issue A loads for this chunk while staging completes
      bf16x8 a[2];
      const int ns = klen >> 5;
#pragma unroll
      for (int s = 0; s < 2; s++) {
        if (s < ns) {
          size_t base = (size_t)(m0 + r15) * lda + k0 + s * 32 + q * 8;
          a[s] = *(const bf16x8*)&A[base];
        }
      }
      __syncthreads();   // staged W visible
#pragma unroll
      for (int s = 0; s < 2; s++) {
        if (s < ns) {
#pragma unroll
          for (int n = 0; n < 7; n++) {
            int wrow = n * 16 + r15;
            const bf16x8 bh = *(const bf16x8*)&WsH[wrow * WS_STRIDE + s * 32 + q * 8];
            const bf16x8 bl = *(const bf16x8*)&WsL[wrow * WS_STRIDE + s * 32 + q * 8];
            acc[n] = __builtin_amdgcn_mfma_f32_16x16x32_bf16(a[s], bh, acc[n], 0, 0, 0);
            acc[n] = __builtin_amdgcn_mfma_f32_16x16x32_bf16(a[s], bl, acc[n], 0, 0, 0);
          }
        }
      }
    }
  };

  do_seg(A1, lda1, K1, W1h, W1l, ldw1);
  if (A2) do_seg(A2, lda2, K2, W2h, W2l, ldw2);

  // ---------------- epilogue ----------------
  if (mode == 2) {
    // fused: v = acc+bias; L2-normalize row; relu; *snorm; h += v
    float ss[4] = {0.f, 0.f, 0.f, 0.f};
#pragma unroll
    for (int n = 0; n < 7; n++) {
      int col = n * 16 + r15;
      if (col < D) {
        float bv = bias[col];
#pragma unroll
        for (int r = 0; r < 4; r++) {
          float v = acc[n][r] + bv;
          ss[r] += v * v;
        }
      }
    }
#pragma unroll
    for (int m_ = 1; m_ <= 8; m_ <<= 1) {
#pragma unroll
      for (int r = 0; r < 4; r++) ss[r] += __shfl_xor(ss[r], m_, 64);
    }
    float inv[4], sn[4]; int rows[4];
#pragma unroll
    for (int r = 0; r < 4; r++) {
      rows[r] = m0 + q * 4 + r;
      float dn = fmaxf(sqrtf(ss[r]), 1e-12f);
      inv[r] = 1.0f / dn;
      sn[r] = (rows[r] < N_NODES) ? snorm[rows[r]] : 0.f;
    }
#pragma unroll
    for (int n = 0; n < 7; n++) {
      int col = n * 16 + r15;
      if (col >= D) continue;
      float bv = bias[col];
#pragma unroll
      for (int r = 0; r < 4; r++) {
        if (rows[r] >= N_NODES) continue;
        size_t idx = (size_t)rows[r] * KP_H + col;
        float hold = bf_bits2f(hHi[idx]) + bf_bits2f(hLo[idx]);
        float v = acc[n][r] + bv;
        float x = fmaxf(v * inv[r], 0.f) * sn[r];
        float nh = hold + x;
        unsigned short h_, l_; splitf(nh, h_, l_);
        hHi[idx] = h_; hLo[idx] = l_;
      }
    }
  } else {
#pragma unroll
    for (int n = 0; n < 7; n++) {
      int col = n * 16 + r15;
      if (col >= D) continue;
      float bv = bias[col];
#pragma unroll
      for (int r = 0; r < 4; r++) {
        int row = m0 + q * 4 + r;
        if (row >= N_NODES) continue;
        float v = acc[n][r] + bv;
        outH[(size_t)row * PSTRIDE + col] = __float2half_rn(fmaxf(v, 0.f));
      }
    }
  }
}

// ---------------- pull aggregation: one wave/node, 16 edges in flight ----------
// lane = (g, lp): g = edge slot (0..3), lp = 16B segment of the 256B row.
// esrc entries premultiplied by 16. agg output = bf16 (single buffer).
__global__ __launch_bounds__(256)
void k_aggregate(const __half* __restrict__ pooled, const int* __restrict__ offsets,
                 const int* __restrict__ esrc,
                 unsigned int* __restrict__ aggHi)
{
  int t = threadIdx.x;
  int lane = t & 63;
  int g = lane >> 4;
  int lp = lane & 15;
  int v = blockIdx.x * 4 + (t >> 6);
  if (v >= N_PAD) return;
  float va[8];
#pragma unroll
  for (int j = 0; j < 8; j++) va[j] = 0.f;
  int s0 = 0, s1 = 0;
  if (v < N_NODES) { s0 = offsets[v]; s1 = offsets[v + 1]; }
  const uint4* P = (const uint4*)pooled;   // row = 16 uint4 (256B)
  int e = s0;
  for (; e + 15 < s1; e += 16) {
    unsigned o0 = (unsigned)esrc[e + g] + lp;
    unsigned o1 = (unsigned)esrc[e + 4 + g] + lp;
    unsigned o2 = (unsigned)esrc[e + 8 + g] + lp;
    unsigned o3 = (unsigned)esrc[e + 12 + g] + lp;
    uint4 u0 = P[o0];
    uint4 u1 = P[o1];
    uint4 u2 = P[o2];
    uint4 u3 = P[o3];
#pragma unroll
    for (int w = 0; w < 4; w++) {
      uint4 u = (w == 0) ? u0 : (w == 1) ? u1 : (w == 2) ? u2 : u3;
      float2 f0 = __half22float2(__builtin_bit_cast(__half2, u.x));
      float2 f1 = __half22float2(__builtin_bit_cast(__half2, u.y));
      float2 f2 = __half22float2(__builtin_bit_cast(__half2, u.z));
      float2 f3 = __half22float2(__builtin_bit_cast(__half2, u.w));
      va[0] += f0.x; va[1] += f0.y; va[2] += f1.x; va[3] += f1.y;
      va[4] += f2.x; va[5] += f2.y; va[6] += f3.x; va[7] += f3.y;
    }
  }
  for (; e + 7 < s1; e += 8) {
    unsigned o0 = (unsigned)esrc[e + g] + lp;
    unsigned o1 = (unsigned)esrc[e + 4 + g] + lp;
    uint4 u0 = P[o0];
    uint4 u1 = P[o1];
#pragma unroll
    for (int w = 0; w < 2; w++) {
      uint4 u = (w == 0) ? u0 : u1;
      float2 f0 = __half22float2(__builtin_bit_cast(__half2, u.x));
      float2 f1 = __half22float2(__builtin_bit_cast(__half2, u.y));
      float2 f2 = __half22float2(__builtin_bit_cast(__half2, u.z));
      float2 f3 = __half22float2(__builtin_bit_cast(__half2, u.w));
      va[0] += f0.x; va[1] += f0.y; va[2] += f1.x; va[3] += f1.y;
      va[4] += f2.x; va[5] += f2.y; va[6] += f3.x; va[7] += f3.y;
    }
  }
  for (; e < s1; e += 4) {
    int idx = e + g;
    if (idx < s1) {
      unsigned o = (unsigned)esrc[idx] + lp;
      uint4 u = P[o];
      float2 f0 = __half22float2(__builtin_bit_cast(__half2, u.x));
      float2 f1 = __half22float2(__builtin_bit_cast(__half2, u.y));
      float2 f2 = __half22float2(__builtin_bit_cast(__half2, u.z));
      float2 f3 = __half22float2(__builtin_bit_cast(__half2, u.w));
      va[0] += f0.x; va[1] += f0.y; va[2] += f1.x; va[3] += f1.y;
      va[4] += f2.x; va[5] += f2.y; va[6] += f3.x; va[7] += f3.y;
    }
  }
  // combine the 4 edge-slot groups (lanes with equal lp)
#pragma unroll
  for (int j = 0; j < 8; j++) {
    va[j] += __shfl_xor(va[j], 16, 64);
    va[j] += __shfl_xor(va[j], 32, 64);
  }
  if (g == 0) {
    int dgi = s1 - s0; if (dgi < 1) dgi = 1;
    float inv = 1.0f / (float)dgi;
    unsigned int hiw[4];
#pragma unroll
    for (int p = 0; p < 4; p++) {
      unsigned short h0 = f2bf_bits(va[2 * p] * inv);
      unsigned short h1 = f2bf_bits(va[2 * p + 1] * inv);
      hiw[p] = (unsigned)h0 | ((unsigned)h1 << 16);
    }
    *(uint4*)&aggHi[(size_t)v * 64 + lp * 4] = make_uint4(hiw[0], hiw[1], hiw[2], hiw[3]);
  }
}

// ---------------- per-graph mean, phase 1: 8 chunks/graph partial sums ----------
__global__ __launch_bounds__(256)
void k_gm_part(const unsigned short* __restrict__ hHi, const unsigned short* __restrict__ hLo,
               const int* __restrict__ gid, float* __restrict__ hgpart) {
  int g = blockIdx.x >> 3;
  int j = blockIdx.x & 7;
  int t = threadIdx.x;
  int c = t & 127, rp = t >> 7;
  // bounds of graph g (all threads redundantly)
  int lo = 0, hi = N_NODES;
  while (lo < hi) { int m = (lo + hi) >> 1; if (gid[m] < g) lo = m + 1; else hi = m; }
  int s = lo;
  hi = N_NODES;
  while (lo < hi) { int m = (lo + hi) >> 1; if (gid[m] < g + 1) lo = m + 1; else hi = m; }
  int e = lo;
  int per = ((e - s) + 7) >> 3;
  int vs = s + j * per;
  int ve = vs + per; if (ve > e) ve = e;
  float acc = 0.f;
  if (c < D) {
    for (int v = vs + rp; v < ve; v += 2) {
      size_t idx = (size_t)v * KP_H + c;
      acc += bf_bits2f(hHi[idx]) + bf_bits2f(hLo[idx]);
    }
  }
  __shared__ float part[2][128];
  part[rp][c] = acc;
  __syncthreads();
  if (rp == 0 && c < D)
    hgpart[(size_t)blockIdx.x * D + c] = part[0][c] + part[1][c];
}

// ---------------- per-graph mean, phase 2: reduce 8 chunks + divide ------------
__global__ __launch_bounds__(128)
void k_gm_fin(const float* __restrict__ hgpart, const int* __restrict__ gid,
              float* __restrict__ hg) {
  int g = blockIdx.x;
  int t = threadIdx.x;
  int lo = 0, hi = N_NODES;
  while (lo < hi) { int m = (lo + hi) >> 1; if (gid[m] < g) lo = m + 1; else hi = m; }
  int s = lo;
  hi = N_NODES;
  while (lo < hi) { int m = (lo + hi) >> 1; if (gid[m] < g + 1) lo = m + 1; else hi = m; }
  int cnt = lo - s; if (cnt < 1) cnt = 1;
  if (t < D) {
    float sum = 0.f;
#pragma unroll
    for (int j = 0; j < 8; j++) sum += hgpart[(size_t)(g * 8 + j) * D + t];
    hg[g * D + t] = sum / (float)cnt;
  }
}

// ---------------- MLP readout ----------------
__global__ __launch_bounds__(64)
void k_readout(const float* __restrict__ hg,
               const float* __restrict__ Wr0, const float* __restrict__ br0,
               const float* __restrict__ Wr1, const float* __restrict__ br1,
               const float* __restrict__ Wr2, const float* __restrict__ br2,
               float* __restrict__ out) {
  int g = blockIdx.x;
  int t = threadIdx.x;
  __shared__ float x0[D];
  __shared__ float x1[54];
  __shared__ float x2[27];
  for (int i = t; i < D; i += 64) x0[i] = hg[g * D + i];
  __syncthreads();
  if (t < 54) {
    float v = br0[t];
    for (int k = 0; k < D; k++) v += x0[k] * Wr0[t * D + k];
    x1[t] = fmaxf(v, 0.f);
  }
  __syncthreads();
  if (t < 27) {
    float v = br1[t];
    for (int k = 0; k < 54; k++) v += x1[k] * Wr1[t * 54 + k];
    x2[t] = fmaxf(v, 0.f);
  }
  __syncthreads();
  if (t < 10) {
    float v = br2[t];
    for (int k = 0; k < 27; k++) v += x2[k] * Wr2[t * 27 + k];
    out[g * 10 + t] = v;
  }
}

extern "C" void kernel_launch(void* const* d_in, const int* in_sizes, int n_in,
                              void* d_out, int out_size, void* d_ws, size_t ws_size,
                              hipStream_t stream) {
  const float* nodes_feat = (const float*)d_in[0];
  const float* snorm_n    = (const float*)d_in[1];
  const int*   src        = (const int*)d_in[2];
  const int*   dst        = (const int*)d_in[3];
  const int*   gid        = (const int*)d_in[4];
  const float* W_emb      = (const float*)d_in[6];
  const float* b_emb      = (const float*)d_in[7];
  const float* W_pool     = (const float*)d_in[8];
  const float* b_pool     = (const float*)d_in[9];
  const float* W_node     = (const float*)d_in[10];
  const float* b_node     = (const float*)d_in[11];
  const float* W_r0       = (const float*)d_in[12];
  const float* b_r0       = (const float*)d_in[13];
  const float* W_r1       = (const float*)d_in[14];
  const float* b_r1       = (const float*)d_in[15];
  const float* W_r2       = (const float*)d_in[16];
  const float* b_r2       = (const float*)d_in[17];
  float* out = (float*)d_out;

  char* ws = (char*)d_ws;
  size_t off = 0;
  auto alloc = [&](size_t bytes) { size_t o = off; off = (off + bytes + 255) & ~(size_t)255; return o; };

  __half* buf1 = (__half*)(ws + alloc((size_t)N_NODES * PSTRIDE * 2));  // pooled (fp16, padded)
  unsigned short* h_hi = (unsigned short*)(ws + alloc((size_t)N_PAD * KP_H * 2));
  unsigned short* h_lo = (unsigned short*)(ws + alloc((size_t)N_PAD * KP_H * 2));
  unsigned short* agg_hi = (unsigned short*)(ws + alloc((size_t)N_PAD * KP_H * 2));
  uint2* ebin = (uint2*)(ws + alloc((size_t)N_EDGES * 8));
  int* esrc  = (int*)(ws + alloc((size_t)N_EDGES * 4));
  int* offs  = (int*)(ws + alloc((size_t)(N_NODES + 1) * 4));
  int* bhist = (int*)(ws + alloc((size_t)(NBUCKET + 1) * 4));
  int* boffs = (int*)(ws + alloc((size_t)(NBUCKET + 1) * 4));
  int* bcur  = (int*)(ws + alloc((size_t)(NBUCKET + 1) * 4));
  unsigned short* wHi = (unsigned short*)(ws + alloc((size_t)W_TOTAL * 2));
  unsigned short* wLo = (unsigned short*)(ws + alloc((size_t)W_TOTAL * 2));
  float* hgpart = (float*)(ws + alloc((size_t)N_GRAPHS * 8 * D * 4));
  float* hg = (float*)(ws + alloc((size_t)N_GRAPHS * D * 4));
  (void)ws_size; (void)n_in; (void)in_sizes; (void)out_size;

  hipMemsetAsync(bhist, 0, (size_t)NBUCKET * 4, stream);

  // weight split
  k_split_w<<<(W_TOTAL + 255) / 256, 256, 0, stream>>>(W_emb, W_pool, W_node, wHi, wLo);

  // CSR build via bucket counting sort (writes offs + esrc premultiplied)
  const int EB = (N_EDGES + 2047) / 2048;  // 782
  k_bhist<<<EB, 256, 0, stream>>>(dst, bhist);
  k_bscan<<<1, 512, 0, stream>>>(bhist, boffs, bcur, offs);
  k_binscatter<<<EB, 256, 0, stream>>>(src, dst, bcur, ebin);
  k_scatter2<<<NBUCKET, 256, 0, stream>>>(ebin, boffs, offs, esrc);

  const int GEMM_GRID = N_PAD / 128;  // 782
  // embedding: h = nodes_feat @ W_emb^T + b_emb  (fp32 A fused split; writes h pad)
  k_mm_embed<<<GEMM_GRID, 512, 0, stream>>>(nodes_feat, wHi + WEMB_OFF, wLo + WEMB_OFF,
                                            b_emb, h_hi, h_lo);

  for (int l = 0; l < 4; l++) {
    const unsigned short* wpH = wHi + WPOOL_OFF + (size_t)l * 14336;
    const unsigned short* wpL = wLo + WPOOL_OFF + (size_t)l * 14336;
    const unsigned short* wn1H = wHi + WNODE1_OFF + (size_t)l * 14336;
    const unsigned short* wn1L = wLo + WNODE1_OFF + (size_t)l * 14336;
    const unsigned short* wn2H = wHi + WNODE2_OFF + (size_t)l * 14336;
    const unsigned short* wn2L = wLo + WNODE2_OFF + (size_t)l * 14336;
    const float* bp = b_pool + (size_t)l * D;
    const float* bn = b_node + (size_t)l * D;

    // pooled = relu(h @ Wp^T + bp)  (fp16 out, padded stride; A = h_hi only)
    k_mm<<<GEMM_GRID, 512, 0, stream>>>(h_hi, KP_H, KP_H,
                                        wpH, wpL, KP_H,
                                        nullptr, 0, 0, nullptr, nullptr, 0,
                                        bp, 1, buf1, nullptr, nullptr, nullptr);
    // agg = mean_in(pooled)  (bf16 out)
    k_aggregate<<<N_PAD / 4, 256, 0, stream>>>(buf1, offs, esrc, (unsigned int*)agg_hi);
    // h += relu(normalize(h@Wn1^T + agg@Wn2^T + bn)) * snorm   (fused)
    k_mm<<<GEMM_GRID, 512, 0, stream>>>(h_hi, KP_H, KP_H,
                                        wn1H, wn1L, KP_H,
                                        agg_hi, KP_H, KP_H,
                                        wn2H, wn2L, KP_H,
                                        bn, 2, nullptr, h_hi, h_lo, snorm_n);
  }

  k_gm_part<<<N_GRAPHS * 8, 256, 0, stream>>>(h_hi, h_lo, gid, hgpart);
  k_gm_fin<<<N_GRAPHS, 128, 0, stream>>>(hgpart, gid, hg);
  k_readout<<<N_GRAPHS, 64, 0, stream>>>(hg, W_r0, b_r0, W_r1, b_r1, W_r2, b_r2, out);
}

// Round 17
// 566.048 us; speedup vs baseline: 1.6003x; 1.2264x over previous
//
#include <hip/hip_runtime.h>
#include <hip/hip_bf16.h>
#include <hip/hip_fp16.h>

#define N_NODES  100000
#define N_PAD    100096
#define N_EDGES  1600000
#define N_GRAPHS 128
#define D        108
#define IN_DIM   146
#define KP_H     128
#define KP_NF    160
#define PSTRIDE  128      // pooled row stride in halves (256B, line-aligned)
#define NBUCKET  391      // ceil(N_NODES/256)
#define LBUF     8192     // per-bucket LDS scatter buffer (max bucket edges ~4400)

typedef _Float16 f16x8 __attribute__((ext_vector_type(8)));
typedef float    f32x4 __attribute__((ext_vector_type(4)));

__device__ __forceinline__ unsigned short f2h_bits(float v) {
  __half h = __float2half_rn(v);
  return __builtin_bit_cast(unsigned short, h);
}
__device__ __forceinline__ float h_bits2f(unsigned short u) {
  __half h = __builtin_bit_cast(__half, u);
  return __half2float(h);
}

// ---------------- bucket histogram (LDS-batched) ----------------
__global__ __launch_bounds__(256)
void k_bhist(const int* __restrict__ dst, int* __restrict__ bhist) {
  __shared__ int bh[NBUCKET];
  int t = threadIdx.x;
  for (int i = t; i < NBUCKET; i += 256) bh[i] = 0;
  __syncthreads();
  int e0 = blockIdx.x * 2048;
#pragma unroll
  for (int j = 0; j < 8; j++) {
    int e = e0 + j * 256 + t;
    if (e < N_EDGES) atomicAdd(&bh[dst[e] >> 8], 1);
  }
  __syncthreads();
  for (int i = t; i < NBUCKET; i += 256)
    if (bh[i]) atomicAdd(&bhist[i], bh[i]);
}

// ---------------- bucket scan (one block) ----------------
__global__ __launch_bounds__(512)
void k_bscan(const int* __restrict__ bhist, int* __restrict__ boffs,
             int* __restrict__ bcur, int* __restrict__ offs) {
  __shared__ int sh[512];
  int t = threadIdx.x;
  sh[t] = (t < NBUCKET) ? bhist[t] : 0;
  __syncthreads();
  for (int off = 1; off < 512; off <<= 1) {
    int v = (t >= off) ? sh[t - off] : 0;
    __syncthreads();
    sh[t] += v;
    __syncthreads();
  }
  if (t < NBUCKET) {
    int excl = (t > 0) ? sh[t - 1] : 0;
    boffs[t] = excl;
    bcur[t]  = excl;
  }
  if (t == 0) { boffs[NBUCKET] = N_EDGES; offs[N_NODES] = N_EDGES; }
}

// ---------------- bin edges into bucket-contiguous ebin (LDS-batched ranks) ----
__global__ __launch_bounds__(256)
void k_binscatter(const int* __restrict__ src, const int* __restrict__ dst,
                  int* __restrict__ bcur, uint2* __restrict__ ebin) {
  __shared__ int lhist[NBUCKET];
  __shared__ int lbase[NBUCKET];
  int t = threadIdx.x;
  for (int i = t; i < NBUCKET; i += 256) lhist[i] = 0;
  __syncthreads();
  int e0 = blockIdx.x * 2048;
  int s[8], d[8], r[8];
#pragma unroll
  for (int j = 0; j < 8; j++) {
    int e = e0 + j * 256 + t;
    if (e < N_EDGES) {
      s[j] = src[e]; d[j] = dst[e];
      r[j] = atomicAdd(&lhist[d[j] >> 8], 1);
    }
  }
  __syncthreads();
  for (int i = t; i < NBUCKET; i += 256)
    lbase[i] = lhist[i] ? atomicAdd(&bcur[i], lhist[i]) : 0;
  __syncthreads();
#pragma unroll
  for (int j = 0; j < 8; j++) {
    int e = e0 + j * 256 + t;
    if (e < N_EDGES)
      ebin[(size_t)lbase[d[j] >> 8] + r[j]] = make_uint2((unsigned)s[j], (unsigned)d[j]);
  }
}

// ---------------- per-bucket local CSR: writes offs + coalesced esrc ----------
// esrc entries are PREMULTIPLIED by 16 (uint4-index of the pooled row).
__global__ __launch_bounds__(256)
void k_scatter2(const uint2* __restrict__ ebin, const int* __restrict__ boffs,
                int* __restrict__ offs, int* __restrict__ esrc) {
  __shared__ int lcnt[256];
  __shared__ int lcur[256];
  __shared__ int lbuf[LBUF];
  int b = blockIdx.x;
  int t = threadIdx.x;
  int vbase = b << 8;
  int estart = boffs[b], eend = boffs[b + 1];
  int cnt = eend - estart;
  lcnt[t] = 0;
  __syncthreads();
  for (int e = estart + t; e < eend; e += 256)
    atomicAdd(&lcnt[ebin[e].y & 255], 1);
  __syncthreads();
  // inclusive scan of lcnt (in-place Hillis-Steele)
  for (int off = 1; off < 256; off <<= 1) {
    int v = (t >= off) ? lcnt[t - off] : 0;
    __syncthreads();
    lcnt[t] += v;
    __syncthreads();
  }
  int excl = (t > 0) ? lcnt[t - 1] : 0;
  int v = vbase + t;
  if (v < N_NODES) offs[v] = estart + excl;
  lcur[t] = excl;
  __syncthreads();
  if (cnt <= LBUF) {
    for (int e = estart + t; e < eend; e += 256) {
      uint2 u = ebin[e];
      int pos = atomicAdd(&lcur[u.y & 255], 1);
      lbuf[pos] = (int)(u.x << 4);
    }
    __syncthreads();
    for (int i = t; i < cnt; i += 256) esrc[estart + i] = lbuf[i];
  } else {   // safety fallback (statistically unreachable)
    for (int e = estart + t; e < eend; e += 256) {
      uint2 u = ebin[e];
      int pos = atomicAdd(&lcur[u.y & 255], 1);
      esrc[estart + pos] = (int)(u.x << 4);
    }
  }
}

// ---------------- convert + pad all weights into one fp16 buffer ----------------
// layout: [0,17920) Wemb [112][160]; then 4x wpool [112][128]; 4x wnode1; 4x wnode2
#define WEMB_OFF   0
#define WPOOL_OFF  17920
#define WNODE1_OFF (17920 + 4*14336)
#define WNODE2_OFF (17920 + 8*14336)
#define W_TOTAL    (17920 + 12*14336)

__global__ void k_split_w(const float* __restrict__ W_emb, const float* __restrict__ W_pool,
                          const float* __restrict__ W_node,
                          unsigned short* __restrict__ wF) {
  size_t stride = (size_t)gridDim.x * blockDim.x;
  for (size_t i = (size_t)blockIdx.x * blockDim.x + threadIdx.x; i < W_TOTAL; i += stride) {
    float v = 0.f;
    if (i < WPOOL_OFF) {
      int r = (int)(i / KP_NF), k = (int)(i % KP_NF);
      if (r < D && k < IN_DIM) v = W_emb[(size_t)r * IN_DIM + k];
    } else {
      size_t i2 = i - WPOOL_OFF;
      int seg = (int)(i2 / (4 * 14336));
      size_t r2 = i2 % (4 * 14336);
      int l = (int)(r2 / 14336);
      int n = (int)((r2 % 14336) / KP_H);
      int k = (int)(r2 % KP_H);
      if (n < D && k < D) {
        if (seg == 0)      v = W_pool[(size_t)l * D * D + (size_t)n * D + k];
        else if (seg == 1) v = W_node[(size_t)l * D * 2 * D + (size_t)n * 2 * D + k];
        else               v = W_node[(size_t)l * D * 2 * D + (size_t)n * 2 * D + D + k];
      }
    }
    wF[i] = f2h_bits(v);
  }
}

// ---------------- embed GEMM: fp32 A (nodes_feat) -> fp16 h ----------
// grid 782, block 512 (8 waves), M-tile 128 (16 rows/wave), n-tile 112 (7x16)
// Writes h pad (cols 112..127, rows >= N_NODES) = 0.
#define WS_STRIDE 76
__global__ __launch_bounds__(512)
void k_mm_embed(const float* __restrict__ Af,
                const unsigned short* __restrict__ W_,
                const float* __restrict__ bias,
                unsigned short* __restrict__ hF)
{
  __shared__ unsigned short Ws[112 * WS_STRIDE];

  const int t = threadIdx.x;
  const int lane = t & 63;
  const int wv = t >> 6;
  const int r15 = lane & 15;
  const int q = lane >> 4;
  const int m0 = blockIdx.x * 128 + wv * 16;
  const int row = m0 + r15;
  const bool rok = row < N_NODES;
  const float* rp_ = Af + (size_t)row * IN_DIM;

  f32x4 acc[7];
#pragma unroll
  for (int j = 0; j < 7; j++) acc[j] = f32x4{0.f, 0.f, 0.f, 0.f};

  for (int k0 = 0; k0 < KP_NF; k0 += 64) {
    const int klen = (KP_NF - k0 >= 64) ? 64 : (KP_NF - k0);
    const int ns = klen >> 5;
    __syncthreads();
    if (klen == 64) {
      for (int u = t; u < 896; u += 512) {
        int r_ = u >> 3, kq = u & 7;
        *(uint4*)&Ws[r_ * WS_STRIDE + kq * 8] =
            *(const uint4*)&W_[(size_t)r_ * KP_NF + k0 + kq * 8];
      }
    } else {
      for (int u = t; u < 448; u += 512) {
        int r_ = u >> 2, kq = u & 3;
        *(uint4*)&Ws[r_ * WS_STRIDE + kq * 8] =
            *(const uint4*)&W_[(size_t)r_ * KP_NF + k0 + kq * 8];
      }
    }
    // load + convert A fragments from fp32 (vectorized when fully in-bounds)
    f16x8 a[2];
#pragma unroll
    for (int s = 0; s < 2; s++) {
      if (s < ns) {
        int kb = k0 + s * 32 + q * 8;
        float vv[8];
        if (rok && kb + 8 <= IN_DIM) {
          const float2* pf = (const float2*)(rp_ + kb);   // 8B-aligned always
          float2 f0 = pf[0], f1 = pf[1], f2 = pf[2], f3 = pf[3];
          vv[0] = f0.x; vv[1] = f0.y; vv[2] = f1.x; vv[3] = f1.y;
          vv[4] = f2.x; vv[5] = f2.y; vv[6] = f3.x; vv[7] = f3.y;
        } else {
#pragma unroll
          for (int j = 0; j < 8; j++) {
            int k = kb + j;
            vv[j] = (rok && k < IN_DIM) ? rp_[k] : 0.f;
          }
        }
#pragma unroll
        for (int j = 0; j < 8; j++) a[s][j] = (_Float16)vv[j];
      }
    }
    __syncthreads();
#pragma unroll
    for (int s = 0; s < 2; s++) {
      if (s < ns) {
#pragma unroll
        for (int n = 0; n < 7; n++) {
          int wrow = n * 16 + r15;
          const f16x8 b = *(const f16x8*)&Ws[wrow * WS_STRIDE + s * 32 + q * 8];
          acc[n] = __builtin_amdgcn_mfma_f32_16x16x32_f16(a[s], b, acc[n], 0, 0, 0);
        }
      }
    }
  }

  // epilogue: write full [row][0..127] including pad zeros
#pragma unroll
  for (int n = 0; n < 7; n++) {
    int col = n * 16 + r15;
    float bv = (col < D) ? bias[col] : 0.f;
#pragma unroll
    for (int r = 0; r < 4; r++) {
      int orow = m0 + q * 4 + r;
      float v = (orow < N_NODES && col < D) ? (acc[n][r] + bv) : 0.f;
      hF[(size_t)orow * KP_H + col] = f2h_bits(v);
    }
  }
  {
    int col = 112 + r15;
#pragma unroll
    for (int r = 0; r < 4; r++) {
      int orow = m0 + q * 4 + r;
      hF[(size_t)orow * KP_H + col] = 0;
    }
  }
}

// ---------------- fp16 MFMA GEMM, LDS-staged W, 8 waves R=1 ----------------
// grid 782, block 512 (8 waves), M-tile 128 (16 rows/wave), n-tile 112 (7x16)
// modes: 1 = pool (fp16 out + relu, PSTRIDE), 2 = node (fused norm/res on fp16 h)
__global__ __launch_bounds__(512)
void k_mm(const unsigned short* A1, int lda1, int K1,
          const unsigned short* __restrict__ W1, int ldw1,
          const unsigned short* A2, int lda2, int K2,
          const unsigned short* __restrict__ W2, int ldw2,
          const float* __restrict__ bias, int mode,
          __half* __restrict__ outH,
          unsigned short* hF,
          const float* __restrict__ snorm)
{
  __shared__ unsigned short Ws[112 * WS_STRIDE];

  const int t = threadIdx.x;
  const int lane = t & 63;
  const int wv = t >> 6;          // 0..7
  const int r15 = lane & 15;
  const int q = lane >> 4;
  const int m0 = blockIdx.x * 128 + wv * 16;

  f32x4 acc[7];
#pragma unroll
  for (int j = 0; j < 7; j++) acc[j] = f32x4{0.f, 0.f, 0.f, 0.f};

  auto do_seg = [&](const unsigned short* A, int lda, int K,
                    const unsigned short* W, int ldw) {
    for (int k0 = 0; k0 < K; k0 += 64) {
      const int klen = (K - k0 >= 64) ? 64 : (K - k0);
      __syncthreads();   // previous chunk's LDS reads done
      if (klen == 64) {
        for (int u = t; u < 896; u += 512) {
          int row = u >> 3, kq = u & 7;
          *(uint4*)&Ws[row * WS_STRIDE + kq * 8] =
              *(const uint4*)&W[(size_t)row * ldw + k0 + kq * 8];
        }
      } else { // 32
        for (int u = t; u < 448; u += 512) {
          int row = u >> 2, kq = u & 3;
          *(uint4*)&Ws[row * WS_STRIDE + kq * 8] =
              *(const uint4*)&W[(size_t)row * ldw + k0 + kq * 8];
        }
      }
      // issue A loads for this chunk while staging completes
      f16x8 a[2];
      const int ns = klen >> 5;
#pragma unroll
      for (int s = 0; s < 2; s++) {
        if (s < ns) {
          size_t base = (size_t)(m0 + r15) * lda + k0 + s * 32 + q * 8;
          a[s] = *(const f16x8*)&A[base];
        }
      }
      __syncthreads();   // staged W visible
#pragma unroll
      for (int s = 0; s < 2; s++) {
        if (s < ns) {
#pragma unroll
          for (int n = 0; n < 7; n++) {
            int wrow = n * 16 + r15;
            const f16x8 b = *(const f16x8*)&Ws[wrow * WS_STRIDE + s * 32 + q * 8];
            acc[n] = __builtin_amdgcn_mfma_f32_16x16x32_f16(a[s], b, acc[n], 0, 0, 0);
          }
        }
      }
    }
  };

  do_seg(A1, lda1, K1, W1, ldw1);
  if (A2) do_seg(A2, lda2, K2, W2, ldw2);

  // ---------------- epilogue ----------------
  if (mode == 2) {
    // fused: v = acc+bias; L2-normalize row; relu; *snorm; h += v
    float ss[4] = {0.f, 0.f, 0.f, 0.f};
#pragma unroll
    for (int n = 0; n < 7; n++) {
      int col = n * 16 + r15;
      if (col < D) {
        float bv = bias[col];
#pragma unroll
        for (int r = 0; r < 4; r++) {
          float v = acc[n][r] + bv;
          ss[r] += v * v;
        }
      }
    }
#pragma unroll
    for (int m_ = 1; m_ <= 8; m_ <<= 1) {
#pragma unroll
      for (int r = 0; r < 4; r++) ss[r] += __shfl_xor(ss[r], m_, 64);
    }
    float inv[4], sn[4]; int rows[4];
#pragma unroll
    for (int r = 0; r < 4; r++) {
      rows[r] = m0 + q * 4 + r;
      float dn = fmaxf(sqrtf(ss[r]), 1e-12f);
      inv[r] = 1.0f / dn;
      sn[r] = (rows[r] < N_NODES) ? snorm[rows[r]] : 0.f;
    }
#pragma unroll
    for (int n = 0; n < 7; n++) {
      int col = n * 16 + r15;
      if (col >= D) continue;
      float bv = bias[col];
#pragma unroll
      for (int r = 0; r < 4; r++) {
        if (rows[r] >= N_NODES) continue;
        size_t idx = (size_t)rows[r] * KP_H + col;
        float hold = h_bits2f(hF[idx]);
        float v = acc[n][r] + bv;
        float x = fmaxf(v * inv[r], 0.f) * sn[r];
        hF[idx] = f2h_bits(hold + x);
      }
    }
  } else {
#pragma unroll
    for (int n = 0; n < 7; n++) {
      int col = n * 16 + r15;
      if (col >= D) continue;
      float bv = bias[col];
#pragma unroll
      for (int r = 0; r < 4; r++) {
        int row = m0 + q * 4 + r;
        if (row >= N_NODES) continue;
        float v = acc[n][r] + bv;
        outH[(size_t)row * PSTRIDE + col] = __float2half_rn(fmaxf(v, 0.f));
      }
    }
  }
}

// ---------------- pull aggregation: one wave/node, 16 edges in flight ----------
// lane = (g, lp): g = edge slot (0..3), lp = 16B segment of the 256B row.
// esrc entries premultiplied by 16. agg output = fp16.
__global__ __launch_bounds__(256)
void k_aggregate(const __half* __restrict__ pooled, const int* __restrict__ offsets,
                 const int* __restrict__ esrc,
                 unsigned int* __restrict__ aggF)
{
  int t = threadIdx.x;
  int lane = t & 63;
  int g = lane >> 4;
  int lp = lane & 15;
  int v = blockIdx.x * 4 + (t >> 6);
  if (v >= N_PAD) return;
  float va[8];
#pragma unroll
  for (int j = 0; j < 8; j++) va[j] = 0.f;
  int s0 = 0, s1 = 0;
  if (v < N_NODES) { s0 = offsets[v]; s1 = offsets[v + 1]; }
  const uint4* P = (const uint4*)pooled;   // row = 16 uint4 (256B)
  int e = s0;
  for (; e + 15 < s1; e += 16) {
    unsigned o0 = (unsigned)esrc[e + g] + lp;
    unsigned o1 = (unsigned)esrc[e + 4 + g] + lp;
    unsigned o2 = (unsigned)esrc[e + 8 + g] + lp;
    unsigned o3 = (unsigned)esrc[e + 12 + g] + lp;
    uint4 u0 = P[o0];
    uint4 u1 = P[o1];
    uint4 u2 = P[o2];
    uint4 u3 = P[o3];
#pragma unroll
    for (int w = 0; w < 4; w++) {
      uint4 u = (w == 0) ? u0 : (w == 1) ? u1 : (w == 2) ? u2 : u3;
      float2 f0 = __half22float2(__builtin_bit_cast(__half2, u.x));
      float2 f1 = __half22float2(__builtin_bit_cast(__half2, u.y));
      float2 f2 = __half22float2(__builtin_bit_cast(__half2, u.z));
      float2 f3 = __half22float2(__builtin_bit_cast(__half2, u.w));
      va[0] += f0.x; va[1] += f0.y; va[2] += f1.x; va[3] += f1.y;
      va[4] += f2.x; va[5] += f2.y; va[6] += f3.x; va[7] += f3.y;
    }
  }
  for (; e + 7 < s1; e += 8) {
    unsigned o0 = (unsigned)esrc[e + g] + lp;
    unsigned o1 = (unsigned)esrc[e + 4 + g] + lp;
    uint4 u0 = P[o0];
    uint4 u1 = P[o1];
#pragma unroll
    for (int w = 0; w < 2; w++) {
      uint4 u = (w == 0) ? u0 : u1;
      float2 f0 = __half22float2(__builtin_bit_cast(__half2, u.x));
      float2 f1 = __half22float2(__builtin_bit_cast(__half2, u.y));
      float2 f2 = __half22float2(__builtin_bit_cast(__half2, u.z));
      float2 f3 = __half22float2(__builtin_bit_cast(__half2, u.w));
      va[0] += f0.x; va[1] += f0.y; va[2] += f1.x; va[3] += f1.y;
      va[4] += f2.x; va[5] += f2.y; va[6] += f3.x; va[7] += f3.y;
    }
  }
  for (; e < s1; e += 4) {
    int idx = e + g;
    if (idx < s1) {
      unsigned o = (unsigned)esrc[idx] + lp;
      uint4 u = P[o];
      float2 f0 = __half22float2(__builtin_bit_cast(__half2, u.x));
      float2 f1 = __half22float2(__builtin_bit_cast(__half2, u.y));
      float2 f2 = __half22float2(__builtin_bit_cast(__half2, u.z));
      float2 f3 = __half22float2(__builtin_bit_cast(__half2, u.w));
      va[0] += f0.x; va[1] += f0.y; va[2] += f1.x; va[3] += f1.y;
      va[4] += f2.x; va[5] += f2.y; va[6] += f3.x; va[7] += f3.y;
    }
  }
  // combine the 4 edge-slot groups (lanes with equal lp)
#pragma unroll
  for (int j = 0; j < 8; j++) {
    va[j] += __shfl_xor(va[j], 16, 64);
    va[j] += __shfl_xor(va[j], 32, 64);
  }
  if (g == 0) {
    int dgi = s1 - s0; if (dgi < 1) dgi = 1;
    float inv = 1.0f / (float)dgi;
    unsigned int w_[4];
#pragma unroll
    for (int p = 0; p < 4; p++) {
      unsigned short h0 = f2h_bits(va[2 * p] * inv);
      unsigned short h1 = f2h_bits(va[2 * p + 1] * inv);
      w_[p] = (unsigned)h0 | ((unsigned)h1 << 16);
    }
    *(uint4*)&aggF[(size_t)v * 64 + lp * 4] = make_uint4(w_[0], w_[1], w_[2], w_[3]);
  }
}

// ---------------- per-graph mean, phase 1: 8 chunks/graph partial sums ----------
__global__ __launch_bounds__(256)
void k_gm_part(const unsigned short* __restrict__ hF,
               const int* __restrict__ gid, float* __restrict__ hgpart) {
  int g = blockIdx.x >> 3;
  int j = blockIdx.x & 7;
  int t = threadIdx.x;
  int c = t & 127, rp = t >> 7;
  int lo = 0, hi = N_NODES;
  while (lo < hi) { int m = (lo + hi) >> 1; if (gid[m] < g) lo = m + 1; else hi = m; }
  int s = lo;
  hi = N_NODES;
  while (lo < hi) { int m = (lo + hi) >> 1; if (gid[m] < g + 1) lo = m + 1; else hi = m; }
  int e = lo;
  int per = ((e - s) + 7) >> 3;
  int vs = s + j * per;
  int ve = vs + per; if (ve > e) ve = e;
  float acc = 0.f;
  if (c < D) {
    for (int v = vs + rp; v < ve; v += 2) {
      acc += h_bits2f(hF[(size_t)v * KP_H + c]);
    }
  }
  __shared__ float part[2][128];
  part[rp][c] = acc;
  __syncthreads();
  if (rp == 0 && c < D)
    hgpart[(size_t)blockIdx.x * D + c] = part[0][c] + part[1][c];
}

// ---------------- per-graph mean, phase 2: reduce 8 chunks + divide ------------
__global__ __launch_bounds__(128)
void k_gm_fin(const float* __restrict__ hgpart, const int* __restrict__ gid,
              float* __restrict__ hg) {
  int g = blockIdx.x;
  int t = threadIdx.x;
  int lo = 0, hi = N_NODES;
  while (lo < hi) { int m = (lo + hi) >> 1; if (gid[m] < g) lo = m + 1; else hi = m; }
  int s = lo;
  hi = N_NODES;
  while (lo < hi) { int m = (lo + hi) >> 1; if (gid[m] < g + 1) lo = m + 1; else hi = m; }
  int cnt = lo - s; if (cnt < 1) cnt = 1;
  if (t < D) {
    float sum = 0.f;
#pragma unroll
    for (int j = 0; j < 8; j++) sum += hgpart[(size_t)(g * 8 + j) * D + t];
    hg[g * D + t] = sum / (float)cnt;
  }
}

// ---------------- MLP readout ----------------
__global__ __launch_bounds__(64)
void k_readout(const float* __restrict__ hg,
               const float* __restrict__ Wr0, const float* __restrict__ br0,
               const float* __restrict__ Wr1, const float* __restrict__ br1,
               const float* __restrict__ Wr2, const float* __restrict__ br2,
               float* __restrict__ out) {
  int g = blockIdx.x;
  int t = threadIdx.x;
  __shared__ float x0[D];
  __shared__ float x1[54];
  __shared__ float x2[27];
  for (int i = t; i < D; i += 64) x0[i] = hg[g * D + i];
  __syncthreads();
  if (t < 54) {
    float v = br0[t];
    for (int k = 0; k < D; k++) v += x0[k] * Wr0[t * D + k];
    x1[t] = fmaxf(v, 0.f);
  }
  __syncthreads();
  if (t < 27) {
    float v = br1[t];
    for (int k = 0; k < 54; k++) v += x1[k] * Wr1[t * 54 + k];
    x2[t] = fmaxf(v, 0.f);
  }
  __syncthreads();
  if (t < 10) {
    float v = br2[t];
    for (int k = 0; k < 27; k++) v += x2[k] * Wr2[t * 27 + k];
    out[g * 10 + t] = v;
  }
}

extern "C" void kernel_launch(void* const* d_in, const int* in_sizes, int n_in,
                              void* d_out, int out_size, void* d_ws, size_t ws_size,
                              hipStream_t stream) {
  const float* nodes_feat = (const float*)d_in[0];
  const float* snorm_n    = (const float*)d_in[1];
  const int*   src        = (const int*)d_in[2];
  const int*   dst        = (const int*)d_in[3];
  const int*   gid        = (const int*)d_in[4];
  const float* W_emb      = (const float*)d_in[6];
  const float* b_emb      = (const float*)d_in[7];
  const float* W_pool     = (const float*)d_in[8];
  const float* b_pool     = (const float*)d_in[9];
  const float* W_node     = (const float*)d_in[10];
  const float* b_node     = (const float*)d_in[11];
  const float* W_r0       = (const float*)d_in[12];
  const float* b_r0       = (const float*)d_in[13];
  const float* W_r1       = (const float*)d_in[14];
  const float* b_r1       = (const float*)d_in[15];
  const float* W_r2       = (const float*)d_in[16];
  const float* b_r2       = (const float*)d_in[17];
  float* out = (float*)d_out;

  char* ws = (char*)d_ws;
  size_t off = 0;
  auto alloc = [&](size_t bytes) { size_t o = off; off = (off + bytes + 255) & ~(size_t)255; return o; };

  __half* buf1 = (__half*)(ws + alloc((size_t)N_NODES * PSTRIDE * 2));  // pooled (fp16, padded)
  unsigned short* hF   = (unsigned short*)(ws + alloc((size_t)N_PAD * KP_H * 2));
  unsigned short* aggF = (unsigned short*)(ws + alloc((size_t)N_PAD * KP_H * 2));
  uint2* ebin = (uint2*)(ws + alloc((size_t)N_EDGES * 8));
  int* esrc  = (int*)(ws + alloc((size_t)N_EDGES * 4));
  int* offs  = (int*)(ws + alloc((size_t)(N_NODES + 1) * 4));
  int* bhist = (int*)(ws + alloc((size_t)(NBUCKET + 1) * 4));
  int* boffs = (int*)(ws + alloc((size_t)(NBUCKET + 1) * 4));
  int* bcur  = (int*)(ws + alloc((size_t)(NBUCKET + 1) * 4));
  unsigned short* wF = (unsigned short*)(ws + alloc((size_t)W_TOTAL * 2));
  float* hgpart = (float*)(ws + alloc((size_t)N_GRAPHS * 8 * D * 4));
  float* hg = (float*)(ws + alloc((size_t)N_GRAPHS * D * 4));
  (void)ws_size; (void)n_in; (void)in_sizes; (void)out_size;

  hipMemsetAsync(bhist, 0, (size_t)NBUCKET * 4, stream);

  // weight convert
  k_split_w<<<(W_TOTAL + 255) / 256, 256, 0, stream>>>(W_emb, W_pool, W_node, wF);

  // CSR build via bucket counting sort (writes offs + esrc premultiplied)
  const int EB = (N_EDGES + 2047) / 2048;  // 782
  k_bhist<<<EB, 256, 0, stream>>>(dst, bhist);
  k_bscan<<<1, 512, 0, stream>>>(bhist, boffs, bcur, offs);
  k_binscatter<<<EB, 256, 0, stream>>>(src, dst, bcur, ebin);
  k_scatter2<<<NBUCKET, 256, 0, stream>>>(ebin, boffs, offs, esrc);

  const int GEMM_GRID = N_PAD / 128;  // 782
  // embedding: h = nodes_feat @ W_emb^T + b_emb  (fp32 A fused convert; writes h pad)
  k_mm_embed<<<GEMM_GRID, 512, 0, stream>>>(nodes_feat, wF + WEMB_OFF, b_emb, hF);

  for (int l = 0; l < 4; l++) {
    const unsigned short* wp  = wF + WPOOL_OFF  + (size_t)l * 14336;
    const unsigned short* wn1 = wF + WNODE1_OFF + (size_t)l * 14336;
    const unsigned short* wn2 = wF + WNODE2_OFF + (size_t)l * 14336;
    const float* bp = b_pool + (size_t)l * D;
    const float* bn = b_node + (size_t)l * D;

    // pooled = relu(h @ Wp^T + bp)  (fp16 out, padded stride)
    k_mm<<<GEMM_GRID, 512, 0, stream>>>(hF, KP_H, KP_H,
                                        wp, KP_H,
                                        nullptr, 0, 0, nullptr, 0,
                                        bp, 1, buf1, nullptr, nullptr);
    // agg = mean_in(pooled)  (fp16 out)
    k_aggregate<<<N_PAD / 4, 256, 0, stream>>>(buf1, offs, esrc, (unsigned int*)aggF);
    // h += relu(normalize(h@Wn1^T + agg@Wn2^T + bn)) * snorm   (fused)
    k_mm<<<GEMM_GRID, 512, 0, stream>>>(hF, KP_H, KP_H,
                                        wn1, KP_H,
                                        aggF, KP_H, KP_H,
                                        wn2, KP_H,
                                        bn, 2, nullptr, hF, snorm_n);
  }

  k_gm_part<<<N_GRAPHS * 8, 256, 0, stream>>>(hF, gid, hgpart);
  k_gm_fin<<<N_GRAPHS, 128, 0, stream>>>(hgpart, gid, hg);
  k_readout<<<N_GRAPHS, 64, 0, stream>>>(hg, W_r0, b_r0, W_r1, b_r1, W_r2, b_r2, out);
}

// Round 18
// 528.400 us; speedup vs baseline: 1.7144x; 1.0712x over previous
//
#include <hip/hip_runtime.h>
#include <hip/hip_bf16.h>
#include <hip/hip_fp16.h>

#define N_NODES  100000
#define N_PAD    100096
#define N_EDGES  1600000
#define N_GRAPHS 128
#define D        108
#define IN_DIM   146
#define KP_H     128
#define KP_NF    160
#define PSTRIDE  128      // pooled row stride in halves (256B, line-aligned)
#define NBUCKET  391      // ceil(N_NODES/256)
#define LBUF     8192     // per-bucket LDS scatter buffer (max bucket edges ~4400)

typedef _Float16 f16x8 __attribute__((ext_vector_type(8)));
typedef float    f32x4 __attribute__((ext_vector_type(4)));

__device__ __forceinline__ unsigned short f2h_bits(float v) {
  __half h = __float2half_rn(v);
  return __builtin_bit_cast(unsigned short, h);
}
__device__ __forceinline__ float h_bits2f(unsigned short u) {
  __half h = __builtin_bit_cast(__half, u);
  return __half2float(h);
}

// ---------------- bucket histogram (LDS-batched) ----------------
__global__ __launch_bounds__(256)
void k_bhist(const int* __restrict__ dst, int* __restrict__ bhist) {
  __shared__ int bh[NBUCKET];
  int t = threadIdx.x;
  for (int i = t; i < NBUCKET; i += 256) bh[i] = 0;
  __syncthreads();
  int e0 = blockIdx.x * 2048;
#pragma unroll
  for (int j = 0; j < 8; j++) {
    int e = e0 + j * 256 + t;
    if (e < N_EDGES) atomicAdd(&bh[dst[e] >> 8], 1);
  }
  __syncthreads();
  for (int i = t; i < NBUCKET; i += 256)
    if (bh[i]) atomicAdd(&bhist[i], bh[i]);
}

// ---------------- bucket scan (one block) ----------------
__global__ __launch_bounds__(512)
void k_bscan(const int* __restrict__ bhist, int* __restrict__ boffs,
             int* __restrict__ bcur, int* __restrict__ offs) {
  __shared__ int sh[512];
  int t = threadIdx.x;
  sh[t] = (t < NBUCKET) ? bhist[t] : 0;
  __syncthreads();
  for (int off = 1; off < 512; off <<= 1) {
    int v = (t >= off) ? sh[t - off] : 0;
    __syncthreads();
    sh[t] += v;
    __syncthreads();
  }
  if (t < NBUCKET) {
    int excl = (t > 0) ? sh[t - 1] : 0;
    boffs[t] = excl;
    bcur[t]  = excl;
  }
  if (t == 0) { boffs[NBUCKET] = N_EDGES; offs[N_NODES] = N_EDGES; }
}

// ---------------- bin edges into bucket-contiguous ebin (LDS-batched ranks) ----
__global__ __launch_bounds__(256)
void k_binscatter(const int* __restrict__ src, const int* __restrict__ dst,
                  int* __restrict__ bcur, uint2* __restrict__ ebin) {
  __shared__ int lhist[NBUCKET];
  __shared__ int lbase[NBUCKET];
  int t = threadIdx.x;
  for (int i = t; i < NBUCKET; i += 256) lhist[i] = 0;
  __syncthreads();
  int e0 = blockIdx.x * 2048;
  int s[8], d[8], r[8];
#pragma unroll
  for (int j = 0; j < 8; j++) {
    int e = e0 + j * 256 + t;
    if (e < N_EDGES) {
      s[j] = src[e]; d[j] = dst[e];
      r[j] = atomicAdd(&lhist[d[j] >> 8], 1);
    }
  }
  __syncthreads();
  for (int i = t; i < NBUCKET; i += 256)
    lbase[i] = lhist[i] ? atomicAdd(&bcur[i], lhist[i]) : 0;
  __syncthreads();
#pragma unroll
  for (int j = 0; j < 8; j++) {
    int e = e0 + j * 256 + t;
    if (e < N_EDGES)
      ebin[(size_t)lbase[d[j] >> 8] + r[j]] = make_uint2((unsigned)s[j], (unsigned)d[j]);
  }
}

// ---------------- per-bucket local CSR: writes offs + coalesced esrc ----------
// esrc entries are PREMULTIPLIED by 16 (uint4-index of the pooled row).
__global__ __launch_bounds__(256)
void k_scatter2(const uint2* __restrict__ ebin, const int* __restrict__ boffs,
                int* __restrict__ offs, int* __restrict__ esrc) {
  __shared__ int lcnt[256];
  __shared__ int lcur[256];
  __shared__ int lbuf[LBUF];
  int b = blockIdx.x;
  int t = threadIdx.x;
  int vbase = b << 8;
  int estart = boffs[b], eend = boffs[b + 1];
  int cnt = eend - estart;
  lcnt[t] = 0;
  __syncthreads();
  for (int e = estart + t; e < eend; e += 256)
    atomicAdd(&lcnt[ebin[e].y & 255], 1);
  __syncthreads();
  // inclusive scan of lcnt (in-place Hillis-Steele)
  for (int off = 1; off < 256; off <<= 1) {
    int v = (t >= off) ? lcnt[t - off] : 0;
    __syncthreads();
    lcnt[t] += v;
    __syncthreads();
  }
  int excl = (t > 0) ? lcnt[t - 1] : 0;
  int v = vbase + t;
  if (v < N_NODES) offs[v] = estart + excl;
  lcur[t] = excl;
  __syncthreads();
  if (cnt <= LBUF) {
    for (int e = estart + t; e < eend; e += 256) {
      uint2 u = ebin[e];
      int pos = atomicAdd(&lcur[u.y & 255], 1);
      lbuf[pos] = (int)(u.x << 4);
    }
    __syncthreads();
    for (int i = t; i < cnt; i += 256) esrc[estart + i] = lbuf[i];
  } else {   // safety fallback (statistically unreachable)
    for (int e = estart + t; e < eend; e += 256) {
      uint2 u = ebin[e];
      int pos = atomicAdd(&lcur[u.y & 255], 1);
      esrc[estart + pos] = (int)(u.x << 4);
    }
  }
}

// ---------------- convert + pad all weights into one fp16 buffer ----------------
// layout: [0,17920) Wemb [112][160]; then 4x wpool [112][128]; 4x wnode1; 4x wnode2
#define WEMB_OFF   0
#define WPOOL_OFF  17920
#define WNODE1_OFF (17920 + 4*14336)
#define WNODE2_OFF (17920 + 8*14336)
#define W_TOTAL    (17920 + 12*14336)

__global__ void k_split_w(const float* __restrict__ W_emb, const float* __restrict__ W_pool,
                          const float* __restrict__ W_node,
                          unsigned short* __restrict__ wF) {
  size_t stride = (size_t)gridDim.x * blockDim.x;
  for (size_t i = (size_t)blockIdx.x * blockDim.x + threadIdx.x; i < W_TOTAL; i += stride) {
    float v = 0.f;
    if (i < WPOOL_OFF) {
      int r = (int)(i / KP_NF), k = (int)(i % KP_NF);
      if (r < D && k < IN_DIM) v = W_emb[(size_t)r * IN_DIM + k];
    } else {
      size_t i2 = i - WPOOL_OFF;
      int seg = (int)(i2 / (4 * 14336));
      size_t r2 = i2 % (4 * 14336);
      int l = (int)(r2 / 14336);
      int n = (int)((r2 % 14336) / KP_H);
      int k = (int)(r2 % KP_H);
      if (n < D && k < D) {
        if (seg == 0)      v = W_pool[(size_t)l * D * D + (size_t)n * D + k];
        else if (seg == 1) v = W_node[(size_t)l * D * 2 * D + (size_t)n * 2 * D + k];
        else               v = W_node[(size_t)l * D * 2 * D + (size_t)n * 2 * D + D + k];
      }
    }
    wF[i] = f2h_bits(v);
  }
}

// ---------------- embed GEMM: fp32 A (nodes_feat) -> fp16 h, dbuf W staging ----
// grid 782, block 512 (8 waves), M-tile 128 (16 rows/wave), n-tile 112 (7x16)
// Writes h pad (cols 112..127, rows >= N_NODES) = 0.
#define WS_STRIDE 76
__global__ __launch_bounds__(512)
void k_mm_embed(const float* __restrict__ Af,
                const unsigned short* __restrict__ W_,
                const float* __restrict__ bias,
                unsigned short* __restrict__ hF)
{
  __shared__ unsigned short Ws[2][112 * WS_STRIDE];

  const int t = threadIdx.x;
  const int lane = t & 63;
  const int wv = t >> 6;
  const int r15 = lane & 15;
  const int q = lane >> 4;
  const int m0 = blockIdx.x * 128 + wv * 16;
  const int row = m0 + r15;
  const bool rok = row < N_NODES;
  const float* rp_ = Af + (size_t)row * IN_DIM;

  f32x4 acc[7];
#pragma unroll
  for (int j = 0; j < 7; j++) acc[j] = f32x4{0.f, 0.f, 0.f, 0.f};

  const int NCH = 3;               // 64, 64, 32
  auto stage = [&](int buf, int k0, int klen) {
    if (klen == 64) {
      for (int u = t; u < 896; u += 512) {
        int r_ = u >> 3, kq = u & 7;
        *(uint4*)&Ws[buf][r_ * WS_STRIDE + kq * 8] =
            *(const uint4*)&W_[(size_t)r_ * KP_NF + k0 + kq * 8];
      }
    } else {
      for (int u = t; u < 448; u += 512) {
        int r_ = u >> 2, kq = u & 3;
        *(uint4*)&Ws[buf][r_ * WS_STRIDE + kq * 8] =
            *(const uint4*)&W_[(size_t)r_ * KP_NF + k0 + kq * 8];
      }
    }
  };

  stage(0, 0, 64);
  __syncthreads();
  for (int c = 0; c < NCH; c++) {
    const int k0 = c * 64;
    const int klen = (KP_NF - k0 >= 64) ? 64 : (KP_NF - k0);
    const int ns = klen >> 5;
    // A fragments for this chunk
    f16x8 a[2];
#pragma unroll
    for (int s = 0; s < 2; s++) {
      if (s < ns) {
        int kb = k0 + s * 32 + q * 8;
        float vv[8];
        if (rok && kb + 8 <= IN_DIM) {
          const float2* pf = (const float2*)(rp_ + kb);   // 8B-aligned always
          float2 f0 = pf[0], f1 = pf[1], f2 = pf[2], f3 = pf[3];
          vv[0] = f0.x; vv[1] = f0.y; vv[2] = f1.x; vv[3] = f1.y;
          vv[4] = f2.x; vv[5] = f2.y; vv[6] = f3.x; vv[7] = f3.y;
        } else {
#pragma unroll
          for (int j = 0; j < 8; j++) {
            int k = kb + j;
            vv[j] = (rok && k < IN_DIM) ? rp_[k] : 0.f;
          }
        }
#pragma unroll
        for (int j = 0; j < 8; j++) a[s][j] = (_Float16)vv[j];
      }
    }
    // stage next chunk into alternate buffer (overlaps MFMA below)
    if (c + 1 < NCH) {
      int nk0 = (c + 1) * 64;
      stage((c + 1) & 1, nk0, (KP_NF - nk0 >= 64) ? 64 : (KP_NF - nk0));
    }
#pragma unroll
    for (int s = 0; s < 2; s++) {
      if (s < ns) {
#pragma unroll
        for (int n = 0; n < 7; n++) {
          int wrow = n * 16 + r15;
          const f16x8 b = *(const f16x8*)&Ws[c & 1][wrow * WS_STRIDE + s * 32 + q * 8];
          acc[n] = __builtin_amdgcn_mfma_f32_16x16x32_f16(a[s], b, acc[n], 0, 0, 0);
        }
      }
    }
    __syncthreads();
  }

  // epilogue: write full [row][0..127] including pad zeros
#pragma unroll
  for (int n = 0; n < 7; n++) {
    int col = n * 16 + r15;
    float bv = (col < D) ? bias[col] : 0.f;
#pragma unroll
    for (int r = 0; r < 4; r++) {
      int orow = m0 + q * 4 + r;
      float v = (orow < N_NODES && col < D) ? (acc[n][r] + bv) : 0.f;
      hF[(size_t)orow * KP_H + col] = f2h_bits(v);
    }
  }
  {
    int col = 112 + r15;
#pragma unroll
    for (int r = 0; r < 4; r++) {
      int orow = m0 + q * 4 + r;
      hF[(size_t)orow * KP_H + col] = 0;
    }
  }
}

// ---------------- fp16 MFMA GEMM, dbuf W staging, 8 waves R=1 ----------------
// grid 782, block 512 (8 waves), M-tile 128 (16 rows/wave), n-tile 112 (7x16)
// A1/A2 segments flattened into one chunk list (all K multiples of 64 here).
// modes: 1 = pool (fp16 out + relu, PSTRIDE), 2 = node (fused norm/res on fp16 h)
__global__ __launch_bounds__(512)
void k_mm(const unsigned short* A1, int lda1, int K1,
          const unsigned short* __restrict__ W1, int ldw1,
          const unsigned short* A2, int lda2, int K2,
          const unsigned short* __restrict__ W2, int ldw2,
          const float* __restrict__ bias, int mode,
          __half* __restrict__ outH,
          unsigned short* hF,
          const float* __restrict__ snorm)
{
  __shared__ unsigned short Ws[2][112 * WS_STRIDE];

  const int t = threadIdx.x;
  const int lane = t & 63;
  const int wv = t >> 6;          // 0..7
  const int r15 = lane & 15;
  const int q = lane >> 4;
  const int m0 = blockIdx.x * 128 + wv * 16;

  const int nch1 = K1 >> 6;
  const int nch2 = A2 ? (K2 >> 6) : 0;
  const int ncht = nch1 + nch2;

  f32x4 acc[7];
#pragma unroll
  for (int j = 0; j < 7; j++) acc[j] = f32x4{0.f, 0.f, 0.f, 0.f};

  auto chunk_W = [&](int c, const unsigned short*& W, int& ldw, int& k0) {
    if (c < nch1) { W = W1; ldw = ldw1; k0 = c << 6; }
    else          { W = W2; ldw = ldw2; k0 = (c - nch1) << 6; }
  };
  auto stage = [&](int buf, int c) {
    const unsigned short* W; int ldw, k0;
    chunk_W(c, W, ldw, k0);
    for (int u = t; u < 896; u += 512) {
      int row = u >> 3, kq = u & 7;
      *(uint4*)&Ws[buf][row * WS_STRIDE + kq * 8] =
          *(const uint4*)&W[(size_t)row * ldw + k0 + kq * 8];
    }
  };

  stage(0, 0);
  __syncthreads();
  for (int c = 0; c < ncht; c++) {
    const unsigned short* A; int lda, k0;
    if (c < nch1) { A = A1; lda = lda1; k0 = c << 6; }
    else          { A = A2; lda = lda2; k0 = (c - nch1) << 6; }
    // A fragments
    f16x8 a[2];
#pragma unroll
    for (int s = 0; s < 2; s++) {
      size_t base = (size_t)(m0 + r15) * lda + k0 + s * 32 + q * 8;
      a[s] = *(const f16x8*)&A[base];
    }
    // stage next chunk (overlaps MFMA)
    if (c + 1 < ncht) stage((c + 1) & 1, c + 1);
#pragma unroll
    for (int s = 0; s < 2; s++) {
#pragma unroll
      for (int n = 0; n < 7; n++) {
        int wrow = n * 16 + r15;
        const f16x8 b = *(const f16x8*)&Ws[c & 1][wrow * WS_STRIDE + s * 32 + q * 8];
        acc[n] = __builtin_amdgcn_mfma_f32_16x16x32_f16(a[s], b, acc[n], 0, 0, 0);
      }
    }
    __syncthreads();
  }

  // ---------------- epilogue ----------------
  if (mode == 2) {
    // fused: v = acc+bias; L2-normalize row; relu; *snorm; h += v
    float ss[4] = {0.f, 0.f, 0.f, 0.f};
#pragma unroll
    for (int n = 0; n < 7; n++) {
      int col = n * 16 + r15;
      if (col < D) {
        float bv = bias[col];
#pragma unroll
        for (int r = 0; r < 4; r++) {
          float v = acc[n][r] + bv;
          ss[r] += v * v;
        }
      }
    }
#pragma unroll
    for (int m_ = 1; m_ <= 8; m_ <<= 1) {
#pragma unroll
      for (int r = 0; r < 4; r++) ss[r] += __shfl_xor(ss[r], m_, 64);
    }
    float inv[4], sn[4]; int rows[4];
#pragma unroll
    for (int r = 0; r < 4; r++) {
      rows[r] = m0 + q * 4 + r;
      float dn = fmaxf(sqrtf(ss[r]), 1e-12f);
      inv[r] = 1.0f / dn;
      sn[r] = (rows[r] < N_NODES) ? snorm[rows[r]] : 0.f;
    }
#pragma unroll
    for (int n = 0; n < 7; n++) {
      int col = n * 16 + r15;
      if (col >= D) continue;
      float bv = bias[col];
#pragma unroll
      for (int r = 0; r < 4; r++) {
        if (rows[r] >= N_NODES) continue;
        size_t idx = (size_t)rows[r] * KP_H + col;
        float hold = h_bits2f(hF[idx]);
        float v = acc[n][r] + bv;
        float x = fmaxf(v * inv[r], 0.f) * sn[r];
        hF[idx] = f2h_bits(hold + x);
      }
    }
  } else {
#pragma unroll
    for (int n = 0; n < 7; n++) {
      int col = n * 16 + r15;
      if (col >= D) continue;
      float bv = bias[col];
#pragma unroll
      for (int r = 0; r < 4; r++) {
        int row = m0 + q * 4 + r;
        if (row >= N_NODES) continue;
        float v = acc[n][r] + bv;
        outH[(size_t)row * PSTRIDE + col] = __float2half_rn(fmaxf(v, 0.f));
      }
    }
  }
}

// ---------------- pull aggregation: one wave/node, 16 edges in flight ----------
// lane = (g, lp): g = edge slot (0..3), lp = 16B segment of the 256B row.
// esrc entries premultiplied by 16. agg output = fp16.
__global__ __launch_bounds__(256)
void k_aggregate(const __half* __restrict__ pooled, const int* __restrict__ offsets,
                 const int* __restrict__ esrc,
                 unsigned int* __restrict__ aggF)
{
  int t = threadIdx.x;
  int lane = t & 63;
  int g = lane >> 4;
  int lp = lane & 15;
  int v = blockIdx.x * 4 + (t >> 6);
  if (v >= N_PAD) return;
  float va[8];
#pragma unroll
  for (int j = 0; j < 8; j++) va[j] = 0.f;
  int s0 = 0, s1 = 0;
  if (v < N_NODES) { s0 = offsets[v]; s1 = offsets[v + 1]; }
  const uint4* P = (const uint4*)pooled;   // row = 16 uint4 (256B)
  int e = s0;
  for (; e + 15 < s1; e += 16) {
    unsigned o0 = (unsigned)esrc[e + g] + lp;
    unsigned o1 = (unsigned)esrc[e + 4 + g] + lp;
    unsigned o2 = (unsigned)esrc[e + 8 + g] + lp;
    unsigned o3 = (unsigned)esrc[e + 12 + g] + lp;
    uint4 u0 = P[o0];
    uint4 u1 = P[o1];
    uint4 u2 = P[o2];
    uint4 u3 = P[o3];
#pragma unroll
    for (int w = 0; w < 4; w++) {
      uint4 u = (w == 0) ? u0 : (w == 1) ? u1 : (w == 2) ? u2 : u3;
      float2 f0 = __half22float2(__builtin_bit_cast(__half2, u.x));
      float2 f1 = __half22float2(__builtin_bit_cast(__half2, u.y));
      float2 f2 = __half22float2(__builtin_bit_cast(__half2, u.z));
      float2 f3 = __half22float2(__builtin_bit_cast(__half2, u.w));
      va[0] += f0.x; va[1] += f0.y; va[2] += f1.x; va[3] += f1.y;
      va[4] += f2.x; va[5] += f2.y; va[6] += f3.x; va[7] += f3.y;
    }
  }
  for (; e + 7 < s1; e += 8) {
    unsigned o0 = (unsigned)esrc[e + g] + lp;
    unsigned o1 = (unsigned)esrc[e + 4 + g] + lp;
    uint4 u0 = P[o0];
    uint4 u1 = P[o1];
#pragma unroll
    for (int w = 0; w < 2; w++) {
      uint4 u = (w == 0) ? u0 : u1;
      float2 f0 = __half22float2(__builtin_bit_cast(__half2, u.x));
      float2 f1 = __half22float2(__builtin_bit_cast(__half2, u.y));
      float2 f2 = __half22float2(__builtin_bit_cast(__half2, u.z));
      float2 f3 = __half22float2(__builtin_bit_cast(__half2, u.w));
      va[0] += f0.x; va[1] += f0.y; va[2] += f1.x; va[3] += f1.y;
      va[4] += f2.x; va[5] += f2.y; va[6] += f3.x; va[7] += f3.y;
    }
  }
  for (; e < s1; e += 4) {
    int idx = e + g;
    if (idx < s1) {
      unsigned o = (unsigned)esrc[idx] + lp;
      uint4 u = P[o];
      float2 f0 = __half22float2(__builtin_bit_cast(__half2, u.x));
      float2 f1 = __half22float2(__builtin_bit_cast(__half2, u.y));
      float2 f2 = __half22float2(__builtin_bit_cast(__half2, u.z));
      float2 f3 = __half22float2(__builtin_bit_cast(__half2, u.w));
      va[0] += f0.x; va[1] += f0.y; va[2] += f1.x; va[3] += f1.y;
      va[4] += f2.x; va[5] += f2.y; va[6] += f3.x; va[7] += f3.y;
    }
  }
  // combine the 4 edge-slot groups (lanes with equal lp)
#pragma unroll
  for (int j = 0; j < 8; j++) {
    va[j] += __shfl_xor(va[j], 16, 64);
    va[j] += __shfl_xor(va[j], 32, 64);
  }
  if (g == 0) {
    int dgi = s1 - s0; if (dgi < 1) dgi = 1;
    float inv = 1.0f / (float)dgi;
    unsigned int w_[4];
#pragma unroll
    for (int p = 0; p < 4; p++) {
      unsigned short h0 = f2h_bits(va[2 * p] * inv);
      unsigned short h1 = f2h_bits(va[2 * p + 1] * inv);
      w_[p] = (unsigned)h0 | ((unsigned)h1 << 16);
    }
    *(uint4*)&aggF[(size_t)v * 64 + lp * 4] = make_uint4(w_[0], w_[1], w_[2], w_[3]);
  }
}

// ---------------- per-graph mean, phase 1: 8 chunks/graph partial sums ----------
__global__ __launch_bounds__(256)
void k_gm_part(const unsigned short* __restrict__ hF,
               const int* __restrict__ gid, float* __restrict__ hgpart) {
  int g = blockIdx.x >> 3;
  int j = blockIdx.x & 7;
  int t = threadIdx.x;
  int c = t & 127, rp = t >> 7;
  int lo = 0, hi = N_NODES;
  while (lo < hi) { int m = (lo + hi) >> 1; if (gid[m] < g) lo = m + 1; else hi = m; }
  int s = lo;
  hi = N_NODES;
  while (lo < hi) { int m = (lo + hi) >> 1; if (gid[m] < g + 1) lo = m + 1; else hi = m; }
  int e = lo;
  int per = ((e - s) + 7) >> 3;
  int vs = s + j * per;
  int ve = vs + per; if (ve > e) ve = e;
  float acc = 0.f;
  if (c < D) {
    for (int v = vs + rp; v < ve; v += 2) {
      acc += h_bits2f(hF[(size_t)v * KP_H + c]);
    }
  }
  __shared__ float part[2][128];
  part[rp][c] = acc;
  __syncthreads();
  if (rp == 0 && c < D)
    hgpart[(size_t)blockIdx.x * D + c] = part[0][c] + part[1][c];
}

// ---------------- per-graph mean, phase 2: reduce 8 chunks + divide ------------
__global__ __launch_bounds__(128)
void k_gm_fin(const float* __restrict__ hgpart, const int* __restrict__ gid,
              float* __restrict__ hg) {
  int g = blockIdx.x;
  int t = threadIdx.x;
  int lo = 0, hi = N_NODES;
  while (lo < hi) { int m = (lo + hi) >> 1; if (gid[m] < g) lo = m + 1; else hi = m; }
  int s = lo;
  hi = N_NODES;
  while (lo < hi) { int m = (lo + hi) >> 1; if (gid[m] < g + 1) lo = m + 1; else hi = m; }
  int cnt = lo - s; if (cnt < 1) cnt = 1;
  if (t < D) {
    float sum = 0.f;
#pragma unroll
    for (int j = 0; j < 8; j++) sum += hgpart[(size_t)(g * 8 + j) * D + t];
    hg[g * D + t] = sum / (float)cnt;
  }
}

// ---------------- MLP readout ----------------
__global__ __launch_bounds__(64)
void k_readout(const float* __restrict__ hg,
               const float* __restrict__ Wr0, const float* __restrict__ br0,
               const float* __restrict__ Wr1, const float* __restrict__ br1,
               const float* __restrict__ Wr2, const float* __restrict__ br2,
               float* __restrict__ out) {
  int g = blockIdx.x;
  int t = threadIdx.x;
  __shared__ float x0[D];
  __shared__ float x1[54];
  __shared__ float x2[27];
  for (int i = t; i < D; i += 64) x0[i] = hg[g * D + i];
  __syncthreads();
  if (t < 54) {
    float v = br0[t];
    for (int k = 0; k < D; k++) v += x0[k] * Wr0[t * D + k];
    x1[t] = fmaxf(v, 0.f);
  }
  __syncthreads();
  if (t < 27) {
    float v = br1[t];
    for (int k = 0; k < 54; k++) v += x1[k] * Wr1[t * 54 + k];
    x2[t] = fmaxf(v, 0.f);
  }
  __syncthreads();
  if (t < 10) {
    float v = br2[t];
    for (int k = 0; k < 27; k++) v += x2[k] * Wr2[t * 27 + k];
    out[g * 10 + t] = v;
  }
}

extern "C" void kernel_launch(void* const* d_in, const int* in_sizes, int n_in,
                              void* d_out, int out_size, void* d_ws, size_t ws_size,
                              hipStream_t stream) {
  const float* nodes_feat = (const float*)d_in[0];
  const float* snorm_n    = (const float*)d_in[1];
  const int*   src        = (const int*)d_in[2];
  const int*   dst        = (const int*)d_in[3];
  const int*   gid        = (const int*)d_in[4];
  const float* W_emb      = (const float*)d_in[6];
  const float* b_emb      = (const float*)d_in[7];
  const float* W_pool     = (const float*)d_in[8];
  const float* b_pool     = (const float*)d_in[9];
  const float* W_node     = (const float*)d_in[10];
  const float* b_node     = (const float*)d_in[11];
  const float* W_r0       = (const float*)d_in[12];
  const float* b_r0       = (const float*)d_in[13];
  const float* W_r1       = (const float*)d_in[14];
  const float* b_r1       = (const float*)d_in[15];
  const float* W_r2       = (const float*)d_in[16];
  const float* b_r2       = (const float*)d_in[17];
  float* out = (float*)d_out;

  char* ws = (char*)d_ws;
  size_t off = 0;
  auto alloc = [&](size_t bytes) { size_t o = off; off = (off + bytes + 255) & ~(size_t)255; return o; };

  __half* buf1 = (__half*)(ws + alloc((size_t)N_NODES * PSTRIDE * 2));  // pooled (fp16, padded)
  unsigned short* hF   = (unsigned short*)(ws + alloc((size_t)N_PAD * KP_H * 2));
  unsigned short* aggF = (unsigned short*)(ws + alloc((size_t)N_PAD * KP_H * 2));
  uint2* ebin = (uint2*)(ws + alloc((size_t)N_EDGES * 8));
  int* esrc  = (int*)(ws + alloc((size_t)N_EDGES * 4));
  int* offs  = (int*)(ws + alloc((size_t)(N_NODES + 1) * 4));
  int* bhist = (int*)(ws + alloc((size_t)(NBUCKET + 1) * 4));
  int* boffs = (int*)(ws + alloc((size_t)(NBUCKET + 1) * 4));
  int* bcur  = (int*)(ws + alloc((size_t)(NBUCKET + 1) * 4));
  unsigned short* wF = (unsigned short*)(ws + alloc((size_t)W_TOTAL * 2));
  float* hgpart = (float*)(ws + alloc((size_t)N_GRAPHS * 8 * D * 4));
  float* hg = (float*)(ws + alloc((size_t)N_GRAPHS * D * 4));
  (void)ws_size; (void)n_in; (void)in_sizes; (void)out_size;

  hipMemsetAsync(bhist, 0, (size_t)NBUCKET * 4, stream);

  // weight convert
  k_split_w<<<(W_TOTAL + 255) / 256, 256, 0, stream>>>(W_emb, W_pool, W_node, wF);

  // CSR build via bucket counting sort (writes offs + esrc premultiplied)
  const int EB = (N_EDGES + 2047) / 2048;  // 782
  k_bhist<<<EB, 256, 0, stream>>>(dst, bhist);
  k_bscan<<<1, 512, 0, stream>>>(bhist, boffs, bcur, offs);
  k_binscatter<<<EB, 256, 0, stream>>>(src, dst, bcur, ebin);
  k_scatter2<<<NBUCKET, 256, 0, stream>>>(ebin, boffs, offs, esrc);

  const int GEMM_GRID = N_PAD / 128;  // 782
  // embedding: h = nodes_feat @ W_emb^T + b_emb  (fp32 A fused convert; writes h pad)
  k_mm_embed<<<GEMM_GRID, 512, 0, stream>>>(nodes_feat, wF + WEMB_OFF, b_emb, hF);

  for (int l = 0; l < 4; l++) {
    const unsigned short* wp  = wF + WPOOL_OFF  + (size_t)l * 14336;
    const unsigned short* wn1 = wF + WNODE1_OFF + (size_t)l * 14336;
    const unsigned short* wn2 = wF + WNODE2_OFF + (size_t)l * 14336;
    const float* bp = b_pool + (size_t)l * D;
    const float* bn = b_node + (size_t)l * D;

    // pooled = relu(h @ Wp^T + bp)  (fp16 out, padded stride)
    k_mm<<<GEMM_GRID, 512, 0, stream>>>(hF, KP_H, KP_H,
                                        wp, KP_H,
                                        nullptr, 0, 0, nullptr, 0,
                                        bp, 1, buf1, nullptr, nullptr);
    // agg = mean_in(pooled)  (fp16 out)
    k_aggregate<<<N_PAD / 4, 256, 0, stream>>>(buf1, offs, esrc, (unsigned int*)aggF);
    // h += relu(normalize(h@Wn1^T + agg@Wn2^T + bn)) * snorm   (fused)
    k_mm<<<GEMM_GRID, 512, 0, stream>>>(hF, KP_H, KP_H,
                                        wn1, KP_H,
                                        aggF, KP_H, KP_H,
                                        wn2, KP_H,
                                        bn, 2, nullptr, hF, snorm_n);
  }

  k_gm_part<<<N_GRAPHS * 8, 256, 0, stream>>>(hF, gid, hgpart);
  k_gm_fin<<<N_GRAPHS, 128, 0, stream>>>(hgpart, gid, hg);
  k_readout<<<N_GRAPHS, 64, 0, stream>>>(hg, W_r0, b_r0, W_r1, b_r1, W_r2, b_r2, out);
}

// Round 19
// 528.193 us; speedup vs baseline: 1.7150x; 1.0004x over previous
//
#include <hip/hip_runtime.h>
#include <hip/hip_bf16.h>
#include <hip/hip_fp16.h>

#define N_NODES  100000
#define N_PAD    100096
#define N_EDGES  1600000
#define N_GRAPHS 128
#define D        108
#define IN_DIM   146
#define KP_H     128
#define KP_NF    160
#define PSTRIDE  128      // pooled row stride in halves (256B, line-aligned)
#define NBUCKET  391      // ceil(N_NODES/256)
#define LBUF     8192     // per-bucket LDS scatter buffer (max bucket edges ~4400)

typedef _Float16 f16x8 __attribute__((ext_vector_type(8)));
typedef float    f32x4 __attribute__((ext_vector_type(4)));

__device__ __forceinline__ unsigned short f2h_bits(float v) {
  __half h = __float2half_rn(v);
  return __builtin_bit_cast(unsigned short, h);
}
__device__ __forceinline__ float h_bits2f(unsigned short u) {
  __half h = __builtin_bit_cast(__half, u);
  return __half2float(h);
}

// ---------------- bucket histogram (LDS-batched) ----------------
__global__ __launch_bounds__(256)
void k_bhist(const int* __restrict__ dst, int* __restrict__ bhist) {
  __shared__ int bh[NBUCKET];
  int t = threadIdx.x;
  for (int i = t; i < NBUCKET; i += 256) bh[i] = 0;
  __syncthreads();
  int e0 = blockIdx.x * 2048;
#pragma unroll
  for (int j = 0; j < 8; j++) {
    int e = e0 + j * 256 + t;
    if (e < N_EDGES) atomicAdd(&bh[dst[e] >> 8], 1);
  }
  __syncthreads();
  for (int i = t; i < NBUCKET; i += 256)
    if (bh[i]) atomicAdd(&bhist[i], bh[i]);
}

// ---------------- bucket scan (one block) ----------------
__global__ __launch_bounds__(512)
void k_bscan(const int* __restrict__ bhist, int* __restrict__ boffs,
             int* __restrict__ bcur, int* __restrict__ offs) {
  __shared__ int sh[512];
  int t = threadIdx.x;
  sh[t] = (t < NBUCKET) ? bhist[t] : 0;
  __syncthreads();
  for (int off = 1; off < 512; off <<= 1) {
    int v = (t >= off) ? sh[t - off] : 0;
    __syncthreads();
    sh[t] += v;
    __syncthreads();
  }
  if (t < NBUCKET) {
    int excl = (t > 0) ? sh[t - 1] : 0;
    boffs[t] = excl;
    bcur[t]  = excl;
  }
  if (t == 0) { boffs[NBUCKET] = N_EDGES; offs[N_NODES] = N_EDGES; }
}

// ---------------- bin edges into bucket-contiguous ebin (LDS-batched ranks) ----
__global__ __launch_bounds__(256)
void k_binscatter(const int* __restrict__ src, const int* __restrict__ dst,
                  int* __restrict__ bcur, uint2* __restrict__ ebin) {
  __shared__ int lhist[NBUCKET];
  __shared__ int lbase[NBUCKET];
  int t = threadIdx.x;
  for (int i = t; i < NBUCKET; i += 256) lhist[i] = 0;
  __syncthreads();
  int e0 = blockIdx.x * 2048;
  int s[8], d[8], r[8];
#pragma unroll
  for (int j = 0; j < 8; j++) {
    int e = e0 + j * 256 + t;
    if (e < N_EDGES) {
      s[j] = src[e]; d[j] = dst[e];
      r[j] = atomicAdd(&lhist[d[j] >> 8], 1);
    }
  }
  __syncthreads();
  for (int i = t; i < NBUCKET; i += 256)
    lbase[i] = lhist[i] ? atomicAdd(&bcur[i], lhist[i]) : 0;
  __syncthreads();
#pragma unroll
  for (int j = 0; j < 8; j++) {
    int e = e0 + j * 256 + t;
    if (e < N_EDGES)
      ebin[(size_t)lbase[d[j] >> 8] + r[j]] = make_uint2((unsigned)s[j], (unsigned)d[j]);
  }
}

// ---------------- per-bucket local CSR: writes offs + coalesced esrc ----------
// esrc entries are PREMULTIPLIED by 16 (uint4-index of the pooled row).
__global__ __launch_bounds__(256)
void k_scatter2(const uint2* __restrict__ ebin, const int* __restrict__ boffs,
                int* __restrict__ offs, int* __restrict__ esrc) {
  __shared__ int lcnt[256];
  __shared__ int lcur[256];
  __shared__ int lbuf[LBUF];
  int b = blockIdx.x;
  int t = threadIdx.x;
  int vbase = b << 8;
  int estart = boffs[b], eend = boffs[b + 1];
  int cnt = eend - estart;
  lcnt[t] = 0;
  __syncthreads();
  for (int e = estart + t; e < eend; e += 256)
    atomicAdd(&lcnt[ebin[e].y & 255], 1);
  __syncthreads();
  // inclusive scan of lcnt (in-place Hillis-Steele)
  for (int off = 1; off < 256; off <<= 1) {
    int v = (t >= off) ? lcnt[t - off] : 0;
    __syncthreads();
    lcnt[t] += v;
    __syncthreads();
  }
  int excl = (t > 0) ? lcnt[t - 1] : 0;
  int v = vbase + t;
  if (v < N_NODES) offs[v] = estart + excl;
  lcur[t] = excl;
  __syncthreads();
  if (cnt <= LBUF) {
    for (int e = estart + t; e < eend; e += 256) {
      uint2 u = ebin[e];
      int pos = atomicAdd(&lcur[u.y & 255], 1);
      lbuf[pos] = (int)(u.x << 4);
    }
    __syncthreads();
    for (int i = t; i < cnt; i += 256) esrc[estart + i] = lbuf[i];
  } else {   // safety fallback (statistically unreachable)
    for (int e = estart + t; e < eend; e += 256) {
      uint2 u = ebin[e];
      int pos = atomicAdd(&lcur[u.y & 255], 1);
      esrc[estart + pos] = (int)(u.x << 4);
    }
  }
}

// ---------------- convert + pad all weights into one fp16 buffer ----------------
// layout: [0,17920) Wemb [112][160]; then 4x wpool [112][128]; 4x wnode1; 4x wnode2
#define WEMB_OFF   0
#define WPOOL_OFF  17920
#define WNODE1_OFF (17920 + 4*14336)
#define WNODE2_OFF (17920 + 8*14336)
#define W_TOTAL    (17920 + 12*14336)

__global__ void k_split_w(const float* __restrict__ W_emb, const float* __restrict__ W_pool,
                          const float* __restrict__ W_node,
                          unsigned short* __restrict__ wF) {
  size_t stride = (size_t)gridDim.x * blockDim.x;
  for (size_t i = (size_t)blockIdx.x * blockDim.x + threadIdx.x; i < W_TOTAL; i += stride) {
    float v = 0.f;
    if (i < WPOOL_OFF) {
      int r = (int)(i / KP_NF), k = (int)(i % KP_NF);
      if (r < D && k < IN_DIM) v = W_emb[(size_t)r * IN_DIM + k];
    } else {
      size_t i2 = i - WPOOL_OFF;
      int seg = (int)(i2 / (4 * 14336));
      size_t r2 = i2 % (4 * 14336);
      int l = (int)(r2 / 14336);
      int n = (int)((r2 % 14336) / KP_H);
      int k = (int)(r2 % KP_H);
      if (n < D && k < D) {
        if (seg == 0)      v = W_pool[(size_t)l * D * D + (size_t)n * D + k];
        else if (seg == 1) v = W_node[(size_t)l * D * 2 * D + (size_t)n * 2 * D + k];
        else               v = W_node[(size_t)l * D * 2 * D + (size_t)n * 2 * D + D + k];
      }
    }
    wF[i] = f2h_bits(v);
  }
}

// ---------------- embed GEMM: fp32 A (nodes_feat) -> fp16 h, dbuf W staging ----
// grid 782, block 512 (8 waves), M-tile 128 (16 rows/wave), n-tile 112 (7x16)
// Writes h pad (cols 112..127, rows >= N_NODES) = 0.
#define WS_STRIDE 76
__global__ __launch_bounds__(512)
void k_mm_embed(const float* __restrict__ Af,
                const unsigned short* __restrict__ W_,
                const float* __restrict__ bias,
                unsigned short* __restrict__ hF)
{
  __shared__ unsigned short Ws[2][112 * WS_STRIDE];

  const int t = threadIdx.x;
  const int lane = t & 63;
  const int wv = t >> 6;
  const int r15 = lane & 15;
  const int q = lane >> 4;
  const int m0 = blockIdx.x * 128 + wv * 16;
  const int row = m0 + r15;
  const bool rok = row < N_NODES;
  const float* rp_ = Af + (size_t)row * IN_DIM;

  f32x4 acc[7];
#pragma unroll
  for (int j = 0; j < 7; j++) acc[j] = f32x4{0.f, 0.f, 0.f, 0.f};

  const int NCH = 3;               // 64, 64, 32
  auto stage = [&](int buf, int k0, int klen) {
    if (klen == 64) {
      for (int u = t; u < 896; u += 512) {
        int r_ = u >> 3, kq = u & 7;
        *(uint4*)&Ws[buf][r_ * WS_STRIDE + kq * 8] =
            *(const uint4*)&W_[(size_t)r_ * KP_NF + k0 + kq * 8];
      }
    } else {
      for (int u = t; u < 448; u += 512) {
        int r_ = u >> 2, kq = u & 3;
        *(uint4*)&Ws[buf][r_ * WS_STRIDE + kq * 8] =
            *(const uint4*)&W_[(size_t)r_ * KP_NF + k0 + kq * 8];
      }
    }
  };

  stage(0, 0, 64);
  __syncthreads();
  for (int c = 0; c < NCH; c++) {
    const int k0 = c * 64;
    const int klen = (KP_NF - k0 >= 64) ? 64 : (KP_NF - k0);
    const int ns = klen >> 5;
    // A fragments for this chunk
    f16x8 a[2];
#pragma unroll
    for (int s = 0; s < 2; s++) {
      if (s < ns) {
        int kb = k0 + s * 32 + q * 8;
        float vv[8];
        if (rok && kb + 8 <= IN_DIM) {
          const float2* pf = (const float2*)(rp_ + kb);   // 8B-aligned always
          float2 f0 = pf[0], f1 = pf[1], f2 = pf[2], f3 = pf[3];
          vv[0] = f0.x; vv[1] = f0.y; vv[2] = f1.x; vv[3] = f1.y;
          vv[4] = f2.x; vv[5] = f2.y; vv[6] = f3.x; vv[7] = f3.y;
        } else {
#pragma unroll
          for (int j = 0; j < 8; j++) {
            int k = kb + j;
            vv[j] = (rok && k < IN_DIM) ? rp_[k] : 0.f;
          }
        }
#pragma unroll
        for (int j = 0; j < 8; j++) a[s][j] = (_Float16)vv[j];
      }
    }
    // stage next chunk into alternate buffer (overlaps MFMA below)
    if (c + 1 < NCH) {
      int nk0 = (c + 1) * 64;
      stage((c + 1) & 1, nk0, (KP_NF - nk0 >= 64) ? 64 : (KP_NF - nk0));
    }
#pragma unroll
    for (int s = 0; s < 2; s++) {
      if (s < ns) {
#pragma unroll
        for (int n = 0; n < 7; n++) {
          int wrow = n * 16 + r15;
          const f16x8 b = *(const f16x8*)&Ws[c & 1][wrow * WS_STRIDE + s * 32 + q * 8];
          acc[n] = __builtin_amdgcn_mfma_f32_16x16x32_f16(a[s], b, acc[n], 0, 0, 0);
        }
      }
    }
    __syncthreads();
  }

  // epilogue: write full [row][0..127] including pad zeros
#pragma unroll
  for (int n = 0; n < 7; n++) {
    int col = n * 16 + r15;
    float bv = (col < D) ? bias[col] : 0.f;
#pragma unroll
    for (int r = 0; r < 4; r++) {
      int orow = m0 + q * 4 + r;
      float v = (orow < N_NODES && col < D) ? (acc[n][r] + bv) : 0.f;
      hF[(size_t)orow * KP_H + col] = f2h_bits(v);
    }
  }
  {
    int col = 112 + r15;
#pragma unroll
    for (int r = 0; r < 4; r++) {
      int orow = m0 + q * 4 + r;
      hF[(size_t)orow * KP_H + col] = 0;
    }
  }
}

// ---------------- fp16 MFMA GEMM, dbuf W staging, 8 waves R=1 ----------------
// grid 782, block 512 (8 waves), M-tile 128 (16 rows/wave), n-tile 112 (7x16)
// modes: 1 = pool (fp16 out + relu, PSTRIDE), 2 = node (fused norm/res on fp16 h)
__global__ __launch_bounds__(512)
void k_mm(const unsigned short* A1, int lda1, int K1,
          const unsigned short* __restrict__ W1, int ldw1,
          const unsigned short* A2, int lda2, int K2,
          const unsigned short* __restrict__ W2, int ldw2,
          const float* __restrict__ bias, int mode,
          __half* __restrict__ outH,
          unsigned short* hF,
          const float* __restrict__ snorm)
{
  __shared__ unsigned short Ws[2][112 * WS_STRIDE];

  const int t = threadIdx.x;
  const int lane = t & 63;
  const int wv = t >> 6;          // 0..7
  const int r15 = lane & 15;
  const int q = lane >> 4;
  const int m0 = blockIdx.x * 128 + wv * 16;

  const int nch1 = K1 >> 6;
  const int nch2 = A2 ? (K2 >> 6) : 0;
  const int ncht = nch1 + nch2;

  f32x4 acc[7];
#pragma unroll
  for (int j = 0; j < 7; j++) acc[j] = f32x4{0.f, 0.f, 0.f, 0.f};

  auto chunk_W = [&](int c, const unsigned short*& W, int& ldw, int& k0) {
    if (c < nch1) { W = W1; ldw = ldw1; k0 = c << 6; }
    else          { W = W2; ldw = ldw2; k0 = (c - nch1) << 6; }
  };
  auto stage = [&](int buf, int c) {
    const unsigned short* W; int ldw, k0;
    chunk_W(c, W, ldw, k0);
    for (int u = t; u < 896; u += 512) {
      int row = u >> 3, kq = u & 7;
      *(uint4*)&Ws[buf][row * WS_STRIDE + kq * 8] =
          *(const uint4*)&W[(size_t)row * ldw + k0 + kq * 8];
    }
  };

  stage(0, 0);
  __syncthreads();
  for (int c = 0; c < ncht; c++) {
    const unsigned short* A; int lda, k0;
    if (c < nch1) { A = A1; lda = lda1; k0 = c << 6; }
    else          { A = A2; lda = lda2; k0 = (c - nch1) << 6; }
    // A fragments
    f16x8 a[2];
#pragma unroll
    for (int s = 0; s < 2; s++) {
      size_t base = (size_t)(m0 + r15) * lda + k0 + s * 32 + q * 8;
      a[s] = *(const f16x8*)&A[base];
    }
    // stage next chunk (overlaps MFMA)
    if (c + 1 < ncht) stage((c + 1) & 1, c + 1);
#pragma unroll
    for (int s = 0; s < 2; s++) {
#pragma unroll
      for (int n = 0; n < 7; n++) {
        int wrow = n * 16 + r15;
        const f16x8 b = *(const f16x8*)&Ws[c & 1][wrow * WS_STRIDE + s * 32 + q * 8];
        acc[n] = __builtin_amdgcn_mfma_f32_16x16x32_f16(a[s], b, acc[n], 0, 0, 0);
      }
    }
    __syncthreads();
  }

  // ---------------- epilogue ----------------
  if (mode == 2) {
    // fused: v = acc+bias; L2-normalize row; relu; *snorm; h += v
    float ss[4] = {0.f, 0.f, 0.f, 0.f};
#pragma unroll
    for (int n = 0; n < 7; n++) {
      int col = n * 16 + r15;
      if (col < D) {
        float bv = bias[col];
#pragma unroll
        for (int r = 0; r < 4; r++) {
          float v = acc[n][r] + bv;
          ss[r] += v * v;
        }
      }
    }
#pragma unroll
    for (int m_ = 1; m_ <= 8; m_ <<= 1) {
#pragma unroll
      for (int r = 0; r < 4; r++) ss[r] += __shfl_xor(ss[r], m_, 64);
    }
    float inv[4], sn[4]; int rows[4];
#pragma unroll
    for (int r = 0; r < 4; r++) {
      rows[r] = m0 + q * 4 + r;
      float dn = fmaxf(sqrtf(ss[r]), 1e-12f);
      inv[r] = 1.0f / dn;
      sn[r] = (rows[r] < N_NODES) ? snorm[rows[r]] : 0.f;
    }
#pragma unroll
    for (int n = 0; n < 7; n++) {
      int col = n * 16 + r15;
      if (col >= D) continue;
      float bv = bias[col];
#pragma unroll
      for (int r = 0; r < 4; r++) {
        if (rows[r] >= N_NODES) continue;
        size_t idx = (size_t)rows[r] * KP_H + col;
        float hold = h_bits2f(hF[idx]);
        float v = acc[n][r] + bv;
        float x = fmaxf(v * inv[r], 0.f) * sn[r];
        hF[idx] = f2h_bits(hold + x);
      }
    }
  } else {
#pragma unroll
    for (int n = 0; n < 7; n++) {
      int col = n * 16 + r15;
      if (col >= D) continue;
      float bv = bias[col];
#pragma unroll
      for (int r = 0; r < 4; r++) {
        int row = m0 + q * 4 + r;
        if (row >= N_NODES) continue;
        float v = acc[n][r] + bv;
        outH[(size_t)row * PSTRIDE + col] = __float2half_rn(fmaxf(v, 0.f));
      }
    }
  }
}

// ---------------- pull aggregation: one wave/node, 16 edges in flight ----------
// lane = (g, lp): g = edge slot (0..3), lp = 16B segment of the 256B row.
// esrc entries premultiplied by 16. Packed fp16 accumulation (v_pk_add_f16).
__global__ __launch_bounds__(256)
void k_aggregate(const __half* __restrict__ pooled, const int* __restrict__ offsets,
                 const int* __restrict__ esrc,
                 unsigned int* __restrict__ aggF)
{
  int t = threadIdx.x;
  int lane = t & 63;
  int g = lane >> 4;
  int lp = lane & 15;
  int v = blockIdx.x * 4 + (t >> 6);
  if (v >= N_PAD) return;
  __half2 va[4];
#pragma unroll
  for (int j = 0; j < 4; j++) va[j] = __half2(__float2half_rn(0.f), __float2half_rn(0.f));
  int s0 = 0, s1 = 0;
  if (v < N_NODES) { s0 = offsets[v]; s1 = offsets[v + 1]; }
  const uint4* P = (const uint4*)pooled;   // row = 16 uint4 (256B)
  int e = s0;
  for (; e + 15 < s1; e += 16) {
    unsigned o0 = (unsigned)esrc[e + g] + lp;
    unsigned o1 = (unsigned)esrc[e + 4 + g] + lp;
    unsigned o2 = (unsigned)esrc[e + 8 + g] + lp;
    unsigned o3 = (unsigned)esrc[e + 12 + g] + lp;
    uint4 u0 = P[o0];
    uint4 u1 = P[o1];
    uint4 u2 = P[o2];
    uint4 u3 = P[o3];
#pragma unroll
    for (int w = 0; w < 4; w++) {
      uint4 u = (w == 0) ? u0 : (w == 1) ? u1 : (w == 2) ? u2 : u3;
      va[0] = __hadd2(va[0], __builtin_bit_cast(__half2, u.x));
      va[1] = __hadd2(va[1], __builtin_bit_cast(__half2, u.y));
      va[2] = __hadd2(va[2], __builtin_bit_cast(__half2, u.z));
      va[3] = __hadd2(va[3], __builtin_bit_cast(__half2, u.w));
    }
  }
  for (; e + 7 < s1; e += 8) {
    unsigned o0 = (unsigned)esrc[e + g] + lp;
    unsigned o1 = (unsigned)esrc[e + 4 + g] + lp;
    uint4 u0 = P[o0];
    uint4 u1 = P[o1];
#pragma unroll
    for (int w = 0; w < 2; w++) {
      uint4 u = (w == 0) ? u0 : u1;
      va[0] = __hadd2(va[0], __builtin_bit_cast(__half2, u.x));
      va[1] = __hadd2(va[1], __builtin_bit_cast(__half2, u.y));
      va[2] = __hadd2(va[2], __builtin_bit_cast(__half2, u.z));
      va[3] = __hadd2(va[3], __builtin_bit_cast(__half2, u.w));
    }
  }
  for (; e < s1; e += 4) {
    int idx = e + g;
    if (idx < s1) {
      unsigned o = (unsigned)esrc[idx] + lp;
      uint4 u = P[o];
      va[0] = __hadd2(va[0], __builtin_bit_cast(__half2, u.x));
      va[1] = __hadd2(va[1], __builtin_bit_cast(__half2, u.y));
      va[2] = __hadd2(va[2], __builtin_bit_cast(__half2, u.z));
      va[3] = __hadd2(va[3], __builtin_bit_cast(__half2, u.w));
    }
  }
  // combine the 4 edge-slot groups (lanes with equal lp), packed
#pragma unroll
  for (int j = 0; j < 4; j++) {
    unsigned x = __builtin_bit_cast(unsigned, va[j]);
    unsigned y = (unsigned)__shfl_xor((int)x, 16, 64);
    va[j] = __hadd2(va[j], __builtin_bit_cast(__half2, y));
    x = __builtin_bit_cast(unsigned, va[j]);
    y = (unsigned)__shfl_xor((int)x, 32, 64);
    va[j] = __hadd2(va[j], __builtin_bit_cast(__half2, y));
  }
  if (g == 0) {
    int dgi = s1 - s0; if (dgi < 1) dgi = 1;
    float inv = 1.0f / (float)dgi;
    unsigned int w_[4];
#pragma unroll
    for (int p = 0; p < 4; p++) {
      float2 f = __half22float2(va[p]);
      unsigned short h0 = f2h_bits(f.x * inv);
      unsigned short h1 = f2h_bits(f.y * inv);
      w_[p] = (unsigned)h0 | ((unsigned)h1 << 16);
    }
    *(uint4*)&aggF[(size_t)v * 64 + lp * 4] = make_uint4(w_[0], w_[1], w_[2], w_[3]);
  }
}

// ---------------- per-graph mean, phase 1: 8 chunks/graph partial sums ----------
__global__ __launch_bounds__(256)
void k_gm_part(const unsigned short* __restrict__ hF,
               const int* __restrict__ gid, float* __restrict__ hgpart) {
  int g = blockIdx.x >> 3;
  int j = blockIdx.x & 7;
  int t = threadIdx.x;
  int c = t & 127, rp = t >> 7;
  int lo = 0, hi = N_NODES;
  while (lo < hi) { int m = (lo + hi) >> 1; if (gid[m] < g) lo = m + 1; else hi = m; }
  int s = lo;
  hi = N_NODES;
  while (lo < hi) { int m = (lo + hi) >> 1; if (gid[m] < g + 1) lo = m + 1; else hi = m; }
  int e = lo;
  int per = ((e - s) + 7) >> 3;
  int vs = s + j * per;
  int ve = vs + per; if (ve > e) ve = e;
  float acc = 0.f;
  if (c < D) {
    for (int v = vs + rp; v < ve; v += 2) {
      acc += h_bits2f(hF[(size_t)v * KP_H + c]);
    }
  }
  __shared__ float part[2][128];
  part[rp][c] = acc;
  __syncthreads();
  if (rp == 0 && c < D)
    hgpart[(size_t)blockIdx.x * D + c] = part[0][c] + part[1][c];
}

// ---------------- per-graph mean, phase 2: reduce 8 chunks + divide ------------
__global__ __launch_bounds__(128)
void k_gm_fin(const float* __restrict__ hgpart, const int* __restrict__ gid,
              float* __restrict__ hg) {
  int g = blockIdx.x;
  int t = threadIdx.x;
  int lo = 0, hi = N_NODES;
  while (lo < hi) { int m = (lo + hi) >> 1; if (gid[m] < g) lo = m + 1; else hi = m; }
  int s = lo;
  hi = N_NODES;
  while (lo < hi) { int m = (lo + hi) >> 1; if (gid[m] < g + 1) lo = m + 1; else hi = m; }
  int cnt = lo - s; if (cnt < 1) cnt = 1;
  if (t < D) {
    float sum = 0.f;
#pragma unroll
    for (int j = 0; j < 8; j++) sum += hgpart[(size_t)(g * 8 + j) * D + t];
    hg[g * D + t] = sum / (float)cnt;
  }
}

// ---------------- MLP readout ----------------
__global__ __launch_bounds__(64)
void k_readout(const float* __restrict__ hg,
               const float* __restrict__ Wr0, const float* __restrict__ br0,
               const float* __restrict__ Wr1, const float* __restrict__ br1,
               const float* __restrict__ Wr2, const float* __restrict__ br2,
               float* __restrict__ out) {
  int g = blockIdx.x;
  int t = threadIdx.x;
  __shared__ float x0[D];
  __shared__ float x1[54];
  __shared__ float x2[27];
  for (int i = t; i < D; i += 64) x0[i] = hg[g * D + i];
  __syncthreads();
  if (t < 54) {
    float v = br0[t];
    for (int k = 0; k < D; k++) v += x0[k] * Wr0[t * D + k];
    x1[t] = fmaxf(v, 0.f);
  }
  __syncthreads();
  if (t < 27) {
    float v = br1[t];
    for (int k = 0; k < 54; k++) v += x1[k] * Wr1[t * 54 + k];
    x2[t] = fmaxf(v, 0.f);
  }
  __syncthreads();
  if (t < 10) {
    float v = br2[t];
    for (int k = 0; k < 27; k++) v += x2[k] * Wr2[t * 27 + k];
    out[g * 10 + t] = v;
  }
}

extern "C" void kernel_launch(void* const* d_in, const int* in_sizes, int n_in,
                              void* d_out, int out_size, void* d_ws, size_t ws_size,
                              hipStream_t stream) {
  const float* nodes_feat = (const float*)d_in[0];
  const float* snorm_n    = (const float*)d_in[1];
  const int*   src        = (const int*)d_in[2];
  const int*   dst        = (const int*)d_in[3];
  const int*   gid        = (const int*)d_in[4];
  const float* W_emb      = (const float*)d_in[6];
  const float* b_emb      = (const float*)d_in[7];
  const float* W_pool     = (const float*)d_in[8];
  const float* b_pool     = (const float*)d_in[9];
  const float* W_node     = (const float*)d_in[10];
  const float* b_node     = (const float*)d_in[11];
  const float* W_r0       = (const float*)d_in[12];
  const float* b_r0       = (const float*)d_in[13];
  const float* W_r1       = (const float*)d_in[14];
  const float* b_r1       = (const float*)d_in[15];
  const float* W_r2       = (const float*)d_in[16];
  const float* b_r2       = (const float*)d_in[17];
  float* out = (float*)d_out;

  char* ws = (char*)d_ws;
  size_t off = 0;
  auto alloc = [&](size_t bytes) { size_t o = off; off = (off + bytes + 255) & ~(size_t)255; return o; };

  __half* buf1 = (__half*)(ws + alloc((size_t)N_NODES * PSTRIDE * 2));  // pooled (fp16, padded)
  unsigned short* hF   = (unsigned short*)(ws + alloc((size_t)N_PAD * KP_H * 2));
  unsigned short* aggF = (unsigned short*)(ws + alloc((size_t)N_PAD * KP_H * 2));
  uint2* ebin = (uint2*)(ws + alloc((size_t)N_EDGES * 8));
  int* esrc  = (int*)(ws + alloc((size_t)N_EDGES * 4));
  int* offs  = (int*)(ws + alloc((size_t)(N_NODES + 1) * 4));
  int* bhist = (int*)(ws + alloc((size_t)(NBUCKET + 1) * 4));
  int* boffs = (int*)(ws + alloc((size_t)(NBUCKET + 1) * 4));
  int* bcur  = (int*)(ws + alloc((size_t)(NBUCKET + 1) * 4));
  unsigned short* wF = (unsigned short*)(ws + alloc((size_t)W_TOTAL * 2));
  float* hgpart = (float*)(ws + alloc((size_t)N_GRAPHS * 8 * D * 4));
  float* hg = (float*)(ws + alloc((size_t)N_GRAPHS * D * 4));
  (void)ws_size; (void)n_in; (void)in_sizes; (void)out_size;

  hipMemsetAsync(bhist, 0, (size_t)NBUCKET * 4, stream);

  // weight convert
  k_split_w<<<(W_TOTAL + 255) / 256, 256, 0, stream>>>(W_emb, W_pool, W_node, wF);

  // CSR build via bucket counting sort (writes offs + esrc premultiplied)
  const int EB = (N_EDGES + 2047) / 2048;  // 782
  k_bhist<<<EB, 256, 0, stream>>>(dst, bhist);
  k_bscan<<<1, 512, 0, stream>>>(bhist, boffs, bcur, offs);
  k_binscatter<<<EB, 256, 0, stream>>>(src, dst, bcur, ebin);
  k_scatter2<<<NBUCKET, 256, 0, stream>>>(ebin, boffs, offs, esrc);

  const int GEMM_GRID = N_PAD / 128;  // 782
  // embedding: h = nodes_feat @ W_emb^T + b_emb  (fp32 A fused convert; writes h pad)
  k_mm_embed<<<GEMM_GRID, 512, 0, stream>>>(nodes_feat, wF + WEMB_OFF, b_emb, hF);

  for (int l = 0; l < 4; l++) {
    const unsigned short* wp  = wF + WPOOL_OFF  + (size_t)l * 14336;
    const unsigned short* wn1 = wF + WNODE1_OFF + (size_t)l * 14336;
    const unsigned short* wn2 = wF + WNODE2_OFF + (size_t)l * 14336;
    const float* bp = b_pool + (size_t)l * D;
    const float* bn = b_node + (size_t)l * D;

    // pooled = relu(h @ Wp^T + bp)  (fp16 out, padded stride)
    k_mm<<<GEMM_GRID, 512, 0, stream>>>(hF, KP_H, KP_H,
                                        wp, KP_H,
                                        nullptr, 0, 0, nullptr, 0,
                                        bp, 1, buf1, nullptr, nullptr);
    // agg = mean_in(pooled)  (fp16 out)
    k_aggregate<<<N_PAD / 4, 256, 0, stream>>>(buf1, offs, esrc, (unsigned int*)aggF);
    // h += relu(normalize(h@Wn1^T + agg@Wn2^T + bn)) * snorm   (fused)
    k_mm<<<GEMM_GRID, 512, 0, stream>>>(hF, KP_H, KP_H,
                                        wn1, KP_H,
                                        aggF, KP_H, KP_H,
                                        wn2, KP_H,
                                        bn, 2, nullptr, hF, snorm_n);
  }

  k_gm_part<<<N_GRAPHS * 8, 256, 0, stream>>>(hF, gid, hgpart);
  k_gm_fin<<<N_GRAPHS, 128, 0, stream>>>(hgpart, gid, hg);
  k_readout<<<N_GRAPHS, 64, 0, stream>>>(hg, W_r0, b_r0, W_r1, b_r1, W_r2, b_r2, out);
}